// Round 17
// baseline (913.070 us; speedup 1.0000x reference)
//
#include <hip/hip_runtime.h>
#include <cstdint>

#define TEMP_C 20.0f

typedef float f32x4 __attribute__((ext_vector_type(4)));
typedef float f32x16 __attribute__((ext_vector_type(16)));
typedef int i32x4 __attribute__((ext_vector_type(4)));
typedef int i32x8 __attribute__((ext_vector_type(8)));

// fp32 -> bf16 round-to-nearest-even
__device__ __forceinline__ unsigned short f2bf(float f) {
  union { float f; unsigned int u; } v; v.f = f;
  unsigned int r = v.u + 0x7FFFu + ((v.u >> 16) & 1u);
  return (unsigned short)(r >> 16);
}
__device__ __forceinline__ float bf2f(unsigned short b) {
  union { unsigned int u; float f; } v; v.u = ((unsigned int)b) << 16;
  return v.f;
}

// fp32 -> OCP e4m3fn, RTNE, clamp to +-448
__device__ __forceinline__ unsigned char f2e4m3(float f) {
  unsigned u = __float_as_uint(f);
  unsigned s = (u >> 24) & 0x80u;
  float a = fminf(fabsf(f), 448.0f);
  if (a < 0.015625f) {
    int d = (int)rintf(a * 512.0f);
    return (unsigned char)(s | (unsigned)d);
  }
  unsigned au = __float_as_uint(a);
  unsigned r = au + 0xFFFFFu + ((au >> 20) & 1u);
  int Ep = (int)(r >> 23) - 127;
  if (Ep > 8) return (unsigned char)(s | 0x7E);
  unsigned m = (r >> 20) & 7u;
  return (unsigned char)(s | ((unsigned)(Ep + 7) << 3) | m);
}

// fp32 -> e2m1 nibble (round to nearest of {0,.5,1,1.5,2,3,4,6}, sign bit3)
__device__ __forceinline__ unsigned f2e2m1(float f) {
  unsigned s = (__float_as_uint(f) >> 28) & 8u;
  float a = fabsf(f);
  unsigned n = (unsigned)(a >= 0.25f) + (a >= 0.75f) + (a >= 1.25f) +
               (a >= 1.75f) + (a >= 2.5f) + (a >= 3.5f) + (a >= 5.0f);
  return s | n;
}

// async global->LDS, 16B per lane (dest = wave-uniform base + lane*16)
__device__ __forceinline__ void gload_lds16(const void* g, void* l) {
  __builtin_amdgcn_global_load_lds(
      (__attribute__((address_space(1))) void*)(g),
      (__attribute__((address_space(3))) void*)(l), 16, 0, 0);
}

// ---------------------------------------------------------------------------
// 1) fused transpose + FP4 pack + per-(pixel, 32ch-group) sumsq partials.
__global__ __launch_bounds__(256) void tpose2_f4_k(
    const float* __restrict__ X4, const float* __restrict__ X3,
    unsigned char* __restrict__ T, float* __restrict__ part)
{
  __shared__ float tile[32][33];
  __shared__ float red2[8][33];
  const int tx = threadIdx.x, ty = threadIdx.y;
  const int y = blockIdx.y;
  const float* X; int c0;
  if (y < 64) { X = X4; c0 = y * 32; }
  else        { X = X3; c0 = (y - 64) * 32; }
  const int p0 = blockIdx.x * 32;
  #pragma unroll
  for (int i = 0; i < 4; ++i) {
    int c = c0 + ty + i * 8, p = p0 + tx;
    tile[ty + i * 8][tx] = (p < 3600) ? X[(size_t)c * 3600 + p] : 0.f;
  }
  __syncthreads();
  {
    float s = 0.f;
    #pragma unroll
    for (int k = 0; k < 4; ++k) { float v = tile[ty * 4 + k][tx]; s += v * v; }
    red2[ty][tx] = s;
  }
  if (tx < 16) {
    const size_t gbase = (size_t)y * 3840 * 16 + tx;
    #pragma unroll
    for (int i = 0; i < 4; ++i) {
      int p = p0 + ty + i * 8;
      if (p < 3600) {
        unsigned lo = f2e2m1(tile[2 * tx][ty + i * 8]);
        unsigned hi = f2e2m1(tile[2 * tx + 1][ty + i * 8]);
        T[gbase + (size_t)p * 16] = (unsigned char)(lo | (hi << 4));
      }
    }
  }
  __syncthreads();
  if (ty == 0 && p0 + tx < 3600) {
    float s = 0.f;
    #pragma unroll
    for (int j = 0; j < 8; ++j) s += red2[j][tx];
    part[(size_t)y * 3600 + p0 + tx] = s;
  }
}

// 1b) finish: inv4[p] = 1/||x4_p||, inv3[p] = 1/||x3_p|| from 96 partials
__global__ __launch_bounds__(256) void norm_fin_k(
    const float* __restrict__ part, float* __restrict__ inv4,
    float* __restrict__ inv3)
{
  const int p = blockIdx.x * 256 + threadIdx.x;
  if (p >= 3600) return;
  float s4 = 0.f, s3 = 0.f;
  #pragma unroll
  for (int y = 0; y < 64; ++y) s4 += part[(size_t)y * 3600 + p];
  #pragma unroll
  for (int y = 64; y < 96; ++y) s3 += part[(size_t)y * 3600 + p];
  inv4[p] = 1.0f / fmaxf(sqrtf(s4), 1e-12f);
  inv3[p] = 1.0f / fmaxf(sqrtf(s3), 1e-12f);
}

// ---------------------------------------------------------------------------
// 2) V cast to fp8, K-group-major over s
__global__ void castv_f8_k(const float* __restrict__ X, unsigned char* __restrict__ V8)
{
  int i = blockIdx.x * 256 + threadIdx.x;
  if (i >= 512 * 3600) return;
  int c = i / 3600, s = i - c * 3600;
  V8[((size_t)(s >> 4) * 512 + c) * 16 + (s & 15)] = f2e4m3(X[i]);
}

// ---------------------------------------------------------------------------
// 3) 128x128 MX-FP4 DUAL-LEVEL GEMM (r16 structure). ONLY change vs r16:
//    __launch_bounds__(256, 4) — VGPR_Count measured 124 <= 128-cap for
//    4 blocks/CU, so request the occupancy (r16's (256,2) left it at 2
//    blocks/CU and MfmaUtil fell to 16%). LDS 32KB x 4 = 128KB fits.
__global__ __launch_bounds__(256, 4) void gemm128_f4_dual(
    const unsigned char* __restrict__ A, const unsigned char* __restrict__ B,
    unsigned short* __restrict__ C, int MPr, int ldc, int nbn,
    const float* __restrict__ invq4, const float* __restrict__ invq3,
    const float* __restrict__ invs4, const float* __restrict__ invs3,
    const float* __restrict__ wch)
{
  __shared__ __align__(16) unsigned char As[2][8192];   // [4 g][128 rows][16B]
  __shared__ __align__(16) unsigned char Bs[2][8192];

  const int tid  = threadIdx.x;
  const int lane = tid & 63;
  const int wave = tid >> 6;
  const int wrow = wave >> 1;
  const int wcol = wave & 1;

  // XCD-aware bijective block remap (m204)
  const int nwg = gridDim.x;
  const int q8 = nwg >> 3, r8 = nwg & 7;
  const int xcd = blockIdx.x & 7, bidx = blockIdx.x >> 3;
  const int wg = (xcd < r8 ? xcd * (q8 + 1) : r8 * (q8 + 1) + (xcd - r8) * q8) + bidx;
  const long Arow0 = (long)(wg / nbn) * 128;
  const long Brow0 = (long)(wg % nbn) * 128;

  const unsigned char* sA[2];
  const unsigned char* sB[2];
  #pragma unroll
  for (int q = 0; q < 2; ++q) {
    const int c = q * 256 + tid;
    const int g = c >> 7, r = c & 127;
    sA[q] = A + ((long)g * MPr + Arow0 + r) * 16;
    sB[q] = B + ((long)g * MPr + Brow0 + r) * 16;
  }
  const long kstride = (long)MPr * 16 * 4;   // 4 groups (=128 fp4 k) per tile

  #define STAGE(tt) do { const int _sl = (tt) & 1; const long _ko = (long)(tt) * kstride; \
    gload_lds16(sA[0] + _ko, &As[_sl][tid * 16]);              \
    gload_lds16(sA[1] + _ko, &As[_sl][(256 + tid) * 16]);      \
    gload_lds16(sB[0] + _ko, &Bs[_sl][tid * 16]);              \
    gload_lds16(sB[1] + _ko, &Bs[_sl][(256 + tid) * 16]);      \
  } while (0)

  const int l31 = lane & 31, lk = lane >> 5;
  const int arow0 = (wrow * 64 + l31) * 16;
  const int brow0 = (wcol * 64 + l31) * 16;

  f32x16 acc4[2][2] = {};
  f32x16 acc3[2][2] = {};
  const int NT = 24;   // 16 level4 tiles + 8 level3 tiles (96 groups)

  STAGE(0);

  for (int t = 0; t < NT; ++t) {
    const int sl = t & 1;
    if (t + 1 < NT) {
      STAGE(t + 1);
      asm volatile("s_waitcnt vmcnt(4)" ::: "memory");
    } else {
      asm volatile("s_waitcnt vmcnt(0)" ::: "memory");
    }
    asm volatile("s_barrier" ::: "memory");

    const unsigned char* Ap = As[sl];
    const unsigned char* Bp = Bs[sl];
    #define FRAG4(dst, base, rowb, g) do {                       \
      i32x4 _v = *(const i32x4*)((base) + ((g) << 11) + (rowb)); \
      dst[0]=_v[0]; dst[1]=_v[1]; dst[2]=_v[2]; dst[3]=_v[3];    \
      dst[4]=_v[0]; dst[5]=_v[1]; dst[6]=_v[2]; dst[7]=_v[3];    \
    } while (0)
    #define MFMA4(a, b, d) \
      d = __builtin_amdgcn_mfma_scale_f32_32x32x64_f8f6f4( \
          a, b, d, 4, 4, 0, 127, 0, 127)

    if (t < 16) {
      #pragma unroll
      for (int h = 0; h < 2; ++h) {
        const int g = h * 2 + lk;
        i32x8 a0, a1, b0, b1;
        FRAG4(a0, Ap, arow0, g); FRAG4(a1, Ap, arow0 + 512, g);
        FRAG4(b0, Bp, brow0, g); FRAG4(b1, Bp, brow0 + 512, g);
        __builtin_amdgcn_s_setprio(1);
        MFMA4(a0, b0, acc4[0][0]); MFMA4(a0, b1, acc4[0][1]);
        MFMA4(a1, b0, acc4[1][0]); MFMA4(a1, b1, acc4[1][1]);
        __builtin_amdgcn_s_setprio(0);
      }
    } else {
      #pragma unroll
      for (int h = 0; h < 2; ++h) {
        const int g = h * 2 + lk;
        i32x8 a0, a1, b0, b1;
        FRAG4(a0, Ap, arow0, g); FRAG4(a1, Ap, arow0 + 512, g);
        FRAG4(b0, Bp, brow0, g); FRAG4(b1, Bp, brow0 + 512, g);
        __builtin_amdgcn_s_setprio(1);
        MFMA4(a0, b0, acc3[0][0]); MFMA4(a0, b1, acc3[0][1]);
        MFMA4(a1, b0, acc3[1][0]); MFMA4(a1, b1, acc3[1][1]);
        __builtin_amdgcn_s_setprio(0);
      }
    }
    #undef FRAG4
    #undef MFMA4
    asm volatile("s_barrier" ::: "memory");
  }
  #undef STAGE

  // epilogue: assemble logits. col=lane&31 (+0/+32), row=(reg&3)+8*(reg>>2)+4*lk
  const float w0 = TEMP_C * wch[0];
  const float w1 = TEMP_C * wch[1];
  const long col0 = Brow0 + wcol * 64 + l31;
  const float s40 = invs4[col0],      s30 = invs3[col0];
  const float s41 = invs4[col0 + 32], s31 = invs3[col0 + 32];
  #pragma unroll
  for (int m = 0; m < 2; ++m) {
    const long rowb = Arow0 + wrow * 64 + m * 32;
    #pragma unroll
    for (int g4 = 0; g4 < 4; ++g4) {
      #pragma unroll
      for (int r4 = 0; r4 < 4; ++r4) {
        const long row = rowb + r4 + 8 * g4 + 4 * lk;
        const float q4 = w0 * invq4[row], q3 = w1 * invq3[row];
        unsigned short* cp = C + row * (long)ldc + col0;
        const int e = g4 * 4 + r4;
        cp[0]  = f2bf(q4 * s40 * acc4[m][0][e] + q3 * s30 * acc3[m][0][e]);
        cp[32] = f2bf(q4 * s41 * acc4[m][1][e] + q3 * s31 * acc3[m][1][e]);
      }
    }
  }
}

// ---------------------------------------------------------------------------
// 4) PV MX-fp8 GEMM, deep-pipelined (r14 verified, unchanged).
__global__ __launch_bounds__(256, 2) void pv_f8_k(
    const unsigned char* __restrict__ Att, const unsigned char* __restrict__ V,
    unsigned short* __restrict__ P, int accumulate)
{
  __shared__ __align__(16) unsigned char As[4][4096];
  __shared__ __align__(16) unsigned char As2[4][4096];
  __shared__ __align__(16) unsigned char Bs[4][4096];
  __shared__ __align__(16) unsigned char Bs2[4][4096];

  const int tid  = threadIdx.x;
  const int lane = tid & 63;
  const int wave = tid >> 6;
  const int wrow = wave >> 1;
  const int wcol = wave & 1;

  const int xcd = blockIdx.x & 7, bidx = blockIdx.x >> 3;
  const int wg = xcd * 45 + bidx;
  const int x = wg / 12, rem = wg % 12;
  const int y = rem & 3, z = rem >> 2;
  const long Arow0 = (long)x * 128;
  const long Brow0 = (long)y * 128;
  P += (long)z * 3840 * 512;

  const unsigned char* sA[2];
  const unsigned char* sB[2];
  #pragma unroll
  for (int q = 0; q < 2; ++q) {
    const int c = q * 256 + tid;
    const int g = c >> 7, r = c & 127;
    sA[q] = Att + ((long)(z * 80 + g) * 3840 + Arow0 + r) * 16;
    sB[q] = V   + ((long)(z * 80 + g) * 512  + Brow0 + r) * 16;
  }
  const long ksA = 3840L * 16 * 4;
  const long ksB = 512L * 16 * 4;

  #define STAGE(tt) do { const int _sl = (tt) & 3;                      \
    gload_lds16(sA[0] + (long)(tt) * ksA, &As[_sl][tid * 16]);          \
    gload_lds16(sA[1] + (long)(tt) * ksA, &As2[_sl][tid * 16]);         \
    gload_lds16(sB[0] + (long)(tt) * ksB, &Bs[_sl][tid * 16]);          \
    gload_lds16(sB[1] + (long)(tt) * ksB, &Bs2[_sl][tid * 16]);         \
  } while (0)

  const int l31 = lane & 31, lk = lane >> 5;
  const int arow0 = (wrow * 64 + l31) * 16;
  const int brow0 = (wcol * 64 + l31) * 16;

  f32x16 acc[2][2] = {};
  const int NT = 20;

  STAGE(0); STAGE(1); STAGE(2);

  for (int t = 0; t < NT; ++t) {
    const int sl = t & 3;
    const int rem_t = NT - 1 - t;
    if (rem_t >= 2)      asm volatile("s_waitcnt vmcnt(8)" ::: "memory");
    else if (rem_t == 1) asm volatile("s_waitcnt vmcnt(4)" ::: "memory");
    else                 asm volatile("s_waitcnt vmcnt(0)" ::: "memory");
    asm volatile("s_barrier" ::: "memory");
    if (t + 3 < NT) STAGE(t + 3);

    const unsigned char* ApL = lk ? As2[sl] : As[sl];
    const unsigned char* BpL = lk ? Bs2[sl] : Bs[sl];
    #define LDF(base, rowb, s) (*(const i32x4*)((base) + (((s) << 11) + (rowb))))
    #define FRAG(dst, base, rowb) do {                  \
      i32x4 _lo = LDF(base, rowb, 0);                   \
      i32x4 _hi = LDF(base, rowb, 1);                   \
      dst[0]=_lo[0]; dst[1]=_lo[1]; dst[2]=_lo[2]; dst[3]=_lo[3]; \
      dst[4]=_hi[0]; dst[5]=_hi[1]; dst[6]=_hi[2]; dst[7]=_hi[3]; \
    } while (0)
    #define MFMA8(a, b, m, n) \
      acc[m][n] = __builtin_amdgcn_mfma_scale_f32_32x32x64_f8f6f4( \
          a, b, acc[m][n], 0, 0, 0, 127, 0, 127)

    i32x8 a0, a1, b0, b1;
    FRAG(a0, ApL, arow0); FRAG(a1, ApL, arow0 + 512);
    FRAG(b0, BpL, brow0); FRAG(b1, BpL, brow0 + 512);
    asm volatile("s_waitcnt lgkmcnt(0)" ::: "memory");
    __builtin_amdgcn_sched_barrier(0);
    __builtin_amdgcn_s_setprio(1);
    MFMA8(a0, b0, 0, 0); MFMA8(a0, b1, 0, 1);
    MFMA8(a1, b0, 1, 0); MFMA8(a1, b1, 1, 1);
    __builtin_amdgcn_s_setprio(0);
    #undef LDF
    #undef FRAG
    #undef MFMA8
  }
  #undef STAGE

  #pragma unroll
  for (int m = 0; m < 2; ++m) {
    const long rowb = Arow0 + wrow * 64 + m * 32;
    #pragma unroll
    for (int g4 = 0; g4 < 4; ++g4) {
      #pragma unroll
      for (int r4 = 0; r4 < 4; ++r4) {
        const long row = rowb + r4 + 8 * g4 + 4 * lk;
        unsigned short* cp = P + row * 512 + Brow0 + wcol * 64 + l31;
        float v0 = acc[m][0][g4 * 4 + r4];
        float v1 = acc[m][1][g4 * 4 + r4];
        if (accumulate) { v0 += bf2f(cp[0]); v1 += bf2f(cp[32]); }
        cp[0]  = f2bf(v0);
        cp[32] = f2bf(v1);
      }
    }
  }
}

// ---------------------------------------------------------------------------
// 5) row softmax (logits pre-assembled): single bf16 stream -> fp8 attn*448
__global__ __launch_bounds__(256) void softmax_rows_k(
    const unsigned short* __restrict__ L, unsigned char* __restrict__ Att)
{
  const int q = blockIdx.x;
  const unsigned short* row = L + (size_t)q * 3840;
  const int tid = threadIdx.x;
  float v[15];
  float mx = -1e30f;
  #pragma unroll
  for (int j = 0; j < 15; ++j) {
    int s = tid + j * 256;
    float x = (s < 3600) ? bf2f(row[s]) : -1e30f;
    v[j] = x;
    mx = fmaxf(mx, x);
  }
  #pragma unroll
  for (int o = 32; o > 0; o >>= 1) mx = fmaxf(mx, __shfl_xor(mx, o));
  __shared__ float wmax[4], wsum[4];
  if ((tid & 63) == 0) wmax[tid >> 6] = mx;
  __syncthreads();
  mx = fmaxf(fmaxf(wmax[0], wmax[1]), fmaxf(wmax[2], wmax[3]));
  float sum = 0.f;
  #pragma unroll
  for (int j = 0; j < 15; ++j) {
    int s = tid + j * 256;
    float e = (s < 3600) ? __expf(v[j] - mx) : 0.f;
    v[j] = e;
    sum += e;
  }
  #pragma unroll
  for (int o = 32; o > 0; o >>= 1) sum += __shfl_xor(sum, o);
  if ((tid & 63) == 0) wsum[tid >> 6] = sum;
  __syncthreads();
  sum = wsum[0] + wsum[1] + wsum[2] + wsum[3];
  const float inv448 = 448.0f / sum;
  #pragma unroll
  for (int j = 0; j < 15; ++j) {
    int s = tid + j * 256;
    unsigned char b = (s < 3600) ? f2e4m3(v[j] * inv448) : (unsigned char)0;
    Att[((size_t)(s >> 4) * 3840 + q) * 16 + (s & 15)] = b;
  }
}

// ---------------------------------------------------------------------------
// 6) out[c][p] = 0.5*f_q[c][p] + (0.25/448)*sum_z P[z][p][c]  (3 bf16 partials)
__global__ __launch_bounds__(256) void final_blend_k(
    const unsigned short* __restrict__ P, const float* __restrict__ fq,
    float* __restrict__ out)
{
  __shared__ float t[32][33];
  const int tx = threadIdx.x, ty = threadIdx.y;
  const int p0 = blockIdx.x * 32, c0 = blockIdx.y * 32;
  const long ZC = 3840L * 512;
  #pragma unroll
  for (int i = 0; i < 4; ++i) {
    int p = p0 + ty + i * 8, c = c0 + tx;
    float s = 0.f;
    if (p < 3600) {
      size_t o = (size_t)p * 512 + c;
      #pragma unroll
      for (int z = 0; z < 3; ++z) s += bf2f(P[o + (size_t)z * ZC]);
    }
    t[ty + i * 8][tx] = s;
  }
  __syncthreads();
  const float wts = 0.25f / 448.0f;
  #pragma unroll
  for (int i = 0; i < 4; ++i) {
    int c = c0 + ty + i * 8, p = p0 + tx;
    if (p < 3600) {
      size_t o = (size_t)c * 3600 + p;
      out[o] = 0.5f * fq[o] + wts * t[tx][ty + i * 8];
    }
  }
}

// ---------------------------------------------------------------------------
extern "C" void kernel_launch(void* const* d_in, const int* in_sizes, int n_in,
                              void* d_out, int out_size, void* d_ws, size_t ws_size,
                              hipStream_t stream) {
  const float* fq3 = (const float*)d_in[0];
  const float* fq4 = (const float*)d_in[1];
  const float* fs3 = (const float*)d_in[2];
  const float* fs4 = (const float*)d_in[3];
  const float* f_q = (const float*)d_in[4];
  const float* f_s = (const float*)d_in[5];
  const float* wch = (const float*)d_in[6];
  float* out = (float*)d_out;

  const size_t HW = 3600, MP = 3840, CH = 512;
  const size_t NG = 96;

  // workspace (~80 MB)
  unsigned char* QT4 = (unsigned char*)d_ws;          // (96, MP, 16B) fp4 query (raw)
  unsigned char* ST4 = QT4 + NG * MP * 16;            // (96, MP, 16B) fp4 support
  unsigned char* V8  = ST4 + NG * MP * 16;            // (MP/16, CH, 16B) fp8 V
  unsigned short* L  = (unsigned short*)(V8 + MP * CH);   // (MP,MP) bf16 LOGITS
  unsigned char* Att8 = (unsigned char*)(L + MP * MP);    // (MP/16, MP, 16B) fp8 attn*448
  unsigned short* Pb = (unsigned short*)(Att8 + MP * MP); // 3 x (MP,CH) bf16 partials
  float* invq4 = (float*)(Pb + 3 * MP * CH);          // 4 x 3600 norm inverses
  float* invq3 = invq4 + HW;
  float* invs4 = invq3 + HW;
  float* invs3 = invs4 + HW;
  float* partQ = invs3 + HW;                          // 96 x 3600
  float* partS = partQ + 96 * HW;                     // 96 x 3600

  dim3 tb(32, 8);
  tpose2_f4_k<<<dim3(113, 96), tb, 0, stream>>>(fq4, fq3, QT4, partQ);
  norm_fin_k<<<15, 256, 0, stream>>>(partQ, invq4, invq3);

  for (int b = 0; b < 2; ++b) {
    castv_f8_k<<<7200, 256, 0, stream>>>(f_s + (size_t)b * CH * HW, V8);
    tpose2_f4_k<<<dim3(113, 96), tb, 0, stream>>>(
        fs4 + (size_t)b * 2048 * HW, fs3 + (size_t)b * 1024 * HW, ST4, partS);
    norm_fin_k<<<15, 256, 0, stream>>>(partS, invs4, invs3);

    // one dual-level GEMM: logits assembled in the epilogue (bf16)
    gemm128_f4_dual<<<900, 256, 0, stream>>>(QT4, ST4, L, 3840, 3840, 30,
                                             invq4, invq3, invs4, invs3, wch);

    softmax_rows_k<<<3600, 256, 0, stream>>>(L, Att8);

    // PV split-K=3, deep-pipelined, XCD-chunked (360 blocks)
    pv_f8_k<<<360, 256, 0, stream>>>(Att8, V8, Pb, b);
  }

  final_blend_k<<<dim3(113, 16), tb, 0, stream>>>(Pb, f_q, out);
}

// Round 18
// 266.007 us; speedup vs baseline: 3.4325x; 3.4325x over previous
//
#include <hip/hip_runtime.h>
#include <cstdint>

#define TEMP_C 20.0f

typedef float f32x4 __attribute__((ext_vector_type(4)));
typedef float f32x16 __attribute__((ext_vector_type(16)));
typedef int i32x4 __attribute__((ext_vector_type(4)));
typedef int i32x8 __attribute__((ext_vector_type(8)));

// fp32 -> bf16 round-to-nearest-even
__device__ __forceinline__ unsigned short f2bf(float f) {
  union { float f; unsigned int u; } v; v.f = f;
  unsigned int r = v.u + 0x7FFFu + ((v.u >> 16) & 1u);
  return (unsigned short)(r >> 16);
}
__device__ __forceinline__ float bf2f(unsigned short b) {
  union { unsigned int u; float f; } v; v.u = ((unsigned int)b) << 16;
  return v.f;
}

// fp32 -> OCP e4m3fn, RTNE, clamp to +-448
__device__ __forceinline__ unsigned char f2e4m3(float f) {
  unsigned u = __float_as_uint(f);
  unsigned s = (u >> 24) & 0x80u;
  float a = fminf(fabsf(f), 448.0f);
  if (a < 0.015625f) {
    int d = (int)rintf(a * 512.0f);
    return (unsigned char)(s | (unsigned)d);
  }
  unsigned au = __float_as_uint(a);
  unsigned r = au + 0xFFFFFu + ((au >> 20) & 1u);
  int Ep = (int)(r >> 23) - 127;
  if (Ep > 8) return (unsigned char)(s | 0x7E);
  unsigned m = (r >> 20) & 7u;
  return (unsigned char)(s | ((unsigned)(Ep + 7) << 3) | m);
}

// fp32 -> e2m1 nibble (round to nearest of {0,.5,1,1.5,2,3,4,6}, sign bit3)
__device__ __forceinline__ unsigned f2e2m1(float f) {
  unsigned s = (__float_as_uint(f) >> 28) & 8u;
  float a = fabsf(f);
  unsigned n = (unsigned)(a >= 0.25f) + (a >= 0.75f) + (a >= 1.25f) +
               (a >= 1.75f) + (a >= 2.5f) + (a >= 3.5f) + (a >= 5.0f);
  return s | n;
}

// async global->LDS, 16B per lane (dest = wave-uniform base + lane*16)
__device__ __forceinline__ void gload_lds16(const void* g, void* l) {
  __builtin_amdgcn_global_load_lds(
      (__attribute__((address_space(1))) void*)(g),
      (__attribute__((address_space(3))) void*)(l), 16, 0, 0);
}

// ---------------------------------------------------------------------------
// 1) fused transpose + FP4 pack + per-(pixel, 32ch-group) sumsq partials.
//    K-GROUP-MAJOR fp4: group g = 32 channels = 16B; byte b = channels
//    2b,2b+1 (lo/hi nibble). T[(g*3840 + p)*16 + b]. Norms post-GEMM.
__global__ __launch_bounds__(256) void tpose2_f4_k(
    const float* __restrict__ X4, const float* __restrict__ X3,
    unsigned char* __restrict__ T, float* __restrict__ part)
{
  __shared__ float tile[32][33];
  __shared__ float red2[8][33];
  const int tx = threadIdx.x, ty = threadIdx.y;
  const int y = blockIdx.y;      // group index g == y (level4: 0..63, level3: 64..95)
  const float* X; int c0;
  if (y < 64) { X = X4; c0 = y * 32; }
  else        { X = X3; c0 = (y - 64) * 32; }
  const int p0 = blockIdx.x * 32;
  #pragma unroll
  for (int i = 0; i < 4; ++i) {
    int c = c0 + ty + i * 8, p = p0 + tx;
    tile[ty + i * 8][tx] = (p < 3600) ? X[(size_t)c * 3600 + p] : 0.f;
  }
  __syncthreads();
  {
    float s = 0.f;
    #pragma unroll
    for (int k = 0; k < 4; ++k) { float v = tile[ty * 4 + k][tx]; s += v * v; }
    red2[ty][tx] = s;
  }
  // fp4 write: threads tx<16 own byte b=tx (channels 2tx, 2tx+1)
  if (tx < 16) {
    const size_t gbase = (size_t)y * 3840 * 16 + tx;
    #pragma unroll
    for (int i = 0; i < 4; ++i) {
      int p = p0 + ty + i * 8;
      if (p < 3600) {
        unsigned lo = f2e2m1(tile[2 * tx][ty + i * 8]);
        unsigned hi = f2e2m1(tile[2 * tx + 1][ty + i * 8]);
        T[gbase + (size_t)p * 16] = (unsigned char)(lo | (hi << 4));
      }
    }
  }
  __syncthreads();
  if (ty == 0 && p0 + tx < 3600) {
    float s = 0.f;
    #pragma unroll
    for (int j = 0; j < 8; ++j) s += red2[j][tx];
    part[(size_t)y * 3600 + p0 + tx] = s;
  }
}

// 1b) finish: inv4[p] = 1/||x4_p||, inv3[p] = 1/||x3_p|| from 96 partials
__global__ __launch_bounds__(256) void norm_fin_k(
    const float* __restrict__ part, float* __restrict__ inv4,
    float* __restrict__ inv3)
{
  const int p = blockIdx.x * 256 + threadIdx.x;
  if (p >= 3600) return;
  float s4 = 0.f, s3 = 0.f;
  #pragma unroll
  for (int y = 0; y < 64; ++y) s4 += part[(size_t)y * 3600 + p];
  #pragma unroll
  for (int y = 64; y < 96; ++y) s3 += part[(size_t)y * 3600 + p];
  inv4[p] = 1.0f / fmaxf(sqrtf(s4), 1e-12f);
  inv3[p] = 1.0f / fmaxf(sqrtf(s3), 1e-12f);
}

// ---------------------------------------------------------------------------
// 2) V cast to fp8, K-group-major over s: V8[((s>>4)*512 + c)*16 + (s&15)]
__global__ void castv_f8_k(const float* __restrict__ X, unsigned char* __restrict__ V8)
{
  int i = blockIdx.x * 256 + threadIdx.x;
  if (i >= 512 * 3600) return;
  int c = i / 3600, s = i - c * 3600;
  V8[((size_t)(s >> 4) * 512 + c) * 16 + (s & 15)] = f2e4m3(X[i]);
}

// ---------------------------------------------------------------------------
// 3) 128x128 MX-FP4 GEMM (r15 verified: launch_bounds(256,4), acc=32 regs,
//    no spills). BK=128 fp4 elems (4 nibble-groups). Frag duplicated into
//    both operand halves. cbsz=blgp=4. Output bf16.
__global__ __launch_bounds__(256, 4) void gemm128_f4(
    const unsigned char* __restrict__ A, const unsigned char* __restrict__ B,
    unsigned short* __restrict__ C, int K, int MPr, int ldc, int nbn)
{
  __shared__ __align__(16) unsigned char As[2][8192];   // [4 g][128 rows][16B]
  __shared__ __align__(16) unsigned char Bs[2][8192];

  const int tid  = threadIdx.x;
  const int lane = tid & 63;
  const int wave = tid >> 6;
  const int wrow = wave >> 1;
  const int wcol = wave & 1;

  const int nwg = gridDim.x;
  const int q8 = nwg >> 3, r8 = nwg & 7;
  const int xcd = blockIdx.x & 7, bidx = blockIdx.x >> 3;
  const int wg = (xcd < r8 ? xcd * (q8 + 1) : r8 * (q8 + 1) + (xcd - r8) * q8) + bidx;
  const long Arow0 = (long)(wg / nbn) * 128;
  const long Brow0 = (long)(wg % nbn) * 128;

  const unsigned char* sA[2];
  const unsigned char* sB[2];
  #pragma unroll
  for (int q = 0; q < 2; ++q) {
    const int c = q * 256 + tid;
    const int g = c >> 7, r = c & 127;
    sA[q] = A + ((long)g * MPr + Arow0 + r) * 16;
    sB[q] = B + ((long)g * MPr + Brow0 + r) * 16;
  }
  const long kstride = (long)MPr * 16 * 4;   // 4 groups (=128 fp4 k) per tile

  #define STAGE(tt) do { const int _sl = (tt) & 1; const long _ko = (long)(tt) * kstride; \
    gload_lds16(sA[0] + _ko, &As[_sl][tid * 16]);              \
    gload_lds16(sA[1] + _ko, &As[_sl][(256 + tid) * 16]);      \
    gload_lds16(sB[0] + _ko, &Bs[_sl][tid * 16]);              \
    gload_lds16(sB[1] + _ko, &Bs[_sl][(256 + tid) * 16]);      \
  } while (0)

  const int l31 = lane & 31, lk = lane >> 5;
  const int arow0 = (wrow * 64 + l31) * 16;   // m=0; m=1 at +512 (32 rows)
  const int brow0 = (wcol * 64 + l31) * 16;

  f32x16 acc[2][2] = {};
  const int NT = K >> 7;   // 128 fp4 k per tile

  STAGE(0);

  for (int t = 0; t < NT; ++t) {
    const int sl = t & 1;
    if (t + 1 < NT) {
      STAGE(t + 1);
      asm volatile("s_waitcnt vmcnt(4)" ::: "memory");  // tile t landed; t+1 in flight
    } else {
      asm volatile("s_waitcnt vmcnt(0)" ::: "memory");
    }
    asm volatile("s_barrier" ::: "memory");

    const unsigned char* Ap = As[sl];
    const unsigned char* Bp = Bs[sl];
    // lane's group for k-half h: g = h*2 + lk; group stride 2048B
    #define FRAG4(dst, base, rowb, g) do {                       \
      i32x4 _v = *(const i32x4*)((base) + ((g) << 11) + (rowb)); \
      dst[0]=_v[0]; dst[1]=_v[1]; dst[2]=_v[2]; dst[3]=_v[3];    \
      dst[4]=_v[0]; dst[5]=_v[1]; dst[6]=_v[2]; dst[7]=_v[3];    \
    } while (0)
    #define MFMA4(a, b, m, n) \
      acc[m][n] = __builtin_amdgcn_mfma_scale_f32_32x32x64_f8f6f4( \
          a, b, acc[m][n], 4, 4, 0, 127, 0, 127)

    #pragma unroll
    for (int h = 0; h < 2; ++h) {
      const int g = h * 2 + lk;
      i32x8 a0, a1, b0, b1;
      FRAG4(a0, Ap, arow0, g); FRAG4(a1, Ap, arow0 + 512, g);
      FRAG4(b0, Bp, brow0, g); FRAG4(b1, Bp, brow0 + 512, g);
      __builtin_amdgcn_s_setprio(1);
      MFMA4(a0, b0, 0, 0); MFMA4(a0, b1, 0, 1);
      MFMA4(a1, b0, 1, 0); MFMA4(a1, b1, 1, 1);
      __builtin_amdgcn_s_setprio(0);
    }
    #undef FRAG4
    #undef MFMA4
    asm volatile("s_barrier" ::: "memory");
  }
  #undef STAGE

  // epilogue (bf16): col=lane&31, row = (reg&3) + 8*(reg>>2) + 4*(lane>>5)
  #pragma unroll
  for (int m = 0; m < 2; ++m) {
    const long rowb = Arow0 + wrow * 64 + m * 32;
    #pragma unroll
    for (int g4 = 0; g4 < 4; ++g4) {
      #pragma unroll
      for (int r4 = 0; r4 < 4; ++r4) {
        const long row = rowb + r4 + 8 * g4 + 4 * lk;
        unsigned short* cp = C + row * (long)ldc + Brow0 + wcol * 64 + l31;
        cp[0]  = f2bf(acc[m][0][g4 * 4 + r4]);
        cp[32] = f2bf(acc[m][1][g4 * 4 + r4]);
      }
    }
  }
}

// ---------------------------------------------------------------------------
// 4) PV MX-fp8 GEMM, deep-pipelined (r14 verified, unchanged).
__global__ __launch_bounds__(256, 2) void pv_f8_k(
    const unsigned char* __restrict__ Att, const unsigned char* __restrict__ V,
    unsigned short* __restrict__ P, int accumulate)
{
  __shared__ __align__(16) unsigned char As[4][4096];
  __shared__ __align__(16) unsigned char As2[4][4096];
  __shared__ __align__(16) unsigned char Bs[4][4096];
  __shared__ __align__(16) unsigned char Bs2[4][4096];

  const int tid  = threadIdx.x;
  const int lane = tid & 63;
  const int wave = tid >> 6;
  const int wrow = wave >> 1;
  const int wcol = wave & 1;

  const int xcd = blockIdx.x & 7, bidx = blockIdx.x >> 3;
  const int wg = xcd * 45 + bidx;
  const int x = wg / 12, rem = wg % 12;
  const int y = rem & 3, z = rem >> 2;
  const long Arow0 = (long)x * 128;
  const long Brow0 = (long)y * 128;
  P += (long)z * 3840 * 512;

  const unsigned char* sA[2];
  const unsigned char* sB[2];
  #pragma unroll
  for (int q = 0; q < 2; ++q) {
    const int c = q * 256 + tid;
    const int g = c >> 7, r = c & 127;
    sA[q] = Att + ((long)(z * 80 + g) * 3840 + Arow0 + r) * 16;
    sB[q] = V   + ((long)(z * 80 + g) * 512  + Brow0 + r) * 16;
  }
  const long ksA = 3840L * 16 * 4;
  const long ksB = 512L * 16 * 4;

  #define STAGE(tt) do { const int _sl = (tt) & 3;                      \
    gload_lds16(sA[0] + (long)(tt) * ksA, &As[_sl][tid * 16]);          \
    gload_lds16(sA[1] + (long)(tt) * ksA, &As2[_sl][tid * 16]);         \
    gload_lds16(sB[0] + (long)(tt) * ksB, &Bs[_sl][tid * 16]);          \
    gload_lds16(sB[1] + (long)(tt) * ksB, &Bs2[_sl][tid * 16]);         \
  } while (0)

  const int l31 = lane & 31, lk = lane >> 5;
  const int arow0 = (wrow * 64 + l31) * 16;
  const int brow0 = (wcol * 64 + l31) * 16;

  f32x16 acc[2][2] = {};
  const int NT = 20;

  STAGE(0); STAGE(1); STAGE(2);

  for (int t = 0; t < NT; ++t) {
    const int sl = t & 3;
    const int rem_t = NT - 1 - t;
    if (rem_t >= 2)      asm volatile("s_waitcnt vmcnt(8)" ::: "memory");
    else if (rem_t == 1) asm volatile("s_waitcnt vmcnt(4)" ::: "memory");
    else                 asm volatile("s_waitcnt vmcnt(0)" ::: "memory");
    asm volatile("s_barrier" ::: "memory");
    if (t + 3 < NT) STAGE(t + 3);

    const unsigned char* ApL = lk ? As2[sl] : As[sl];
    const unsigned char* BpL = lk ? Bs2[sl] : Bs[sl];
    #define LDF(base, rowb, s) (*(const i32x4*)((base) + (((s) << 11) + (rowb))))
    #define FRAG(dst, base, rowb) do {                  \
      i32x4 _lo = LDF(base, rowb, 0);                   \
      i32x4 _hi = LDF(base, rowb, 1);                   \
      dst[0]=_lo[0]; dst[1]=_lo[1]; dst[2]=_lo[2]; dst[3]=_lo[3]; \
      dst[4]=_hi[0]; dst[5]=_hi[1]; dst[6]=_hi[2]; dst[7]=_hi[3]; \
    } while (0)
    #define MFMA8(a, b, m, n) \
      acc[m][n] = __builtin_amdgcn_mfma_scale_f32_32x32x64_f8f6f4( \
          a, b, acc[m][n], 0, 0, 0, 127, 0, 127)

    i32x8 a0, a1, b0, b1;
    FRAG(a0, ApL, arow0); FRAG(a1, ApL, arow0 + 512);
    FRAG(b0, BpL, brow0); FRAG(b1, BpL, brow0 + 512);
    asm volatile("s_waitcnt lgkmcnt(0)" ::: "memory");
    __builtin_amdgcn_sched_barrier(0);
    __builtin_amdgcn_s_setprio(1);
    MFMA8(a0, b0, 0, 0); MFMA8(a0, b1, 0, 1);
    MFMA8(a1, b0, 1, 0); MFMA8(a1, b1, 1, 1);
    __builtin_amdgcn_s_setprio(0);
    #undef LDF
    #undef FRAG
    #undef MFMA8
  }
  #undef STAGE

  #pragma unroll
  for (int m = 0; m < 2; ++m) {
    const long rowb = Arow0 + wrow * 64 + m * 32;
    #pragma unroll
    for (int g4 = 0; g4 < 4; ++g4) {
      #pragma unroll
      for (int r4 = 0; r4 < 4; ++r4) {
        const long row = rowb + r4 + 8 * g4 + 4 * lk;
        unsigned short* cp = P + row * 512 + Brow0 + wcol * 64 + l31;
        float v0 = acc[m][0][g4 * 4 + r4];
        float v1 = acc[m][1][g4 * 4 + r4];
        if (accumulate) { v0 += bf2f(cp[0]); v1 += bf2f(cp[32]); }
        cp[0]  = f2bf(v0);
        cp[32] = f2bf(v1);
      }
    }
  }
}

// ---------------------------------------------------------------------------
// 5) row softmax with POST-GEMM norm application -> fp8 attn*448, K-group-major
__global__ __launch_bounds__(256) void softmax_rows_k(
    const unsigned short* __restrict__ L4, const unsigned short* __restrict__ L3,
    const float* __restrict__ invq4, const float* __restrict__ invq3,
    const float* __restrict__ invs4, const float* __restrict__ invs3,
    const float* __restrict__ wch, unsigned char* __restrict__ Att)
{
  const int q = blockIdx.x;
  const unsigned short* r4 = L4 + (size_t)q * 3840;
  const unsigned short* r3 = L3 + (size_t)q * 3840;
  const float c4 = TEMP_C * wch[0] * invq4[q];
  const float c3 = TEMP_C * wch[1] * invq3[q];
  const int tid = threadIdx.x;
  float v[15];
  float mx = -1e30f;
  #pragma unroll
  for (int j = 0; j < 15; ++j) {
    int s = tid + j * 256;
    float x = -1e30f;
    if (s < 3600)
      x = c4 * bf2f(r4[s]) * invs4[s] + c3 * bf2f(r3[s]) * invs3[s];
    v[j] = x;
    mx = fmaxf(mx, x);
  }
  #pragma unroll
  for (int o = 32; o > 0; o >>= 1) mx = fmaxf(mx, __shfl_xor(mx, o));
  __shared__ float wmax[4], wsum[4];
  if ((tid & 63) == 0) wmax[tid >> 6] = mx;
  __syncthreads();
  mx = fmaxf(fmaxf(wmax[0], wmax[1]), fmaxf(wmax[2], wmax[3]));
  float sum = 0.f;
  #pragma unroll
  for (int j = 0; j < 15; ++j) {
    int s = tid + j * 256;
    float e = (s < 3600) ? __expf(v[j] - mx) : 0.f;
    v[j] = e;
    sum += e;
  }
  #pragma unroll
  for (int o = 32; o > 0; o >>= 1) sum += __shfl_xor(sum, o);
  if ((tid & 63) == 0) wsum[tid >> 6] = sum;
  __syncthreads();
  sum = wsum[0] + wsum[1] + wsum[2] + wsum[3];
  const float inv448 = 448.0f / sum;
  #pragma unroll
  for (int j = 0; j < 15; ++j) {
    int s = tid + j * 256;
    unsigned char b = (s < 3600) ? f2e4m3(v[j] * inv448) : (unsigned char)0;
    Att[((size_t)(s >> 4) * 3840 + q) * 16 + (s & 15)] = b;
  }
}

// ---------------------------------------------------------------------------
// 6) out[c][p] = 0.5*f_q[c][p] + (0.25/448)*sum_z P[z][p][c]  (3 bf16 partials)
__global__ __launch_bounds__(256) void final_blend_k(
    const unsigned short* __restrict__ P, const float* __restrict__ fq,
    float* __restrict__ out)
{
  __shared__ float t[32][33];
  const int tx = threadIdx.x, ty = threadIdx.y;
  const int p0 = blockIdx.x * 32, c0 = blockIdx.y * 32;
  const long ZC = 3840L * 512;
  #pragma unroll
  for (int i = 0; i < 4; ++i) {
    int p = p0 + ty + i * 8, c = c0 + tx;
    float s = 0.f;
    if (p < 3600) {
      size_t o = (size_t)p * 512 + c;
      #pragma unroll
      for (int z = 0; z < 3; ++z) s += bf2f(P[o + (size_t)z * ZC]);
    }
    t[ty + i * 8][tx] = s;
  }
  __syncthreads();
  const float wts = 0.25f / 448.0f;
  #pragma unroll
  for (int i = 0; i < 4; ++i) {
    int c = c0 + ty + i * 8, p = p0 + tx;
    if (p < 3600) {
      size_t o = (size_t)c * 3600 + p;
      out[o] = 0.5f * fq[o] + wts * t[tx][ty + i * 8];
    }
  }
}

// ---------------------------------------------------------------------------
extern "C" void kernel_launch(void* const* d_in, const int* in_sizes, int n_in,
                              void* d_out, int out_size, void* d_ws, size_t ws_size,
                              hipStream_t stream) {
  const float* fq3 = (const float*)d_in[0];
  const float* fq4 = (const float*)d_in[1];
  const float* fs3 = (const float*)d_in[2];
  const float* fs4 = (const float*)d_in[3];
  const float* f_q = (const float*)d_in[4];
  const float* f_s = (const float*)d_in[5];
  const float* wch = (const float*)d_in[6];
  float* out = (float*)d_out;

  const size_t HW = 3600, MP = 3840, CH = 512;
  const size_t NG = 96;            // fp4 k-groups (32 ch each) across both levels

  // workspace (~108 MB)
  unsigned char* QT4 = (unsigned char*)d_ws;          // (96, MP, 16B) fp4 query (raw)
  unsigned char* ST4 = QT4 + NG * MP * 16;            // (96, MP, 16B) fp4 support
  unsigned char* V8  = ST4 + NG * MP * 16;            // (MP/16, CH, 16B) fp8 V
  unsigned short* L4 = (unsigned short*)(V8 + MP * CH);   // (MP,MP) bf16 level-4 dots
  unsigned short* L3 = L4 + MP * MP;                  // (MP,MP) bf16 level-3 dots
  unsigned char* Att8 = (unsigned char*)(L3 + MP * MP);   // (MP/16, MP, 16B) fp8 attn*448
  unsigned short* Pb = (unsigned short*)(Att8 + MP * MP); // 3 x (MP,CH) bf16 partials
  float* invq4 = (float*)(Pb + 3 * MP * CH);          // 4 x 3600 norm inverses
  float* invq3 = invq4 + HW;
  float* invs4 = invq3 + HW;
  float* invs3 = invs4 + HW;
  float* partQ = invs3 + HW;                          // 96 x 3600
  float* partS = partQ + 96 * HW;                     // 96 x 3600

  dim3 tb(32, 8);
  tpose2_f4_k<<<dim3(113, 96), tb, 0, stream>>>(fq4, fq3, QT4, partQ);
  norm_fin_k<<<15, 256, 0, stream>>>(partQ, invq4, invq3);

  const long G4OFF = 64L * MP * 16;   // byte offset of group 64 (level-3 cols)

  for (int b = 0; b < 2; ++b) {
    castv_f8_k<<<7200, 256, 0, stream>>>(f_s + (size_t)b * CH * HW, V8);
    tpose2_f4_k<<<dim3(113, 96), tb, 0, stream>>>(
        fs4 + (size_t)b * 2048 * HW, fs3 + (size_t)b * 1024 * HW, ST4, partS);
    norm_fin_k<<<15, 256, 0, stream>>>(partS, invs4, invs3);

    // raw dot products per level (bf16), MX-fp4: K counts fp4 elements
    gemm128_f4<<<900, 256, 0, stream>>>(QT4, ST4, L4, 2048, 3840, 3840, 30);
    gemm128_f4<<<900, 256, 0, stream>>>(QT4 + G4OFF, ST4 + G4OFF, L3, 1024, 3840, 3840, 30);

    softmax_rows_k<<<3600, 256, 0, stream>>>(L4, L3, invq4, invq3, invs4, invs3,
                                             wch, Att8);

    // PV split-K=3, deep-pipelined, XCD-chunked (360 blocks)
    pv_f8_k<<<360, 256, 0, stream>>>(Att8, V8, Pb, b);
  }

  final_blend_k<<<dim3(113, 16), tb, 0, stream>>>(Pb, f_q, out);
}

// Round 19
// 249.776 us; speedup vs baseline: 3.6556x; 1.0650x over previous
//
#include <hip/hip_runtime.h>
#include <cstdint>

#define TEMP_C 20.0f

typedef float f32x4 __attribute__((ext_vector_type(4)));
typedef float f32x16 __attribute__((ext_vector_type(16)));
typedef int i32x4 __attribute__((ext_vector_type(4)));
typedef int i32x8 __attribute__((ext_vector_type(8)));

// fp32 -> bf16 round-to-nearest-even
__device__ __forceinline__ unsigned short f2bf(float f) {
  union { float f; unsigned int u; } v; v.f = f;
  unsigned int r = v.u + 0x7FFFu + ((v.u >> 16) & 1u);
  return (unsigned short)(r >> 16);
}
__device__ __forceinline__ float bf2f(unsigned short b) {
  union { unsigned int u; float f; } v; v.u = ((unsigned int)b) << 16;
  return v.f;
}

// fp32 -> OCP e4m3fn, RTNE, clamp to +-448
__device__ __forceinline__ unsigned char f2e4m3(float f) {
  unsigned u = __float_as_uint(f);
  unsigned s = (u >> 24) & 0x80u;
  float a = fminf(fabsf(f), 448.0f);
  if (a < 0.015625f) {
    int d = (int)rintf(a * 512.0f);
    return (unsigned char)(s | (unsigned)d);
  }
  unsigned au = __float_as_uint(a);
  unsigned r = au + 0xFFFFFu + ((au >> 20) & 1u);
  int Ep = (int)(r >> 23) - 127;
  if (Ep > 8) return (unsigned char)(s | 0x7E);
  unsigned m = (r >> 20) & 7u;
  return (unsigned char)(s | ((unsigned)(Ep + 7) << 3) | m);
}

// fp32 -> e2m1 nibble (round to nearest of {0,.5,1,1.5,2,3,4,6}, sign bit3)
__device__ __forceinline__ unsigned f2e2m1(float f) {
  unsigned s = (__float_as_uint(f) >> 28) & 8u;
  float a = fabsf(f);
  unsigned n = (unsigned)(a >= 0.25f) + (a >= 0.75f) + (a >= 1.25f) +
               (a >= 1.75f) + (a >= 2.5f) + (a >= 3.5f) + (a >= 5.0f);
  return s | n;
}

// async global->LDS, 16B per lane (dest = wave-uniform base + lane*16)
__device__ __forceinline__ void gload_lds16(const void* g, void* l) {
  __builtin_amdgcn_global_load_lds(
      (__attribute__((address_space(1))) void*)(g),
      (__attribute__((address_space(3))) void*)(l), 16, 0, 0);
}

// ---------------------------------------------------------------------------
// 1) fused transpose + FP4 pack + per-(pixel, 32ch-group) sumsq partials.
//    blockIdx.z = batch (strides 0 for the query launch).
__global__ __launch_bounds__(256) void tpose2_f4_k(
    const float* __restrict__ X4, const float* __restrict__ X3,
    unsigned char* __restrict__ T, float* __restrict__ part,
    long sX4, long sX3, long sT, long sPart)
{
  const int b = blockIdx.z;
  X4 += (long)b * sX4; X3 += (long)b * sX3;
  T  += (long)b * sT;  part += (long)b * sPart;
  __shared__ float tile[32][33];
  __shared__ float red2[8][33];
  const int tx = threadIdx.x, ty = threadIdx.y;
  const int y = blockIdx.y;      // group g (level4: 0..63, level3: 64..95)
  const float* X; int c0;
  if (y < 64) { X = X4; c0 = y * 32; }
  else        { X = X3; c0 = (y - 64) * 32; }
  const int p0 = blockIdx.x * 32;
  #pragma unroll
  for (int i = 0; i < 4; ++i) {
    int c = c0 + ty + i * 8, p = p0 + tx;
    tile[ty + i * 8][tx] = (p < 3600) ? X[(size_t)c * 3600 + p] : 0.f;
  }
  __syncthreads();
  {
    float s = 0.f;
    #pragma unroll
    for (int k = 0; k < 4; ++k) { float v = tile[ty * 4 + k][tx]; s += v * v; }
    red2[ty][tx] = s;
  }
  if (tx < 16) {
    const size_t gbase = (size_t)y * 3840 * 16 + tx;
    #pragma unroll
    for (int i = 0; i < 4; ++i) {
      int p = p0 + ty + i * 8;
      if (p < 3600) {
        unsigned lo = f2e2m1(tile[2 * tx][ty + i * 8]);
        unsigned hi = f2e2m1(tile[2 * tx + 1][ty + i * 8]);
        T[gbase + (size_t)p * 16] = (unsigned char)(lo | (hi << 4));
      }
    }
  }
  __syncthreads();
  if (ty == 0 && p0 + tx < 3600) {
    float s = 0.f;
    #pragma unroll
    for (int j = 0; j < 8; ++j) s += red2[j][tx];
    part[(size_t)y * 3600 + p0 + tx] = s;
  }
}

// 1b) finish norms; blockIdx.y = batch (strides 0 for query launch)
__global__ __launch_bounds__(256) void norm_fin_k(
    const float* __restrict__ part, float* __restrict__ inv4,
    float* __restrict__ inv3, long sPart, long sInv)
{
  const int b = blockIdx.y;
  part += (long)b * sPart; inv4 += (long)b * sInv; inv3 += (long)b * sInv;
  const int p = blockIdx.x * 256 + threadIdx.x;
  if (p >= 3600) return;
  float s4 = 0.f, s3 = 0.f;
  #pragma unroll
  for (int y = 0; y < 64; ++y) s4 += part[(size_t)y * 3600 + p];
  #pragma unroll
  for (int y = 64; y < 96; ++y) s3 += part[(size_t)y * 3600 + p];
  inv4[p] = 1.0f / fmaxf(sqrtf(s4), 1e-12f);
  inv3[p] = 1.0f / fmaxf(sqrtf(s3), 1e-12f);
}

// ---------------------------------------------------------------------------
// 2) V cast to fp8, K-group-major; blockIdx.y = batch
__global__ void castv_f8_k(const float* __restrict__ X, unsigned char* __restrict__ V8,
                           long sX, long sV)
{
  const int b = blockIdx.y;
  X += (long)b * sX; V8 += (long)b * sV;
  int i = blockIdx.x * 256 + threadIdx.x;
  if (i >= 512 * 3600) return;
  int c = i / 3600, s = i - c * 3600;
  V8[((size_t)(s >> 4) * 512 + c) * 16 + (s & 15)] = f2e4m3(X[i]);
}

// ---------------------------------------------------------------------------
// 3) 128x128 MX-FP4 GEMM (r15-verified structure); blockIdx.z = batch.
//    A (query) shared across batches (sA_b = 0 from host).
__global__ __launch_bounds__(256, 4) void gemm128_f4(
    const unsigned char* __restrict__ A, const unsigned char* __restrict__ B,
    unsigned short* __restrict__ C, int K, int MPr, int ldc, int nbn,
    long sB_b, long sC_b)
{
  const int bz = blockIdx.z;
  B += (long)bz * sB_b;
  C += (long)bz * sC_b;
  __shared__ __align__(16) unsigned char As[2][8192];   // [4 g][128 rows][16B]
  __shared__ __align__(16) unsigned char Bs[2][8192];

  const int tid  = threadIdx.x;
  const int lane = tid & 63;
  const int wave = tid >> 6;
  const int wrow = wave >> 1;
  const int wcol = wave & 1;

  const int nwg = gridDim.x;
  const int q8 = nwg >> 3, r8 = nwg & 7;
  const int xcd = blockIdx.x & 7, bidx = blockIdx.x >> 3;
  const int wg = (xcd < r8 ? xcd * (q8 + 1) : r8 * (q8 + 1) + (xcd - r8) * q8) + bidx;
  const long Arow0 = (long)(wg / nbn) * 128;
  const long Brow0 = (long)(wg % nbn) * 128;

  const unsigned char* sA[2];
  const unsigned char* sB[2];
  #pragma unroll
  for (int q = 0; q < 2; ++q) {
    const int c = q * 256 + tid;
    const int g = c >> 7, r = c & 127;
    sA[q] = A + ((long)g * MPr + Arow0 + r) * 16;
    sB[q] = B + ((long)g * MPr + Brow0 + r) * 16;
  }
  const long kstride = (long)MPr * 16 * 4;   // 4 groups (=128 fp4 k) per tile

  #define STAGE(tt) do { const int _sl = (tt) & 1; const long _ko = (long)(tt) * kstride; \
    gload_lds16(sA[0] + _ko, &As[_sl][tid * 16]);              \
    gload_lds16(sA[1] + _ko, &As[_sl][(256 + tid) * 16]);      \
    gload_lds16(sB[0] + _ko, &Bs[_sl][tid * 16]);              \
    gload_lds16(sB[1] + _ko, &Bs[_sl][(256 + tid) * 16]);      \
  } while (0)

  const int l31 = lane & 31, lk = lane >> 5;
  const int arow0 = (wrow * 64 + l31) * 16;   // m=0; m=1 at +512 (32 rows)
  const int brow0 = (wcol * 64 + l31) * 16;

  f32x16 acc[2][2] = {};
  const int NT = K >> 7;   // 128 fp4 k per tile

  STAGE(0);

  for (int t = 0; t < NT; ++t) {
    const int sl = t & 1;
    if (t + 1 < NT) {
      STAGE(t + 1);
      asm volatile("s_waitcnt vmcnt(4)" ::: "memory");
    } else {
      asm volatile("s_waitcnt vmcnt(0)" ::: "memory");
    }
    asm volatile("s_barrier" ::: "memory");

    const unsigned char* Ap = As[sl];
    const unsigned char* Bp = Bs[sl];
    #define FRAG4(dst, base, rowb, g) do {                       \
      i32x4 _v = *(const i32x4*)((base) + ((g) << 11) + (rowb)); \
      dst[0]=_v[0]; dst[1]=_v[1]; dst[2]=_v[2]; dst[3]=_v[3];    \
      dst[4]=_v[0]; dst[5]=_v[1]; dst[6]=_v[2]; dst[7]=_v[3];    \
    } while (0)
    #define MFMA4(a, b, m, n) \
      acc[m][n] = __builtin_amdgcn_mfma_scale_f32_32x32x64_f8f6f4( \
          a, b, acc[m][n], 4, 4, 0, 127, 0, 127)

    #pragma unroll
    for (int h = 0; h < 2; ++h) {
      const int g = h * 2 + lk;
      i32x8 a0, a1, b0, b1;
      FRAG4(a0, Ap, arow0, g); FRAG4(a1, Ap, arow0 + 512, g);
      FRAG4(b0, Bp, brow0, g); FRAG4(b1, Bp, brow0 + 512, g);
      __builtin_amdgcn_s_setprio(1);
      MFMA4(a0, b0, 0, 0); MFMA4(a0, b1, 0, 1);
      MFMA4(a1, b0, 1, 0); MFMA4(a1, b1, 1, 1);
      __builtin_amdgcn_s_setprio(0);
    }
    #undef FRAG4
    #undef MFMA4
    asm volatile("s_barrier" ::: "memory");
  }
  #undef STAGE

  // epilogue (bf16): col=lane&31, row = (reg&3) + 8*(reg>>2) + 4*(lane>>5)
  #pragma unroll
  for (int m = 0; m < 2; ++m) {
    const long rowb = Arow0 + wrow * 64 + m * 32;
    #pragma unroll
    for (int g4 = 0; g4 < 4; ++g4) {
      #pragma unroll
      for (int r4 = 0; r4 < 4; ++r4) {
        const long row = rowb + r4 + 8 * g4 + 4 * lk;
        unsigned short* cp = C + row * (long)ldc + Brow0 + wcol * 64 + l31;
        cp[0]  = f2bf(acc[m][0][g4 * 4 + r4]);
        cp[32] = f2bf(acc[m][1][g4 * 4 + r4]);
      }
    }
  }
}

// ---------------------------------------------------------------------------
// 4) PV MX-fp8 GEMM, deep-pipelined (r14 verified). blockIdx.y = batch;
//    partials indexed [batch*3 + z] so batches never touch the same memory
//    (accumulate dependency removed -> batches run concurrently).
__global__ __launch_bounds__(256, 2) void pv_f8_k(
    const unsigned char* __restrict__ Att, const unsigned char* __restrict__ V,
    unsigned short* __restrict__ P, long sAtt, long sV)
{
  const int bb = blockIdx.y;
  Att += (long)bb * sAtt;
  V   += (long)bb * sV;
  __shared__ __align__(16) unsigned char As[4][4096];
  __shared__ __align__(16) unsigned char As2[4][4096];
  __shared__ __align__(16) unsigned char Bs[4][4096];
  __shared__ __align__(16) unsigned char Bs2[4][4096];

  const int tid  = threadIdx.x;
  const int lane = tid & 63;
  const int wave = tid >> 6;
  const int wrow = wave >> 1;
  const int wcol = wave & 1;

  const int xcd = blockIdx.x & 7, bidx = blockIdx.x >> 3;
  const int wg = xcd * 45 + bidx;
  const int x = wg / 12, rem = wg % 12;
  const int y = rem & 3, z = rem >> 2;
  const long Arow0 = (long)x * 128;
  const long Brow0 = (long)y * 128;
  P += (long)(bb * 3 + z) * 3840 * 512;

  const unsigned char* sA[2];
  const unsigned char* sB[2];
  #pragma unroll
  for (int q = 0; q < 2; ++q) {
    const int c = q * 256 + tid;
    const int g = c >> 7, r = c & 127;
    sA[q] = Att + ((long)(z * 80 + g) * 3840 + Arow0 + r) * 16;
    sB[q] = V   + ((long)(z * 80 + g) * 512  + Brow0 + r) * 16;
  }
  const long ksA = 3840L * 16 * 4;
  const long ksB = 512L * 16 * 4;

  #define STAGE(tt) do { const int _sl = (tt) & 3;                      \
    gload_lds16(sA[0] + (long)(tt) * ksA, &As[_sl][tid * 16]);          \
    gload_lds16(sA[1] + (long)(tt) * ksA, &As2[_sl][tid * 16]);         \
    gload_lds16(sB[0] + (long)(tt) * ksB, &Bs[_sl][tid * 16]);          \
    gload_lds16(sB[1] + (long)(tt) * ksB, &Bs2[_sl][tid * 16]);         \
  } while (0)

  const int l31 = lane & 31, lk = lane >> 5;
  const int arow0 = (wrow * 64 + l31) * 16;
  const int brow0 = (wcol * 64 + l31) * 16;

  f32x16 acc[2][2] = {};
  const int NT = 20;

  STAGE(0); STAGE(1); STAGE(2);

  for (int t = 0; t < NT; ++t) {
    const int sl = t & 3;
    const int rem_t = NT - 1 - t;
    if (rem_t >= 2)      asm volatile("s_waitcnt vmcnt(8)" ::: "memory");
    else if (rem_t == 1) asm volatile("s_waitcnt vmcnt(4)" ::: "memory");
    else                 asm volatile("s_waitcnt vmcnt(0)" ::: "memory");
    asm volatile("s_barrier" ::: "memory");
    if (t + 3 < NT) STAGE(t + 3);

    const unsigned char* ApL = lk ? As2[sl] : As[sl];
    const unsigned char* BpL = lk ? Bs2[sl] : Bs[sl];
    #define LDF(base, rowb, s) (*(const i32x4*)((base) + (((s) << 11) + (rowb))))
    #define FRAG(dst, base, rowb) do {                  \
      i32x4 _lo = LDF(base, rowb, 0);                   \
      i32x4 _hi = LDF(base, rowb, 1);                   \
      dst[0]=_lo[0]; dst[1]=_lo[1]; dst[2]=_lo[2]; dst[3]=_lo[3]; \
      dst[4]=_hi[0]; dst[5]=_hi[1]; dst[6]=_hi[2]; dst[7]=_hi[3]; \
    } while (0)
    #define MFMA8(a, b, m, n) \
      acc[m][n] = __builtin_amdgcn_mfma_scale_f32_32x32x64_f8f6f4( \
          a, b, acc[m][n], 0, 0, 0, 127, 0, 127)

    i32x8 a0, a1, b0, b1;
    FRAG(a0, ApL, arow0); FRAG(a1, ApL, arow0 + 512);
    FRAG(b0, BpL, brow0); FRAG(b1, BpL, brow0 + 512);
    asm volatile("s_waitcnt lgkmcnt(0)" ::: "memory");
    __builtin_amdgcn_sched_barrier(0);
    __builtin_amdgcn_s_setprio(1);
    MFMA8(a0, b0, 0, 0); MFMA8(a0, b1, 0, 1);
    MFMA8(a1, b0, 1, 0); MFMA8(a1, b1, 1, 1);
    __builtin_amdgcn_s_setprio(0);
    #undef LDF
    #undef FRAG
    #undef MFMA8
  }
  #undef STAGE

  #pragma unroll
  for (int m = 0; m < 2; ++m) {
    const long rowb = Arow0 + wrow * 64 + m * 32;
    #pragma unroll
    for (int g4 = 0; g4 < 4; ++g4) {
      #pragma unroll
      for (int r4 = 0; r4 < 4; ++r4) {
        const long row = rowb + r4 + 8 * g4 + 4 * lk;
        unsigned short* cp = P + row * 512 + Brow0 + wcol * 64 + l31;
        cp[0]  = f2bf(acc[m][0][g4 * 4 + r4]);
        cp[32] = f2bf(acc[m][1][g4 * 4 + r4]);
      }
    }
  }
}

// ---------------------------------------------------------------------------
// 5) row softmax with POST-GEMM norm application; blockIdx.y = batch
__global__ __launch_bounds__(256) void softmax_rows_k(
    const unsigned short* __restrict__ L4, const unsigned short* __restrict__ L3,
    const float* __restrict__ invq4, const float* __restrict__ invq3,
    const float* __restrict__ invs4, const float* __restrict__ invs3,
    const float* __restrict__ wch, unsigned char* __restrict__ Att,
    long sL, long sInv, long sAtt)
{
  const int b = blockIdx.y;
  L4 += (long)b * sL; L3 += (long)b * sL;
  invs4 += (long)b * sInv; invs3 += (long)b * sInv;
  Att += (long)b * sAtt;
  const int q = blockIdx.x;
  const unsigned short* r4 = L4 + (size_t)q * 3840;
  const unsigned short* r3 = L3 + (size_t)q * 3840;
  const float c4 = TEMP_C * wch[0] * invq4[q];
  const float c3 = TEMP_C * wch[1] * invq3[q];
  const int tid = threadIdx.x;
  float v[15];
  float mx = -1e30f;
  #pragma unroll
  for (int j = 0; j < 15; ++j) {
    int s = tid + j * 256;
    float x = -1e30f;
    if (s < 3600)
      x = c4 * bf2f(r4[s]) * invs4[s] + c3 * bf2f(r3[s]) * invs3[s];
    v[j] = x;
    mx = fmaxf(mx, x);
  }
  #pragma unroll
  for (int o = 32; o > 0; o >>= 1) mx = fmaxf(mx, __shfl_xor(mx, o));
  __shared__ float wmax[4], wsum[4];
  if ((tid & 63) == 0) wmax[tid >> 6] = mx;
  __syncthreads();
  mx = fmaxf(fmaxf(wmax[0], wmax[1]), fmaxf(wmax[2], wmax[3]));
  float sum = 0.f;
  #pragma unroll
  for (int j = 0; j < 15; ++j) {
    int s = tid + j * 256;
    float e = (s < 3600) ? __expf(v[j] - mx) : 0.f;
    v[j] = e;
    sum += e;
  }
  #pragma unroll
  for (int o = 32; o > 0; o >>= 1) sum += __shfl_xor(sum, o);
  if ((tid & 63) == 0) wsum[tid >> 6] = sum;
  __syncthreads();
  sum = wsum[0] + wsum[1] + wsum[2] + wsum[3];
  const float inv448 = 448.0f / sum;
  #pragma unroll
  for (int j = 0; j < 15; ++j) {
    int s = tid + j * 256;
    unsigned char bb = (s < 3600) ? f2e4m3(v[j] * inv448) : (unsigned char)0;
    Att[((size_t)(s >> 4) * 3840 + q) * 16 + (s & 15)] = bb;
  }
}

// ---------------------------------------------------------------------------
// 6) out[c][p] = 0.5*f_q[c][p] + (0.25/448)*sum_{z=0..5} P[z][p][c]
__global__ __launch_bounds__(256) void final_blend_k(
    const unsigned short* __restrict__ P, const float* __restrict__ fq,
    float* __restrict__ out)
{
  __shared__ float t[32][33];
  const int tx = threadIdx.x, ty = threadIdx.y;
  const int p0 = blockIdx.x * 32, c0 = blockIdx.y * 32;
  const long ZC = 3840L * 512;
  #pragma unroll
  for (int i = 0; i < 4; ++i) {
    int p = p0 + ty + i * 8, c = c0 + tx;
    float s = 0.f;
    if (p < 3600) {
      size_t o = (size_t)p * 512 + c;
      #pragma unroll
      for (int z = 0; z < 6; ++z) s += bf2f(P[o + (size_t)z * ZC]);
    }
    t[ty + i * 8][tx] = s;
  }
  __syncthreads();
  const float wts = 0.25f / 448.0f;
  #pragma unroll
  for (int i = 0; i < 4; ++i) {
    int c = c0 + ty + i * 8, p = p0 + tx;
    if (p < 3600) {
      size_t o = (size_t)c * 3600 + p;
      out[o] = 0.5f * fq[o] + wts * t[tx][ty + i * 8];
    }
  }
}

// ---------------------------------------------------------------------------
extern "C" void kernel_launch(void* const* d_in, const int* in_sizes, int n_in,
                              void* d_out, int out_size, void* d_ws, size_t ws_size,
                              hipStream_t stream) {
  const float* fq3 = (const float*)d_in[0];
  const float* fq4 = (const float*)d_in[1];
  const float* fs3 = (const float*)d_in[2];
  const float* fs4 = (const float*)d_in[3];
  const float* f_q = (const float*)d_in[4];
  const float* f_s = (const float*)d_in[5];
  const float* wch = (const float*)d_in[6];
  float* out = (float*)d_out;

  const size_t HW = 3600, MP = 3840, CH = 512;
  const size_t NG = 96;

  // batch strides (elements / bytes as appropriate)
  const long sT   = (long)NG * MP * 16;        // fp4 operand buffer bytes
  const long sV   = 240L * CH * 16;            // V8 bytes (MP/16 groups)
  const long sL   = (long)MP * MP;             // bf16 elems
  const long sAtt = 240L * MP * 16;            // Att8 bytes
  const long sPart = 96L * HW;                 // floats
  const long sInv  = (long)HW;                 // floats

  // workspace (~196 MB; ws >= ~268 MB per harness fill size)
  unsigned char* QT4 = (unsigned char*)d_ws;          // (96, MP, 16B) fp4 query (shared)
  unsigned char* ST4 = QT4 + sT;                      // 2 x fp4 support
  unsigned char* V8  = ST4 + 2 * sT;                  // 2 x fp8 V
  unsigned short* L4 = (unsigned short*)(V8 + 2 * sV);    // 2 x (MP,MP) bf16
  unsigned short* L3 = L4 + 2 * sL;                   // 2 x (MP,MP) bf16
  unsigned char* Att8 = (unsigned char*)(L3 + 2 * sL);    // 2 x fp8 attn*448
  unsigned short* Pb = (unsigned short*)(Att8 + 2 * sAtt); // 6 x (MP,CH) bf16
  float* invq4 = (float*)(Pb + 6 * MP * CH);
  float* invq3 = invq4 + HW;
  float* invs4 = invq3 + HW;                          // 2 x HW
  float* invs3 = invs4 + 2 * HW;                      // 2 x HW
  float* partQ = invs3 + 2 * HW;                      // 96 x HW
  float* partS = partQ + sPart;                       // 2 x 96 x HW

  dim3 tb(32, 8);
  // query side (batch-independent)
  tpose2_f4_k<<<dim3(113, 96, 1), tb, 0, stream>>>(fq4, fq3, QT4, partQ, 0, 0, 0, 0);
  norm_fin_k<<<dim3(15, 1), 256, 0, stream>>>(partQ, invq4, invq3, 0, 0);

  // support side: both batches in each launch
  castv_f8_k<<<dim3(7200, 2), 256, 0, stream>>>(f_s, V8, (long)CH * HW, sV);
  tpose2_f4_k<<<dim3(113, 96, 2), tb, 0, stream>>>(
      fs4, fs3, ST4, partS, 2048L * HW, 1024L * HW, sT, sPart);
  norm_fin_k<<<dim3(15, 2), 256, 0, stream>>>(partS, invs4, invs3, sPart, sInv);

  const long G4OFF = 64L * MP * 16;   // byte offset of group 64 (level-3 cols)

  // raw per-level dots, both batches per launch (z=2 -> 1800 blocks)
  gemm128_f4<<<dim3(900, 1, 2), 256, 0, stream>>>(
      QT4, ST4, L4, 2048, 3840, 3840, 30, sT, sL);
  gemm128_f4<<<dim3(900, 1, 2), 256, 0, stream>>>(
      QT4 + G4OFF, ST4 + G4OFF, L3, 1024, 3840, 3840, 30, sT, sL);

  softmax_rows_k<<<dim3(3600, 2), 256, 0, stream>>>(
      L4, L3, invq4, invq3, invs4, invs3, wch, Att8, sL, sInv, sAtt);

  // PV: both batches (y=2), 6 disjoint partials
  pv_f8_k<<<dim3(360, 2), 256, 0, stream>>>(Att8, V8, Pb, sAtt, sV);

  final_blend_k<<<dim3(113, 16), tb, 0, stream>>>(Pb, f_q, out);
}

// Round 20
// 243.250 us; speedup vs baseline: 3.7536x; 1.0268x over previous
//
#include <hip/hip_runtime.h>
#include <cstdint>

#define TEMP_C 20.0f

typedef float f32x4 __attribute__((ext_vector_type(4)));
typedef float f32x16 __attribute__((ext_vector_type(16)));
typedef int i32x4 __attribute__((ext_vector_type(4)));
typedef int i32x8 __attribute__((ext_vector_type(8)));

// fp32 -> bf16 round-to-nearest-even
__device__ __forceinline__ unsigned short f2bf(float f) {
  union { float f; unsigned int u; } v; v.f = f;
  unsigned int r = v.u + 0x7FFFu + ((v.u >> 16) & 1u);
  return (unsigned short)(r >> 16);
}
__device__ __forceinline__ float bf2f(unsigned short b) {
  union { unsigned int u; float f; } v; v.u = ((unsigned int)b) << 16;
  return v.f;
}

// fp32 -> OCP e4m3fn, RTNE, clamp to +-448
__device__ __forceinline__ unsigned char f2e4m3(float f) {
  unsigned u = __float_as_uint(f);
  unsigned s = (u >> 24) & 0x80u;
  float a = fminf(fabsf(f), 448.0f);
  if (a < 0.015625f) {
    int d = (int)rintf(a * 512.0f);
    return (unsigned char)(s | (unsigned)d);
  }
  unsigned au = __float_as_uint(a);
  unsigned r = au + 0xFFFFFu + ((au >> 20) & 1u);
  int Ep = (int)(r >> 23) - 127;
  if (Ep > 8) return (unsigned char)(s | 0x7E);
  unsigned m = (r >> 20) & 7u;
  return (unsigned char)(s | ((unsigned)(Ep + 7) << 3) | m);
}

// fp32 -> e2m1 nibble
__device__ __forceinline__ unsigned f2e2m1(float f) {
  unsigned s = (__float_as_uint(f) >> 28) & 8u;
  float a = fabsf(f);
  unsigned n = (unsigned)(a >= 0.25f) + (a >= 0.75f) + (a >= 1.25f) +
               (a >= 1.75f) + (a >= 2.5f) + (a >= 3.5f) + (a >= 5.0f);
  return s | n;
}

// async global->LDS, 16B per lane
__device__ __forceinline__ void gload_lds16(const void* g, void* l) {
  __builtin_amdgcn_global_load_lds(
      (__attribute__((address_space(1))) void*)(g),
      (__attribute__((address_space(3))) void*)(l), 16, 0, 0);
}

// ---------------------------------------------------------------------------
// 1) fused transpose + FP4 pack + sumsq partials; blockIdx.z = batch
__global__ __launch_bounds__(256) void tpose2_f4_k(
    const float* __restrict__ X4, const float* __restrict__ X3,
    unsigned char* __restrict__ T, float* __restrict__ part,
    long sX4, long sX3, long sT, long sPart)
{
  const int b = blockIdx.z;
  X4 += (long)b * sX4; X3 += (long)b * sX3;
  T  += (long)b * sT;  part += (long)b * sPart;
  __shared__ float tile[32][33];
  __shared__ float red2[8][33];
  const int tx = threadIdx.x, ty = threadIdx.y;
  const int y = blockIdx.y;
  const float* X; int c0;
  if (y < 64) { X = X4; c0 = y * 32; }
  else        { X = X3; c0 = (y - 64) * 32; }
  const int p0 = blockIdx.x * 32;
  #pragma unroll
  for (int i = 0; i < 4; ++i) {
    int c = c0 + ty + i * 8, p = p0 + tx;
    tile[ty + i * 8][tx] = (p < 3600) ? X[(size_t)c * 3600 + p] : 0.f;
  }
  __syncthreads();
  {
    float s = 0.f;
    #pragma unroll
    for (int k = 0; k < 4; ++k) { float v = tile[ty * 4 + k][tx]; s += v * v; }
    red2[ty][tx] = s;
  }
  if (tx < 16) {
    const size_t gbase = (size_t)y * 3840 * 16 + tx;
    #pragma unroll
    for (int i = 0; i < 4; ++i) {
      int p = p0 + ty + i * 8;
      if (p < 3600) {
        unsigned lo = f2e2m1(tile[2 * tx][ty + i * 8]);
        unsigned hi = f2e2m1(tile[2 * tx + 1][ty + i * 8]);
        T[gbase + (size_t)p * 16] = (unsigned char)(lo | (hi << 4));
      }
    }
  }
  __syncthreads();
  if (ty == 0 && p0 + tx < 3600) {
    float s = 0.f;
    #pragma unroll
    for (int j = 0; j < 8; ++j) s += red2[j][tx];
    part[(size_t)y * 3600 + p0 + tx] = s;
  }
}

// 1b) finish norms; blockIdx.y = batch
__global__ __launch_bounds__(256) void norm_fin_k(
    const float* __restrict__ part, float* __restrict__ inv4,
    float* __restrict__ inv3, long sPart, long sInv)
{
  const int b = blockIdx.y;
  part += (long)b * sPart; inv4 += (long)b * sInv; inv3 += (long)b * sInv;
  const int p = blockIdx.x * 256 + threadIdx.x;
  if (p >= 3600) return;
  float s4 = 0.f, s3 = 0.f;
  #pragma unroll
  for (int y = 0; y < 64; ++y) s4 += part[(size_t)y * 3600 + p];
  #pragma unroll
  for (int y = 64; y < 96; ++y) s3 += part[(size_t)y * 3600 + p];
  inv4[p] = 1.0f / fmaxf(sqrtf(s4), 1e-12f);
  inv3[p] = 1.0f / fmaxf(sqrtf(s3), 1e-12f);
}

// ---------------------------------------------------------------------------
// 2) V cast to fp8, K-group-major; blockIdx.y = batch
__global__ void castv_f8_k(const float* __restrict__ X, unsigned char* __restrict__ V8,
                           long sX, long sV)
{
  const int b = blockIdx.y;
  X += (long)b * sX; V8 += (long)b * sV;
  int i = blockIdx.x * 256 + threadIdx.x;
  if (i >= 512 * 3600) return;
  int c = i / 3600, s = i - c * 3600;
  V8[((size_t)(s >> 4) * 512 + c) * 16 + (s & 15)] = f2e4m3(X[i]);
}

// ---------------------------------------------------------------------------
// 3) 128x128 MX-FP4 GEMM, ALL FOUR jobs in one launch.
//    blockIdx.z = 0..3: batch = z&1, level = z>>1 (0: K=2048 -> L4,
//    1: K=1024, operands +G4OFF -> L3). r15-verified inner structure.
__global__ __launch_bounds__(256, 4) void gemm128_f4(
    const unsigned char* __restrict__ A, const unsigned char* __restrict__ B,
    unsigned short* __restrict__ L4, unsigned short* __restrict__ L3,
    int MPr, int ldc, int nbn, long sB_b, long sC_b, long G4OFF)
{
  const int zb = blockIdx.z;
  const int bat = zb & 1, lev = zb >> 1;
  const long lof = lev ? G4OFF : 0;
  const int K = lev ? 1024 : 2048;
  A += lof;
  B += (long)bat * sB_b + lof;
  unsigned short* C = (lev ? L3 : L4) + (long)bat * sC_b;

  __shared__ __align__(16) unsigned char As[2][8192];
  __shared__ __align__(16) unsigned char Bs[2][8192];

  const int tid  = threadIdx.x;
  const int lane = tid & 63;
  const int wave = tid >> 6;
  const int wrow = wave >> 1;
  const int wcol = wave & 1;

  const int nwg = gridDim.x;
  const int q8 = nwg >> 3, r8 = nwg & 7;
  const int xcd = blockIdx.x & 7, bidx = blockIdx.x >> 3;
  const int wg = (xcd < r8 ? xcd * (q8 + 1) : r8 * (q8 + 1) + (xcd - r8) * q8) + bidx;
  const long Arow0 = (long)(wg / nbn) * 128;
  const long Brow0 = (long)(wg % nbn) * 128;

  const unsigned char* sA[2];
  const unsigned char* sB[2];
  #pragma unroll
  for (int q = 0; q < 2; ++q) {
    const int c = q * 256 + tid;
    const int g = c >> 7, r = c & 127;
    sA[q] = A + ((long)g * MPr + Arow0 + r) * 16;
    sB[q] = B + ((long)g * MPr + Brow0 + r) * 16;
  }
  const long kstride = (long)MPr * 16 * 4;

  #define STAGE(tt) do { const int _sl = (tt) & 1; const long _ko = (long)(tt) * kstride; \
    gload_lds16(sA[0] + _ko, &As[_sl][tid * 16]);              \
    gload_lds16(sA[1] + _ko, &As[_sl][(256 + tid) * 16]);      \
    gload_lds16(sB[0] + _ko, &Bs[_sl][tid * 16]);              \
    gload_lds16(sB[1] + _ko, &Bs[_sl][(256 + tid) * 16]);      \
  } while (0)

  const int l31 = lane & 31, lk = lane >> 5;
  const int arow0 = (wrow * 64 + l31) * 16;
  const int brow0 = (wcol * 64 + l31) * 16;

  f32x16 acc[2][2] = {};
  const int NT = K >> 7;

  STAGE(0);

  for (int t = 0; t < NT; ++t) {
    const int sl = t & 1;
    if (t + 1 < NT) {
      STAGE(t + 1);
      asm volatile("s_waitcnt vmcnt(4)" ::: "memory");
    } else {
      asm volatile("s_waitcnt vmcnt(0)" ::: "memory");
    }
    asm volatile("s_barrier" ::: "memory");

    const unsigned char* Ap = As[sl];
    const unsigned char* Bp = Bs[sl];
    #define FRAG4(dst, base, rowb, g) do {                       \
      i32x4 _v = *(const i32x4*)((base) + ((g) << 11) + (rowb)); \
      dst[0]=_v[0]; dst[1]=_v[1]; dst[2]=_v[2]; dst[3]=_v[3];    \
      dst[4]=_v[0]; dst[5]=_v[1]; dst[6]=_v[2]; dst[7]=_v[3];    \
    } while (0)
    #define MFMA4(a, b, m, n) \
      acc[m][n] = __builtin_amdgcn_mfma_scale_f32_32x32x64_f8f6f4( \
          a, b, acc[m][n], 4, 4, 0, 127, 0, 127)

    #pragma unroll
    for (int h = 0; h < 2; ++h) {
      const int g = h * 2 + lk;
      i32x8 a0, a1, b0, b1;
      FRAG4(a0, Ap, arow0, g); FRAG4(a1, Ap, arow0 + 512, g);
      FRAG4(b0, Bp, brow0, g); FRAG4(b1, Bp, brow0 + 512, g);
      __builtin_amdgcn_s_setprio(1);
      MFMA4(a0, b0, 0, 0); MFMA4(a0, b1, 0, 1);
      MFMA4(a1, b0, 1, 0); MFMA4(a1, b1, 1, 1);
      __builtin_amdgcn_s_setprio(0);
    }
    #undef FRAG4
    #undef MFMA4
    asm volatile("s_barrier" ::: "memory");
  }
  #undef STAGE

  // epilogue (bf16): col=lane&31, row = (reg&3) + 8*(reg>>2) + 4*(lane>>5)
  #pragma unroll
  for (int m = 0; m < 2; ++m) {
    const long rowb = Arow0 + wrow * 64 + m * 32;
    #pragma unroll
    for (int g4 = 0; g4 < 4; ++g4) {
      #pragma unroll
      for (int r4 = 0; r4 < 4; ++r4) {
        const long row = rowb + r4 + 8 * g4 + 4 * lk;
        unsigned short* cp = C + row * (long)ldc + Brow0 + wcol * 64 + l31;
        cp[0]  = f2bf(acc[m][0][g4 * 4 + r4]);
        cp[32] = f2bf(acc[m][1][g4 * 4 + r4]);
      }
    }
  }
}

// ---------------------------------------------------------------------------
// 4) PV MX-fp8 GEMM, deep-pipelined (r14/r19 verified); blockIdx.y = batch.
__global__ __launch_bounds__(256, 2) void pv_f8_k(
    const unsigned char* __restrict__ Att, const unsigned char* __restrict__ V,
    unsigned short* __restrict__ P, long sAtt, long sV)
{
  const int bb = blockIdx.y;
  Att += (long)bb * sAtt;
  V   += (long)bb * sV;
  __shared__ __align__(16) unsigned char As[4][4096];
  __shared__ __align__(16) unsigned char As2[4][4096];
  __shared__ __align__(16) unsigned char Bs[4][4096];
  __shared__ __align__(16) unsigned char Bs2[4][4096];

  const int tid  = threadIdx.x;
  const int lane = tid & 63;
  const int wave = tid >> 6;
  const int wrow = wave >> 1;
  const int wcol = wave & 1;

  const int xcd = blockIdx.x & 7, bidx = blockIdx.x >> 3;
  const int wg = xcd * 45 + bidx;
  const int x = wg / 12, rem = wg % 12;
  const int y = rem & 3, z = rem >> 2;
  const long Arow0 = (long)x * 128;
  const long Brow0 = (long)y * 128;
  P += (long)(bb * 3 + z) * 3840 * 512;

  const unsigned char* sA[2];
  const unsigned char* sB[2];
  #pragma unroll
  for (int q = 0; q < 2; ++q) {
    const int c = q * 256 + tid;
    const int g = c >> 7, r = c & 127;
    sA[q] = Att + ((long)(z * 80 + g) * 3840 + Arow0 + r) * 16;
    sB[q] = V   + ((long)(z * 80 + g) * 512  + Brow0 + r) * 16;
  }
  const long ksA = 3840L * 16 * 4;
  const long ksB = 512L * 16 * 4;

  #define STAGE(tt) do { const int _sl = (tt) & 3;                      \
    gload_lds16(sA[0] + (long)(tt) * ksA, &As[_sl][tid * 16]);          \
    gload_lds16(sA[1] + (long)(tt) * ksA, &As2[_sl][tid * 16]);         \
    gload_lds16(sB[0] + (long)(tt) * ksB, &Bs[_sl][tid * 16]);          \
    gload_lds16(sB[1] + (long)(tt) * ksB, &Bs2[_sl][tid * 16]);         \
  } while (0)

  const int l31 = lane & 31, lk = lane >> 5;
  const int arow0 = (wrow * 64 + l31) * 16;
  const int brow0 = (wcol * 64 + l31) * 16;

  f32x16 acc[2][2] = {};
  const int NT = 20;

  STAGE(0); STAGE(1); STAGE(2);

  for (int t = 0; t < NT; ++t) {
    const int sl = t & 3;
    const int rem_t = NT - 1 - t;
    if (rem_t >= 2)      asm volatile("s_waitcnt vmcnt(8)" ::: "memory");
    else if (rem_t == 1) asm volatile("s_waitcnt vmcnt(4)" ::: "memory");
    else                 asm volatile("s_waitcnt vmcnt(0)" ::: "memory");
    asm volatile("s_barrier" ::: "memory");
    if (t + 3 < NT) STAGE(t + 3);

    const unsigned char* ApL = lk ? As2[sl] : As[sl];
    const unsigned char* BpL = lk ? Bs2[sl] : Bs[sl];
    #define LDF(base, rowb, s) (*(const i32x4*)((base) + (((s) << 11) + (rowb))))
    #define FRAG(dst, base, rowb) do {                  \
      i32x4 _lo = LDF(base, rowb, 0);                   \
      i32x4 _hi = LDF(base, rowb, 1);                   \
      dst[0]=_lo[0]; dst[1]=_lo[1]; dst[2]=_lo[2]; dst[3]=_lo[3]; \
      dst[4]=_hi[0]; dst[5]=_hi[1]; dst[6]=_hi[2]; dst[7]=_hi[3]; \
    } while (0)
    #define MFMA8(a, b, m, n) \
      acc[m][n] = __builtin_amdgcn_mfma_scale_f32_32x32x64_f8f6f4( \
          a, b, acc[m][n], 0, 0, 0, 127, 0, 127)

    i32x8 a0, a1, b0, b1;
    FRAG(a0, ApL, arow0); FRAG(a1, ApL, arow0 + 512);
    FRAG(b0, BpL, brow0); FRAG(b1, BpL, brow0 + 512);
    asm volatile("s_waitcnt lgkmcnt(0)" ::: "memory");
    __builtin_amdgcn_sched_barrier(0);
    __builtin_amdgcn_s_setprio(1);
    MFMA8(a0, b0, 0, 0); MFMA8(a0, b1, 0, 1);
    MFMA8(a1, b0, 1, 0); MFMA8(a1, b1, 1, 1);
    __builtin_amdgcn_s_setprio(0);
    #undef LDF
    #undef FRAG
    #undef MFMA8
  }
  #undef STAGE

  #pragma unroll
  for (int m = 0; m < 2; ++m) {
    const long rowb = Arow0 + wrow * 64 + m * 32;
    #pragma unroll
    for (int g4 = 0; g4 < 4; ++g4) {
      #pragma unroll
      for (int r4 = 0; r4 < 4; ++r4) {
        const long row = rowb + r4 + 8 * g4 + 4 * lk;
        unsigned short* cp = P + row * 512 + Brow0 + wcol * 64 + l31;
        cp[0]  = f2bf(acc[m][0][g4 * 4 + r4]);
        cp[32] = f2bf(acc[m][1][g4 * 4 + r4]);
      }
    }
  }
}

// ---------------------------------------------------------------------------
// 5) row softmax, PAIR-VECTORIZED (2 s per thread elem): uint bf16x2 loads,
//    float2 invs loads, paired fp8 bytes stored as one ushort.
//    blockIdx.y = batch.
__global__ __launch_bounds__(256) void softmax_rows_k(
    const unsigned short* __restrict__ L4, const unsigned short* __restrict__ L3,
    const float* __restrict__ invq4, const float* __restrict__ invq3,
    const float* __restrict__ invs4, const float* __restrict__ invs3,
    const float* __restrict__ wch, unsigned char* __restrict__ Att,
    long sL, long sInv, long sAtt)
{
  const int b = blockIdx.y;
  L4 += (long)b * sL; L3 += (long)b * sL;
  invs4 += (long)b * sInv; invs3 += (long)b * sInv;
  Att += (long)b * sAtt;
  const int q = blockIdx.x;
  const unsigned short* r4 = L4 + (size_t)q * 3840;
  const unsigned short* r3 = L3 + (size_t)q * 3840;
  const float c4 = TEMP_C * wch[0] * invq4[q];
  const float c3 = TEMP_C * wch[1] * invq3[q];
  const int tid = threadIdx.x;
  float v0[8], v1[8];
  float mx = -1e30f;
  #pragma unroll
  for (int j = 0; j < 8; ++j) {
    const int sp = tid + j * 256;     // pair index; s = 2*sp
    float x0 = -1e30f, x1 = -1e30f;
    if (sp < 1800) {
      const unsigned u4 = *(const unsigned*)&r4[2 * sp];
      const unsigned u3 = *(const unsigned*)&r3[2 * sp];
      const float2 i4v = *(const float2*)&invs4[2 * sp];
      const float2 i3v = *(const float2*)&invs3[2 * sp];
      x0 = c4 * bf2f((unsigned short)u4) * i4v.x + c3 * bf2f((unsigned short)u3) * i3v.x;
      x1 = c4 * bf2f((unsigned short)(u4 >> 16)) * i4v.y + c3 * bf2f((unsigned short)(u3 >> 16)) * i3v.y;
    }
    v0[j] = x0; v1[j] = x1;
    mx = fmaxf(mx, fmaxf(x0, x1));
  }
  #pragma unroll
  for (int o = 32; o > 0; o >>= 1) mx = fmaxf(mx, __shfl_xor(mx, o));
  __shared__ float wmax[4], wsum[4];
  if ((tid & 63) == 0) wmax[tid >> 6] = mx;
  __syncthreads();
  mx = fmaxf(fmaxf(wmax[0], wmax[1]), fmaxf(wmax[2], wmax[3]));
  float sum = 0.f;
  #pragma unroll
  for (int j = 0; j < 8; ++j) {
    const int sp = tid + j * 256;
    float e0 = 0.f, e1 = 0.f;
    if (sp < 1800) {
      e0 = __expf(v0[j] - mx);
      e1 = __expf(v1[j] - mx);
    }
    v0[j] = e0; v1[j] = e1;
    sum += e0 + e1;
  }
  #pragma unroll
  for (int o = 32; o > 0; o >>= 1) sum += __shfl_xor(sum, o);
  if ((tid & 63) == 0) wsum[tid >> 6] = sum;
  __syncthreads();
  sum = wsum[0] + wsum[1] + wsum[2] + wsum[3];
  const float inv448 = 448.0f / sum;
  #pragma unroll
  for (int j = 0; j < 8; ++j) {
    const int sp = tid + j * 256;
    if (sp < 1920) {
      const int s = 2 * sp;
      unsigned short w = 0;
      if (sp < 1800) {
        unsigned lo = f2e4m3(v0[j] * inv448);
        unsigned hi = f2e4m3(v1[j] * inv448);
        w = (unsigned short)(lo | (hi << 8));
      }
      // s even -> s and s+1 share the 16B chunk; byte offset s&15 is even
      *(unsigned short*)&Att[((size_t)(s >> 4) * 3840 + q) * 16 + (s & 15)] = w;
    }
  }
}

// ---------------------------------------------------------------------------
// 6) out[c][p] = 0.5*f_q[c][p] + (0.25/448)*sum_{z=0..5} P[z][p][c]
__global__ __launch_bounds__(256) void final_blend_k(
    const unsigned short* __restrict__ P, const float* __restrict__ fq,
    float* __restrict__ out)
{
  __shared__ float t[32][33];
  const int tx = threadIdx.x, ty = threadIdx.y;
  const int p0 = blockIdx.x * 32, c0 = blockIdx.y * 32;
  const long ZC = 3840L * 512;
  #pragma unroll
  for (int i = 0; i < 4; ++i) {
    int p = p0 + ty + i * 8, c = c0 + tx;
    float s = 0.f;
    if (p < 3600) {
      size_t o = (size_t)p * 512 + c;
      #pragma unroll
      for (int z = 0; z < 6; ++z) s += bf2f(P[o + (size_t)z * ZC]);
    }
    t[ty + i * 8][tx] = s;
  }
  __syncthreads();
  const float wts = 0.25f / 448.0f;
  #pragma unroll
  for (int i = 0; i < 4; ++i) {
    int c = c0 + ty + i * 8, p = p0 + tx;
    if (p < 3600) {
      size_t o = (size_t)c * 3600 + p;
      out[o] = 0.5f * fq[o] + wts * t[tx][ty + i * 8];
    }
  }
}

// ---------------------------------------------------------------------------
extern "C" void kernel_launch(void* const* d_in, const int* in_sizes, int n_in,
                              void* d_out, int out_size, void* d_ws, size_t ws_size,
                              hipStream_t stream) {
  const float* fq3 = (const float*)d_in[0];
  const float* fq4 = (const float*)d_in[1];
  const float* fs3 = (const float*)d_in[2];
  const float* fs4 = (const float*)d_in[3];
  const float* f_q = (const float*)d_in[4];
  const float* f_s = (const float*)d_in[5];
  const float* wch = (const float*)d_in[6];
  float* out = (float*)d_out;

  const size_t HW = 3600, MP = 3840, CH = 512;
  const size_t NG = 96;

  const long sT   = (long)NG * MP * 16;
  const long sV   = 240L * CH * 16;
  const long sL   = (long)MP * MP;
  const long sAtt = 240L * MP * 16;
  const long sPart = 96L * HW;
  const long sInv  = (long)HW;

  // workspace (~196 MB)
  unsigned char* QT4 = (unsigned char*)d_ws;
  unsigned char* ST4 = QT4 + sT;                      // 2x
  unsigned char* V8  = ST4 + 2 * sT;                  // 2x
  unsigned short* L4 = (unsigned short*)(V8 + 2 * sV);    // 2x
  unsigned short* L3 = L4 + 2 * sL;                   // 2x
  unsigned char* Att8 = (unsigned char*)(L3 + 2 * sL);    // 2x
  unsigned short* Pb = (unsigned short*)(Att8 + 2 * sAtt); // 6x (MP,CH)
  float* invq4 = (float*)(Pb + 6 * MP * CH);
  float* invq3 = invq4 + HW;
  float* invs4 = invq3 + HW;                          // 2x
  float* invs3 = invs4 + 2 * HW;                      // 2x
  float* partQ = invs3 + 2 * HW;
  float* partS = partQ + sPart;                       // 2x

  dim3 tb(32, 8);
  tpose2_f4_k<<<dim3(113, 96, 1), tb, 0, stream>>>(fq4, fq3, QT4, partQ, 0, 0, 0, 0);
  norm_fin_k<<<dim3(15, 1), 256, 0, stream>>>(partQ, invq4, invq3, 0, 0);

  castv_f8_k<<<dim3(7200, 2), 256, 0, stream>>>(f_s, V8, (long)CH * HW, sV);
  tpose2_f4_k<<<dim3(113, 96, 2), tb, 0, stream>>>(
      fs4, fs3, ST4, partS, 2048L * HW, 1024L * HW, sT, sPart);
  norm_fin_k<<<dim3(15, 2), 256, 0, stream>>>(partS, invs4, invs3, sPart, sInv);

  const long G4OFF = 64L * MP * 16;

  // all 4 GEMM jobs (2 batches x 2 levels) in ONE launch (z=4 -> 3600 blocks)
  gemm128_f4<<<dim3(900, 1, 4), 256, 0, stream>>>(
      QT4, ST4, L4, L3, 3840, 3840, 30, sT, sL, G4OFF);

  softmax_rows_k<<<dim3(3600, 2), 256, 0, stream>>>(
      L4, L3, invq4, invq3, invs4, invs3, wch, Att8, sL, sInv, sAtt);

  pv_f8_k<<<dim3(360, 2), 256, 0, stream>>>(Att8, V8, Pb, sAtt, sV);

  final_blend_k<<<dim3(113, 16), tb, 0, stream>>>(Pb, f_q, out);
}

// Round 21
// 226.532 us; speedup vs baseline: 4.0306x; 1.0738x over previous
//
#include <hip/hip_runtime.h>
#include <cstdint>

#define TEMP_C 20.0f

typedef float f32x4 __attribute__((ext_vector_type(4)));
typedef float f32x16 __attribute__((ext_vector_type(16)));
typedef int i32x4 __attribute__((ext_vector_type(4)));
typedef int i32x8 __attribute__((ext_vector_type(8)));

// fp32 -> bf16 round-to-nearest-even
__device__ __forceinline__ unsigned short f2bf(float f) {
  union { float f; unsigned int u; } v; v.f = f;
  unsigned int r = v.u + 0x7FFFu + ((v.u >> 16) & 1u);
  return (unsigned short)(r >> 16);
}
__device__ __forceinline__ float bf2f(unsigned short b) {
  union { unsigned int u; float f; } v; v.u = ((unsigned int)b) << 16;
  return v.f;
}

// fp32 -> OCP e4m3fn, RTNE, clamp to +-448
__device__ __forceinline__ unsigned char f2e4m3(float f) {
  unsigned u = __float_as_uint(f);
  unsigned s = (u >> 24) & 0x80u;
  float a = fminf(fabsf(f), 448.0f);
  if (a < 0.015625f) {
    int d = (int)rintf(a * 512.0f);
    return (unsigned char)(s | (unsigned)d);
  }
  unsigned au = __float_as_uint(a);
  unsigned r = au + 0xFFFFFu + ((au >> 20) & 1u);
  int Ep = (int)(r >> 23) - 127;
  if (Ep > 8) return (unsigned char)(s | 0x7E);
  unsigned m = (r >> 20) & 7u;
  return (unsigned char)(s | ((unsigned)(Ep + 7) << 3) | m);
}

// fp32 -> e2m1 nibble
__device__ __forceinline__ unsigned f2e2m1(float f) {
  unsigned s = (__float_as_uint(f) >> 28) & 8u;
  float a = fabsf(f);
  unsigned n = (unsigned)(a >= 0.25f) + (a >= 0.75f) + (a >= 1.25f) +
               (a >= 1.75f) + (a >= 2.5f) + (a >= 3.5f) + (a >= 5.0f);
  return s | n;
}

// async global->LDS, 16B per lane
__device__ __forceinline__ void gload_lds16(const void* g, void* l) {
  __builtin_amdgcn_global_load_lds(
      (__attribute__((address_space(1))) void*)(g),
      (__attribute__((address_space(3))) void*)(l), 16, 0, 0);
}

// ---------------------------------------------------------------------------
// 1) MEGA-PREP: one launch, grid (113, 96, 5).
//    z=0: query transpose+fp4+partials; z=1,2: support (batch z-1);
//    z=3,4: V cast fp8 (batch z-3), linear-block-mapped onto the 113x96 grid.
__global__ __launch_bounds__(256) void prep_k(
    const float* __restrict__ fq4, const float* __restrict__ fq3,
    const float* __restrict__ fs4, const float* __restrict__ fs3,
    const float* __restrict__ f_s,
    unsigned char* __restrict__ QT4, unsigned char* __restrict__ ST4,
    float* __restrict__ partQ, float* __restrict__ partS,
    unsigned char* __restrict__ V8, long sT, long sPart, long sV)
{
  const int z = blockIdx.z;
  const int tx = threadIdx.x, ty = threadIdx.y;
  const int tid = ty * 32 + tx;

  if (z >= 3) {                 // ---- castv path (uniform branch per block)
    const int b = z - 3;
    const long lb = (long)blockIdx.y * 113 + blockIdx.x;
    if (lb >= 7200) return;
    const long i = lb * 256 + tid;
    if (i >= 512L * 3600) return;
    const float* X = f_s + (long)b * 512 * 3600;
    unsigned char* V = V8 + (long)b * sV;
    const int c = (int)(i / 3600), s = (int)(i - (long)c * 3600);
    V[((size_t)(s >> 4) * 512 + c) * 16 + (s & 15)] = f2e4m3(X[i]);
    return;
  }

  // ---- transpose + fp4 + sumsq path
  const float* X4; const float* X3; unsigned char* T; float* part;
  if (z == 0) { X4 = fq4; X3 = fq3; T = QT4; part = partQ; }
  else {
    const int b = z - 1;
    X4 = fs4 + (long)b * 2048 * 3600;
    X3 = fs3 + (long)b * 1024 * 3600;
    T = ST4 + (long)b * sT;
    part = partS + (long)b * sPart;
  }
  __shared__ float tile[32][33];
  __shared__ float red2[8][33];
  const int y = blockIdx.y;
  const float* X; int c0;
  if (y < 64) { X = X4; c0 = y * 32; }
  else        { X = X3; c0 = (y - 64) * 32; }
  const int p0 = blockIdx.x * 32;
  #pragma unroll
  for (int i = 0; i < 4; ++i) {
    int c = c0 + ty + i * 8, p = p0 + tx;
    tile[ty + i * 8][tx] = (p < 3600) ? X[(size_t)c * 3600 + p] : 0.f;
  }
  __syncthreads();
  {
    float s = 0.f;
    #pragma unroll
    for (int k = 0; k < 4; ++k) { float v = tile[ty * 4 + k][tx]; s += v * v; }
    red2[ty][tx] = s;
  }
  if (tx < 16) {
    const size_t gbase = (size_t)y * 3840 * 16 + tx;
    #pragma unroll
    for (int i = 0; i < 4; ++i) {
      int p = p0 + ty + i * 8;
      if (p < 3600) {
        unsigned lo = f2e2m1(tile[2 * tx][ty + i * 8]);
        unsigned hi = f2e2m1(tile[2 * tx + 1][ty + i * 8]);
        T[gbase + (size_t)p * 16] = (unsigned char)(lo | (hi << 4));
      }
    }
  }
  __syncthreads();
  if (ty == 0 && p0 + tx < 3600) {
    float s = 0.f;
    #pragma unroll
    for (int j = 0; j < 8; ++j) s += red2[j][tx];
    part[(size_t)y * 3600 + p0 + tx] = s;
  }
}

// 1b) all three norm jobs in one launch: y=0 query, y=1,2 support batch y-1
__global__ __launch_bounds__(256) void norm_fin_k(
    const float* __restrict__ partQ, const float* __restrict__ partS,
    float* __restrict__ invq4, float* __restrict__ invq3,
    float* __restrict__ invs4, float* __restrict__ invs3, long sPart)
{
  const int yy = blockIdx.y;
  const float* part; float* i4; float* i3;
  if (yy == 0) { part = partQ; i4 = invq4; i3 = invq3; }
  else {
    part = partS + (long)(yy - 1) * sPart;
    i4 = invs4 + (long)(yy - 1) * 3600;
    i3 = invs3 + (long)(yy - 1) * 3600;
  }
  const int p = blockIdx.x * 256 + threadIdx.x;
  if (p >= 3600) return;
  float s4 = 0.f, s3 = 0.f;
  #pragma unroll
  for (int y = 0; y < 64; ++y) s4 += part[(size_t)y * 3600 + p];
  #pragma unroll
  for (int y = 64; y < 96; ++y) s3 += part[(size_t)y * 3600 + p];
  i4[p] = 1.0f / fmaxf(sqrtf(s4), 1e-12f);
  i3[p] = 1.0f / fmaxf(sqrtf(s3), 1e-12f);
}

// ---------------------------------------------------------------------------
// 2) 128x128 MX-FP4 GEMM, all 4 jobs (2 batches x 2 levels) in one launch.
//    (r20 verified)
__global__ __launch_bounds__(256, 4) void gemm128_f4(
    const unsigned char* __restrict__ A, const unsigned char* __restrict__ B,
    unsigned short* __restrict__ L4, unsigned short* __restrict__ L3,
    int MPr, int ldc, int nbn, long sB_b, long sC_b, long G4OFF)
{
  const int zb = blockIdx.z;
  const int bat = zb & 1, lev = zb >> 1;
  const long lof = lev ? G4OFF : 0;
  const int K = lev ? 1024 : 2048;
  A += lof;
  B += (long)bat * sB_b + lof;
  unsigned short* C = (lev ? L3 : L4) + (long)bat * sC_b;

  __shared__ __align__(16) unsigned char As[2][8192];
  __shared__ __align__(16) unsigned char Bs[2][8192];

  const int tid  = threadIdx.x;
  const int lane = tid & 63;
  const int wave = tid >> 6;
  const int wrow = wave >> 1;
  const int wcol = wave & 1;

  const int nwg = gridDim.x;
  const int q8 = nwg >> 3, r8 = nwg & 7;
  const int xcd = blockIdx.x & 7, bidx = blockIdx.x >> 3;
  const int wg = (xcd < r8 ? xcd * (q8 + 1) : r8 * (q8 + 1) + (xcd - r8) * q8) + bidx;
  const long Arow0 = (long)(wg / nbn) * 128;
  const long Brow0 = (long)(wg % nbn) * 128;

  const unsigned char* sA[2];
  const unsigned char* sB[2];
  #pragma unroll
  for (int q = 0; q < 2; ++q) {
    const int c = q * 256 + tid;
    const int g = c >> 7, r = c & 127;
    sA[q] = A + ((long)g * MPr + Arow0 + r) * 16;
    sB[q] = B + ((long)g * MPr + Brow0 + r) * 16;
  }
  const long kstride = (long)MPr * 16 * 4;

  #define STAGE(tt) do { const int _sl = (tt) & 1; const long _ko = (long)(tt) * kstride; \
    gload_lds16(sA[0] + _ko, &As[_sl][tid * 16]);              \
    gload_lds16(sA[1] + _ko, &As[_sl][(256 + tid) * 16]);      \
    gload_lds16(sB[0] + _ko, &Bs[_sl][tid * 16]);              \
    gload_lds16(sB[1] + _ko, &Bs[_sl][(256 + tid) * 16]);      \
  } while (0)

  const int l31 = lane & 31, lk = lane >> 5;
  const int arow0 = (wrow * 64 + l31) * 16;
  const int brow0 = (wcol * 64 + l31) * 16;

  f32x16 acc[2][2] = {};
  const int NT = K >> 7;

  STAGE(0);

  for (int t = 0; t < NT; ++t) {
    const int sl = t & 1;
    if (t + 1 < NT) {
      STAGE(t + 1);
      asm volatile("s_waitcnt vmcnt(4)" ::: "memory");
    } else {
      asm volatile("s_waitcnt vmcnt(0)" ::: "memory");
    }
    asm volatile("s_barrier" ::: "memory");

    const unsigned char* Ap = As[sl];
    const unsigned char* Bp = Bs[sl];
    #define FRAG4(dst, base, rowb, g) do {                       \
      i32x4 _v = *(const i32x4*)((base) + ((g) << 11) + (rowb)); \
      dst[0]=_v[0]; dst[1]=_v[1]; dst[2]=_v[2]; dst[3]=_v[3];    \
      dst[4]=_v[0]; dst[5]=_v[1]; dst[6]=_v[2]; dst[7]=_v[3];    \
    } while (0)
    #define MFMA4(a, b, m, n) \
      acc[m][n] = __builtin_amdgcn_mfma_scale_f32_32x32x64_f8f6f4( \
          a, b, acc[m][n], 4, 4, 0, 127, 0, 127)

    #pragma unroll
    for (int h = 0; h < 2; ++h) {
      const int g = h * 2 + lk;
      i32x8 a0, a1, b0, b1;
      FRAG4(a0, Ap, arow0, g); FRAG4(a1, Ap, arow0 + 512, g);
      FRAG4(b0, Bp, brow0, g); FRAG4(b1, Bp, brow0 + 512, g);
      __builtin_amdgcn_s_setprio(1);
      MFMA4(a0, b0, 0, 0); MFMA4(a0, b1, 0, 1);
      MFMA4(a1, b0, 1, 0); MFMA4(a1, b1, 1, 1);
      __builtin_amdgcn_s_setprio(0);
    }
    #undef FRAG4
    #undef MFMA4
    asm volatile("s_barrier" ::: "memory");
  }
  #undef STAGE

  #pragma unroll
  for (int m = 0; m < 2; ++m) {
    const long rowb = Arow0 + wrow * 64 + m * 32;
    #pragma unroll
    for (int g4 = 0; g4 < 4; ++g4) {
      #pragma unroll
      for (int r4 = 0; r4 < 4; ++r4) {
        const long row = rowb + r4 + 8 * g4 + 4 * lk;
        unsigned short* cp = C + row * (long)ldc + Brow0 + wcol * 64 + l31;
        cp[0]  = f2bf(acc[m][0][g4 * 4 + r4]);
        cp[32] = f2bf(acc[m][1][g4 * 4 + r4]);
      }
    }
  }
}

// ---------------------------------------------------------------------------
// 3) PV MX-fp8 GEMM, deep-pipelined (r14/r19 verified); blockIdx.y = batch.
__global__ __launch_bounds__(256, 2) void pv_f8_k(
    const unsigned char* __restrict__ Att, const unsigned char* __restrict__ V,
    unsigned short* __restrict__ P, long sAtt, long sV)
{
  const int bb = blockIdx.y;
  Att += (long)bb * sAtt;
  V   += (long)bb * sV;
  __shared__ __align__(16) unsigned char As[4][4096];
  __shared__ __align__(16) unsigned char As2[4][4096];
  __shared__ __align__(16) unsigned char Bs[4][4096];
  __shared__ __align__(16) unsigned char Bs2[4][4096];

  const int tid  = threadIdx.x;
  const int lane = tid & 63;
  const int wave = tid >> 6;
  const int wrow = wave >> 1;
  const int wcol = wave & 1;

  const int xcd = blockIdx.x & 7, bidx = blockIdx.x >> 3;
  const int wg = xcd * 45 + bidx;
  const int x = wg / 12, rem = wg % 12;
  const int y = rem & 3, z = rem >> 2;
  const long Arow0 = (long)x * 128;
  const long Brow0 = (long)y * 128;
  P += (long)(bb * 3 + z) * 3840 * 512;

  const unsigned char* sA[2];
  const unsigned char* sB[2];
  #pragma unroll
  for (int q = 0; q < 2; ++q) {
    const int c = q * 256 + tid;
    const int g = c >> 7, r = c & 127;
    sA[q] = Att + ((long)(z * 80 + g) * 3840 + Arow0 + r) * 16;
    sB[q] = V   + ((long)(z * 80 + g) * 512  + Brow0 + r) * 16;
  }
  const long ksA = 3840L * 16 * 4;
  const long ksB = 512L * 16 * 4;

  #define STAGE(tt) do { const int _sl = (tt) & 3;                      \
    gload_lds16(sA[0] + (long)(tt) * ksA, &As[_sl][tid * 16]);          \
    gload_lds16(sA[1] + (long)(tt) * ksA, &As2[_sl][tid * 16]);         \
    gload_lds16(sB[0] + (long)(tt) * ksB, &Bs[_sl][tid * 16]);          \
    gload_lds16(sB[1] + (long)(tt) * ksB, &Bs2[_sl][tid * 16]);         \
  } while (0)

  const int l31 = lane & 31, lk = lane >> 5;
  const int arow0 = (wrow * 64 + l31) * 16;
  const int brow0 = (wcol * 64 + l31) * 16;

  f32x16 acc[2][2] = {};
  const int NT = 20;

  STAGE(0); STAGE(1); STAGE(2);

  for (int t = 0; t < NT; ++t) {
    const int sl = t & 3;
    const int rem_t = NT - 1 - t;
    if (rem_t >= 2)      asm volatile("s_waitcnt vmcnt(8)" ::: "memory");
    else if (rem_t == 1) asm volatile("s_waitcnt vmcnt(4)" ::: "memory");
    else                 asm volatile("s_waitcnt vmcnt(0)" ::: "memory");
    asm volatile("s_barrier" ::: "memory");
    if (t + 3 < NT) STAGE(t + 3);

    const unsigned char* ApL = lk ? As2[sl] : As[sl];
    const unsigned char* BpL = lk ? Bs2[sl] : Bs[sl];
    #define LDF(base, rowb, s) (*(const i32x4*)((base) + (((s) << 11) + (rowb))))
    #define FRAG(dst, base, rowb) do {                  \
      i32x4 _lo = LDF(base, rowb, 0);                   \
      i32x4 _hi = LDF(base, rowb, 1);                   \
      dst[0]=_lo[0]; dst[1]=_lo[1]; dst[2]=_lo[2]; dst[3]=_lo[3]; \
      dst[4]=_hi[0]; dst[5]=_hi[1]; dst[6]=_hi[2]; dst[7]=_hi[3]; \
    } while (0)
    #define MFMA8(a, b, m, n) \
      acc[m][n] = __builtin_amdgcn_mfma_scale_f32_32x32x64_f8f6f4( \
          a, b, acc[m][n], 0, 0, 0, 127, 0, 127)

    i32x8 a0, a1, b0, b1;
    FRAG(a0, ApL, arow0); FRAG(a1, ApL, arow0 + 512);
    FRAG(b0, BpL, brow0); FRAG(b1, BpL, brow0 + 512);
    asm volatile("s_waitcnt lgkmcnt(0)" ::: "memory");
    __builtin_amdgcn_sched_barrier(0);
    __builtin_amdgcn_s_setprio(1);
    MFMA8(a0, b0, 0, 0); MFMA8(a0, b1, 0, 1);
    MFMA8(a1, b0, 1, 0); MFMA8(a1, b1, 1, 1);
    __builtin_amdgcn_s_setprio(0);
    #undef LDF
    #undef FRAG
    #undef MFMA8
  }
  #undef STAGE

  #pragma unroll
  for (int m = 0; m < 2; ++m) {
    const long rowb = Arow0 + wrow * 64 + m * 32;
    #pragma unroll
    for (int g4 = 0; g4 < 4; ++g4) {
      #pragma unroll
      for (int r4 = 0; r4 < 4; ++r4) {
        const long row = rowb + r4 + 8 * g4 + 4 * lk;
        unsigned short* cp = P + row * 512 + Brow0 + wcol * 64 + l31;
        cp[0]  = f2bf(acc[m][0][g4 * 4 + r4]);
        cp[32] = f2bf(acc[m][1][g4 * 4 + r4]);
      }
    }
  }
}

// ---------------------------------------------------------------------------
// 4) row softmax, pair-vectorized (r20 verified); blockIdx.y = batch
__global__ __launch_bounds__(256) void softmax_rows_k(
    const unsigned short* __restrict__ L4, const unsigned short* __restrict__ L3,
    const float* __restrict__ invq4, const float* __restrict__ invq3,
    const float* __restrict__ invs4, const float* __restrict__ invs3,
    const float* __restrict__ wch, unsigned char* __restrict__ Att,
    long sL, long sInv, long sAtt)
{
  const int b = blockIdx.y;
  L4 += (long)b * sL; L3 += (long)b * sL;
  invs4 += (long)b * sInv; invs3 += (long)b * sInv;
  Att += (long)b * sAtt;
  const int q = blockIdx.x;
  const unsigned short* r4 = L4 + (size_t)q * 3840;
  const unsigned short* r3 = L3 + (size_t)q * 3840;
  const float c4 = TEMP_C * wch[0] * invq4[q];
  const float c3 = TEMP_C * wch[1] * invq3[q];
  const int tid = threadIdx.x;
  float v0[8], v1[8];
  float mx = -1e30f;
  #pragma unroll
  for (int j = 0; j < 8; ++j) {
    const int sp = tid + j * 256;
    float x0 = -1e30f, x1 = -1e30f;
    if (sp < 1800) {
      const unsigned u4 = *(const unsigned*)&r4[2 * sp];
      const unsigned u3 = *(const unsigned*)&r3[2 * sp];
      const float2 i4v = *(const float2*)&invs4[2 * sp];
      const float2 i3v = *(const float2*)&invs3[2 * sp];
      x0 = c4 * bf2f((unsigned short)u4) * i4v.x + c3 * bf2f((unsigned short)u3) * i3v.x;
      x1 = c4 * bf2f((unsigned short)(u4 >> 16)) * i4v.y + c3 * bf2f((unsigned short)(u3 >> 16)) * i3v.y;
    }
    v0[j] = x0; v1[j] = x1;
    mx = fmaxf(mx, fmaxf(x0, x1));
  }
  #pragma unroll
  for (int o = 32; o > 0; o >>= 1) mx = fmaxf(mx, __shfl_xor(mx, o));
  __shared__ float wmax[4], wsum[4];
  if ((tid & 63) == 0) wmax[tid >> 6] = mx;
  __syncthreads();
  mx = fmaxf(fmaxf(wmax[0], wmax[1]), fmaxf(wmax[2], wmax[3]));
  float sum = 0.f;
  #pragma unroll
  for (int j = 0; j < 8; ++j) {
    const int sp = tid + j * 256;
    float e0 = 0.f, e1 = 0.f;
    if (sp < 1800) {
      e0 = __expf(v0[j] - mx);
      e1 = __expf(v1[j] - mx);
    }
    v0[j] = e0; v1[j] = e1;
    sum += e0 + e1;
  }
  #pragma unroll
  for (int o = 32; o > 0; o >>= 1) sum += __shfl_xor(sum, o);
  if ((tid & 63) == 0) wsum[tid >> 6] = sum;
  __syncthreads();
  sum = wsum[0] + wsum[1] + wsum[2] + wsum[3];
  const float inv448 = 448.0f / sum;
  #pragma unroll
  for (int j = 0; j < 8; ++j) {
    const int sp = tid + j * 256;
    if (sp < 1920) {
      const int s = 2 * sp;
      unsigned short w = 0;
      if (sp < 1800) {
        unsigned lo = f2e4m3(v0[j] * inv448);
        unsigned hi = f2e4m3(v1[j] * inv448);
        w = (unsigned short)(lo | (hi << 8));
      }
      *(unsigned short*)&Att[((size_t)(s >> 4) * 3840 + q) * 16 + (s & 15)] = w;
    }
  }
}

// ---------------------------------------------------------------------------
// 5) out[c][p] = 0.5*f_q[c][p] + (0.25/448)*sum_{z=0..5} P[z][p][c]
__global__ __launch_bounds__(256) void final_blend_k(
    const unsigned short* __restrict__ P, const float* __restrict__ fq,
    float* __restrict__ out)
{
  __shared__ float t[32][33];
  const int tx = threadIdx.x, ty = threadIdx.y;
  const int p0 = blockIdx.x * 32, c0 = blockIdx.y * 32;
  const long ZC = 3840L * 512;
  #pragma unroll
  for (int i = 0; i < 4; ++i) {
    int p = p0 + ty + i * 8, c = c0 + tx;
    float s = 0.f;
    if (p < 3600) {
      size_t o = (size_t)p * 512 + c;
      #pragma unroll
      for (int z = 0; z < 6; ++z) s += bf2f(P[o + (size_t)z * ZC]);
    }
    t[ty + i * 8][tx] = s;
  }
  __syncthreads();
  const float wts = 0.25f / 448.0f;
  #pragma unroll
  for (int i = 0; i < 4; ++i) {
    int c = c0 + ty + i * 8, p = p0 + tx;
    if (p < 3600) {
      size_t o = (size_t)c * 3600 + p;
      out[o] = 0.5f * fq[o] + wts * t[tx][ty + i * 8];
    }
  }
}

// ---------------------------------------------------------------------------
extern "C" void kernel_launch(void* const* d_in, const int* in_sizes, int n_in,
                              void* d_out, int out_size, void* d_ws, size_t ws_size,
                              hipStream_t stream) {
  const float* fq3 = (const float*)d_in[0];
  const float* fq4 = (const float*)d_in[1];
  const float* fs3 = (const float*)d_in[2];
  const float* fs4 = (const float*)d_in[3];
  const float* f_q = (const float*)d_in[4];
  const float* f_s = (const float*)d_in[5];
  const float* wch = (const float*)d_in[6];
  float* out = (float*)d_out;

  const size_t HW = 3600, MP = 3840, CH = 512;
  const size_t NG = 96;

  const long sT   = (long)NG * MP * 16;
  const long sV   = 240L * CH * 16;
  const long sL   = (long)MP * MP;
  const long sAtt = 240L * MP * 16;
  const long sPart = 96L * HW;
  const long sInv  = (long)HW;

  // workspace (~196 MB)
  unsigned char* QT4 = (unsigned char*)d_ws;
  unsigned char* ST4 = QT4 + sT;                      // 2x
  unsigned char* V8  = ST4 + 2 * sT;                  // 2x
  unsigned short* L4 = (unsigned short*)(V8 + 2 * sV);    // 2x
  unsigned short* L3 = L4 + 2 * sL;                   // 2x
  unsigned char* Att8 = (unsigned char*)(L3 + 2 * sL);    // 2x
  unsigned short* Pb = (unsigned short*)(Att8 + 2 * sAtt); // 6x (MP,CH)
  float* invq4 = (float*)(Pb + 6 * MP * CH);
  float* invq3 = invq4 + HW;
  float* invs4 = invq3 + HW;                          // 2x
  float* invs3 = invs4 + 2 * HW;                      // 2x
  float* partQ = invs3 + 2 * HW;
  float* partS = partQ + sPart;                       // 2x

  dim3 tb(32, 8);
  // all prep work (query tpose, 2x support tpose, 2x castv) in ONE launch
  prep_k<<<dim3(113, 96, 5), tb, 0, stream>>>(
      fq4, fq3, fs4, fs3, f_s, QT4, ST4, partQ, partS, V8, sT, sPart, sV);
  // all three norm reductions in one launch
  norm_fin_k<<<dim3(15, 3), 256, 0, stream>>>(
      partQ, partS, invq4, invq3, invs4, invs3, sPart);

  const long G4OFF = 64L * MP * 16;

  gemm128_f4<<<dim3(900, 1, 4), 256, 0, stream>>>(
      QT4, ST4, L4, L3, 3840, 3840, 30, sT, sL, G4OFF);

  softmax_rows_k<<<dim3(3600, 2), 256, 0, stream>>>(
      L4, L3, invq4, invq3, invs4, invs3, wch, Att8, sL, sInv, sAtt);

  pv_f8_k<<<dim3(360, 2), 256, 0, stream>>>(Att8, V8, Pb, sAtt, sV);

  final_blend_k<<<dim3(113, 16), tb, 0, stream>>>(Pb, f_q, out);
}

// Round 22
// 209.221 us; speedup vs baseline: 4.3641x; 1.0827x over previous
//
#include <hip/hip_runtime.h>
#include <cstdint>

#define TEMP_C 20.0f

typedef float f32x4 __attribute__((ext_vector_type(4)));
typedef float f32x16 __attribute__((ext_vector_type(16)));
typedef int i32x4 __attribute__((ext_vector_type(4)));
typedef int i32x8 __attribute__((ext_vector_type(8)));

// fp32 -> bf16 round-to-nearest-even
__device__ __forceinline__ unsigned short f2bf(float f) {
  union { float f; unsigned int u; } v; v.f = f;
  unsigned int r = v.u + 0x7FFFu + ((v.u >> 16) & 1u);
  return (unsigned short)(r >> 16);
}
__device__ __forceinline__ float bf2f(unsigned short b) {
  union { unsigned int u; float f; } v; v.u = ((unsigned int)b) << 16;
  return v.f;
}

// fp32 -> OCP e4m3fn, RTNE, clamp to +-448
__device__ __forceinline__ unsigned char f2e4m3(float f) {
  unsigned u = __float_as_uint(f);
  unsigned s = (u >> 24) & 0x80u;
  float a = fminf(fabsf(f), 448.0f);
  if (a < 0.015625f) {
    int d = (int)rintf(a * 512.0f);
    return (unsigned char)(s | (unsigned)d);
  }
  unsigned au = __float_as_uint(a);
  unsigned r = au + 0xFFFFFu + ((au >> 20) & 1u);
  int Ep = (int)(r >> 23) - 127;
  if (Ep > 8) return (unsigned char)(s | 0x7E);
  unsigned m = (r >> 20) & 7u;
  return (unsigned char)(s | ((unsigned)(Ep + 7) << 3) | m);
}

// fp32 -> e2m1 nibble
__device__ __forceinline__ unsigned f2e2m1(float f) {
  unsigned s = (__float_as_uint(f) >> 28) & 8u;
  float a = fabsf(f);
  unsigned n = (unsigned)(a >= 0.25f) + (a >= 0.75f) + (a >= 1.25f) +
               (a >= 1.75f) + (a >= 2.5f) + (a >= 3.5f) + (a >= 5.0f);
  return s | n;
}

// async global->LDS, 16B per lane
__device__ __forceinline__ void gload_lds16(const void* g, void* l) {
  __builtin_amdgcn_global_load_lds(
      (__attribute__((address_space(1))) void*)(g),
      (__attribute__((address_space(3))) void*)(l), 16, 0, 0);
}

// ---------------------------------------------------------------------------
// 1) MEGA-PREP (vectorized): grid (113, 96, 5).
//    z=0 query tpose+fp4+partials; z=1,2 support (batch z-1);
//    z=3,4 V cast fp8 (batch z-3), float4-vectorized linear mapping.
__global__ __launch_bounds__(256) void prep_k(
    const float* __restrict__ fq4, const float* __restrict__ fq3,
    const float* __restrict__ fs4, const float* __restrict__ fs3,
    const float* __restrict__ f_s,
    unsigned char* __restrict__ QT4, unsigned char* __restrict__ ST4,
    float* __restrict__ partQ, float* __restrict__ partS,
    unsigned char* __restrict__ V8, long sT, long sPart, long sV)
{
  const int z = blockIdx.z;
  const int tx = threadIdx.x, ty = threadIdx.y;
  const int tid = ty * 32 + tx;

  if (z >= 3) {                 // ---- castv path: float4 load, 4B packed store
    const int b = z - 3;
    const long lb = (long)blockIdx.y * 113 + blockIdx.x;
    if (lb >= 1800) return;     // 460800 float4s / 256 threads
    const long i4 = lb * 256 + tid;
    const float* X = f_s + (long)b * 512 * 3600;
    unsigned char* V = V8 + (long)b * sV;
    f32x4 v = *(const f32x4*)&X[i4 * 4];
    const int c = (int)(i4 / 900);              // 3600/4 = 900 f4 per row
    const int s0 = (int)(i4 - (long)c * 900) * 4;
    unsigned w = (unsigned)f2e4m3(v[0]) | ((unsigned)f2e4m3(v[1]) << 8) |
                 ((unsigned)f2e4m3(v[2]) << 16) | ((unsigned)f2e4m3(v[3]) << 24);
    *(unsigned*)&V[((size_t)(s0 >> 4) * 512 + c) * 16 + (s0 & 15)] = w;
    return;
  }

  // ---- transpose + fp4 + sumsq path
  const float* X4; const float* X3; unsigned char* T; float* part;
  if (z == 0) { X4 = fq4; X3 = fq3; T = QT4; part = partQ; }
  else {
    const int b = z - 1;
    X4 = fs4 + (long)b * 2048 * 3600;
    X3 = fs3 + (long)b * 1024 * 3600;
    T = ST4 + (long)b * sT;
    part = partS + (long)b * sPart;
  }
  __shared__ float tile[32][33];
  __shared__ float red2[8][33];
  const int y = blockIdx.y;
  const float* X; int c0;
  if (y < 64) { X = X4; c0 = y * 32; }
  else        { X = X3; c0 = (y - 64) * 32; }
  const int p0 = blockIdx.x * 32;

  // fill 32x32 tile: thread = (row tid>>3, 4 cols (tid&7)*4). float4 loads
  // except the tail block (float4 would read past the slice end).
  {
    const int cr = tid >> 3;
    const int pc = (tid & 7) * 4;
    const float* src = &X[(size_t)(c0 + cr) * 3600 + p0 + pc];
    if (blockIdx.x != 112) {
      f32x4 v = *(const f32x4*)src;
      tile[cr][pc + 0] = v[0]; tile[cr][pc + 1] = v[1];
      tile[cr][pc + 2] = v[2]; tile[cr][pc + 3] = v[3];
    } else {
      #pragma unroll
      for (int e = 0; e < 4; ++e)
        tile[cr][pc + e] = (p0 + pc + e < 3600) ? src[e] : 0.f;
    }
  }
  __syncthreads();
  // sumsq partial: pixel tx, channels ty*4..ty*4+3
  {
    float s = 0.f;
    #pragma unroll
    for (int k = 0; k < 4; ++k) { float v = tile[ty * 4 + k][tx]; s += v * v; }
    red2[ty][tx] = s;
  }
  // fp4 pack: ALL threads; thread (p = tid>>3, bp = tid&7) packs channels
  // 4bp..4bp+3 into bytes 2bp,2bp+1 of pixel p's 16B chunk.
  {
    const int p = tid >> 3;
    const int bp = tid & 7;
    const int pg = p0 + p;
    if (pg < 3600) {
      unsigned n0 = f2e2m1(tile[4 * bp + 0][p]);
      unsigned n1 = f2e2m1(tile[4 * bp + 1][p]);
      unsigned n2 = f2e2m1(tile[4 * bp + 2][p]);
      unsigned n3 = f2e2m1(tile[4 * bp + 3][p]);
      unsigned short w = (unsigned short)((n0 | (n1 << 4)) | ((n2 | (n3 << 4)) << 8));
      *(unsigned short*)&T[((size_t)y * 3840 + pg) * 16 + 2 * bp] = w;
    }
  }
  __syncthreads();
  if (ty == 0 && p0 + tx < 3600) {
    float s = 0.f;
    #pragma unroll
    for (int j = 0; j < 8; ++j) s += red2[j][tx];
    part[(size_t)y * 3600 + p0 + tx] = s;
  }
}

// 1b) all three norm jobs: y=0 query, y=1,2 support batch y-1
__global__ __launch_bounds__(256) void norm_fin_k(
    const float* __restrict__ partQ, const float* __restrict__ partS,
    float* __restrict__ invq4, float* __restrict__ invq3,
    float* __restrict__ invs4, float* __restrict__ invs3, long sPart)
{
  const int yy = blockIdx.y;
  const float* part; float* i4; float* i3;
  if (yy == 0) { part = partQ; i4 = invq4; i3 = invq3; }
  else {
    part = partS + (long)(yy - 1) * sPart;
    i4 = invs4 + (long)(yy - 1) * 3600;
    i3 = invs3 + (long)(yy - 1) * 3600;
  }
  const int p = blockIdx.x * 256 + threadIdx.x;
  if (p >= 3600) return;
  float s4 = 0.f, s3 = 0.f;
  #pragma unroll
  for (int y = 0; y < 64; ++y) s4 += part[(size_t)y * 3600 + p];
  #pragma unroll
  for (int y = 64; y < 96; ++y) s3 += part[(size_t)y * 3600 + p];
  i4[p] = 1.0f / fmaxf(sqrtf(s4), 1e-12f);
  i3[p] = 1.0f / fmaxf(sqrtf(s3), 1e-12f);
}

// ---------------------------------------------------------------------------
// 2) 128x128 MX-FP4 GEMM, all 4 jobs in one launch (r20 verified)
__global__ __launch_bounds__(256, 4) void gemm128_f4(
    const unsigned char* __restrict__ A, const unsigned char* __restrict__ B,
    unsigned short* __restrict__ L4, unsigned short* __restrict__ L3,
    int MPr, int ldc, int nbn, long sB_b, long sC_b, long G4OFF)
{
  const int zb = blockIdx.z;
  const int bat = zb & 1, lev = zb >> 1;
  const long lof = lev ? G4OFF : 0;
  const int K = lev ? 1024 : 2048;
  A += lof;
  B += (long)bat * sB_b + lof;
  unsigned short* C = (lev ? L3 : L4) + (long)bat * sC_b;

  __shared__ __align__(16) unsigned char As[2][8192];
  __shared__ __align__(16) unsigned char Bs[2][8192];

  const int tid  = threadIdx.x;
  const int lane = tid & 63;
  const int wave = tid >> 6;
  const int wrow = wave >> 1;
  const int wcol = wave & 1;

  const int nwg = gridDim.x;
  const int q8 = nwg >> 3, r8 = nwg & 7;
  const int xcd = blockIdx.x & 7, bidx = blockIdx.x >> 3;
  const int wg = (xcd < r8 ? xcd * (q8 + 1) : r8 * (q8 + 1) + (xcd - r8) * q8) + bidx;
  const long Arow0 = (long)(wg / nbn) * 128;
  const long Brow0 = (long)(wg % nbn) * 128;

  const unsigned char* sA[2];
  const unsigned char* sB[2];
  #pragma unroll
  for (int q = 0; q < 2; ++q) {
    const int c = q * 256 + tid;
    const int g = c >> 7, r = c & 127;
    sA[q] = A + ((long)g * MPr + Arow0 + r) * 16;
    sB[q] = B + ((long)g * MPr + Brow0 + r) * 16;
  }
  const long kstride = (long)MPr * 16 * 4;

  #define STAGE(tt) do { const int _sl = (tt) & 1; const long _ko = (long)(tt) * kstride; \
    gload_lds16(sA[0] + _ko, &As[_sl][tid * 16]);              \
    gload_lds16(sA[1] + _ko, &As[_sl][(256 + tid) * 16]);      \
    gload_lds16(sB[0] + _ko, &Bs[_sl][tid * 16]);              \
    gload_lds16(sB[1] + _ko, &Bs[_sl][(256 + tid) * 16]);      \
  } while (0)

  const int l31 = lane & 31, lk = lane >> 5;
  const int arow0 = (wrow * 64 + l31) * 16;
  const int brow0 = (wcol * 64 + l31) * 16;

  f32x16 acc[2][2] = {};
  const int NT = K >> 7;

  STAGE(0);

  for (int t = 0; t < NT; ++t) {
    const int sl = t & 1;
    if (t + 1 < NT) {
      STAGE(t + 1);
      asm volatile("s_waitcnt vmcnt(4)" ::: "memory");
    } else {
      asm volatile("s_waitcnt vmcnt(0)" ::: "memory");
    }
    asm volatile("s_barrier" ::: "memory");

    const unsigned char* Ap = As[sl];
    const unsigned char* Bp = Bs[sl];
    #define FRAG4(dst, base, rowb, g) do {                       \
      i32x4 _v = *(const i32x4*)((base) + ((g) << 11) + (rowb)); \
      dst[0]=_v[0]; dst[1]=_v[1]; dst[2]=_v[2]; dst[3]=_v[3];    \
      dst[4]=_v[0]; dst[5]=_v[1]; dst[6]=_v[2]; dst[7]=_v[3];    \
    } while (0)
    #define MFMA4(a, b, m, n) \
      acc[m][n] = __builtin_amdgcn_mfma_scale_f32_32x32x64_f8f6f4( \
          a, b, acc[m][n], 4, 4, 0, 127, 0, 127)

    #pragma unroll
    for (int h = 0; h < 2; ++h) {
      const int g = h * 2 + lk;
      i32x8 a0, a1, b0, b1;
      FRAG4(a0, Ap, arow0, g); FRAG4(a1, Ap, arow0 + 512, g);
      FRAG4(b0, Bp, brow0, g); FRAG4(b1, Bp, brow0 + 512, g);
      __builtin_amdgcn_s_setprio(1);
      MFMA4(a0, b0, 0, 0); MFMA4(a0, b1, 0, 1);
      MFMA4(a1, b0, 1, 0); MFMA4(a1, b1, 1, 1);
      __builtin_amdgcn_s_setprio(0);
    }
    #undef FRAG4
    #undef MFMA4
    asm volatile("s_barrier" ::: "memory");
  }
  #undef STAGE

  #pragma unroll
  for (int m = 0; m < 2; ++m) {
    const long rowb = Arow0 + wrow * 64 + m * 32;
    #pragma unroll
    for (int g4 = 0; g4 < 4; ++g4) {
      #pragma unroll
      for (int r4 = 0; r4 < 4; ++r4) {
        const long row = rowb + r4 + 8 * g4 + 4 * lk;
        unsigned short* cp = C + row * (long)ldc + Brow0 + wcol * 64 + l31;
        cp[0]  = f2bf(acc[m][0][g4 * 4 + r4]);
        cp[32] = f2bf(acc[m][1][g4 * 4 + r4]);
      }
    }
  }
}

// ---------------------------------------------------------------------------
// 3) PV MX-fp8 GEMM, deep-pipelined (r14/r19 verified); blockIdx.y = batch.
__global__ __launch_bounds__(256, 2) void pv_f8_k(
    const unsigned char* __restrict__ Att, const unsigned char* __restrict__ V,
    unsigned short* __restrict__ P, long sAtt, long sV)
{
  const int bb = blockIdx.y;
  Att += (long)bb * sAtt;
  V   += (long)bb * sV;
  __shared__ __align__(16) unsigned char As[4][4096];
  __shared__ __align__(16) unsigned char As2[4][4096];
  __shared__ __align__(16) unsigned char Bs[4][4096];
  __shared__ __align__(16) unsigned char Bs2[4][4096];

  const int tid  = threadIdx.x;
  const int lane = tid & 63;
  const int wave = tid >> 6;
  const int wrow = wave >> 1;
  const int wcol = wave & 1;

  const int xcd = blockIdx.x & 7, bidx = blockIdx.x >> 3;
  const int wg = xcd * 45 + bidx;
  const int x = wg / 12, rem = wg % 12;
  const int y = rem & 3, z = rem >> 2;
  const long Arow0 = (long)x * 128;
  const long Brow0 = (long)y * 128;
  P += (long)(bb * 3 + z) * 3840 * 512;

  const unsigned char* sA[2];
  const unsigned char* sB[2];
  #pragma unroll
  for (int q = 0; q < 2; ++q) {
    const int c = q * 256 + tid;
    const int g = c >> 7, r = c & 127;
    sA[q] = Att + ((long)(z * 80 + g) * 3840 + Arow0 + r) * 16;
    sB[q] = V   + ((long)(z * 80 + g) * 512  + Brow0 + r) * 16;
  }
  const long ksA = 3840L * 16 * 4;
  const long ksB = 512L * 16 * 4;

  #define STAGE(tt) do { const int _sl = (tt) & 3;                      \
    gload_lds16(sA[0] + (long)(tt) * ksA, &As[_sl][tid * 16]);          \
    gload_lds16(sA[1] + (long)(tt) * ksA, &As2[_sl][tid * 16]);         \
    gload_lds16(sB[0] + (long)(tt) * ksB, &Bs[_sl][tid * 16]);          \
    gload_lds16(sB[1] + (long)(tt) * ksB, &Bs2[_sl][tid * 16]);         \
  } while (0)

  const int l31 = lane & 31, lk = lane >> 5;
  const int arow0 = (wrow * 64 + l31) * 16;
  const int brow0 = (wcol * 64 + l31) * 16;

  f32x16 acc[2][2] = {};
  const int NT = 20;

  STAGE(0); STAGE(1); STAGE(2);

  for (int t = 0; t < NT; ++t) {
    const int sl = t & 3;
    const int rem_t = NT - 1 - t;
    if (rem_t >= 2)      asm volatile("s_waitcnt vmcnt(8)" ::: "memory");
    else if (rem_t == 1) asm volatile("s_waitcnt vmcnt(4)" ::: "memory");
    else                 asm volatile("s_waitcnt vmcnt(0)" ::: "memory");
    asm volatile("s_barrier" ::: "memory");
    if (t + 3 < NT) STAGE(t + 3);

    const unsigned char* ApL = lk ? As2[sl] : As[sl];
    const unsigned char* BpL = lk ? Bs2[sl] : Bs[sl];
    #define LDF(base, rowb, s) (*(const i32x4*)((base) + (((s) << 11) + (rowb))))
    #define FRAG(dst, base, rowb) do {                  \
      i32x4 _lo = LDF(base, rowb, 0);                   \
      i32x4 _hi = LDF(base, rowb, 1);                   \
      dst[0]=_lo[0]; dst[1]=_lo[1]; dst[2]=_lo[2]; dst[3]=_lo[3]; \
      dst[4]=_hi[0]; dst[5]=_hi[1]; dst[6]=_hi[2]; dst[7]=_hi[3]; \
    } while (0)
    #define MFMA8(a, b, m, n) \
      acc[m][n] = __builtin_amdgcn_mfma_scale_f32_32x32x64_f8f6f4( \
          a, b, acc[m][n], 0, 0, 0, 127, 0, 127)

    i32x8 a0, a1, b0, b1;
    FRAG(a0, ApL, arow0); FRAG(a1, ApL, arow0 + 512);
    FRAG(b0, BpL, brow0); FRAG(b1, BpL, brow0 + 512);
    asm volatile("s_waitcnt lgkmcnt(0)" ::: "memory");
    __builtin_amdgcn_sched_barrier(0);
    __builtin_amdgcn_s_setprio(1);
    MFMA8(a0, b0, 0, 0); MFMA8(a0, b1, 0, 1);
    MFMA8(a1, b0, 1, 0); MFMA8(a1, b1, 1, 1);
    __builtin_amdgcn_s_setprio(0);
    #undef LDF
    #undef FRAG
    #undef MFMA8
  }
  #undef STAGE

  #pragma unroll
  for (int m = 0; m < 2; ++m) {
    const long rowb = Arow0 + wrow * 64 + m * 32;
    #pragma unroll
    for (int g4 = 0; g4 < 4; ++g4) {
      #pragma unroll
      for (int r4 = 0; r4 < 4; ++r4) {
        const long row = rowb + r4 + 8 * g4 + 4 * lk;
        unsigned short* cp = P + row * 512 + Brow0 + wcol * 64 + l31;
        cp[0]  = f2bf(acc[m][0][g4 * 4 + r4]);
        cp[32] = f2bf(acc[m][1][g4 * 4 + r4]);
      }
    }
  }
}

// ---------------------------------------------------------------------------
// 4) row softmax, pair-vectorized (r20 verified); blockIdx.y = batch
__global__ __launch_bounds__(256) void softmax_rows_k(
    const unsigned short* __restrict__ L4, const unsigned short* __restrict__ L3,
    const float* __restrict__ invq4, const float* __restrict__ invq3,
    const float* __restrict__ invs4, const float* __restrict__ invs3,
    const float* __restrict__ wch, unsigned char* __restrict__ Att,
    long sL, long sInv, long sAtt)
{
  const int b = blockIdx.y;
  L4 += (long)b * sL; L3 += (long)b * sL;
  invs4 += (long)b * sInv; invs3 += (long)b * sInv;
  Att += (long)b * sAtt;
  const int q = blockIdx.x;
  const unsigned short* r4 = L4 + (size_t)q * 3840;
  const unsigned short* r3 = L3 + (size_t)q * 3840;
  const float c4 = TEMP_C * wch[0] * invq4[q];
  const float c3 = TEMP_C * wch[1] * invq3[q];
  const int tid = threadIdx.x;
  float v0[8], v1[8];
  float mx = -1e30f;
  #pragma unroll
  for (int j = 0; j < 8; ++j) {
    const int sp = tid + j * 256;
    float x0 = -1e30f, x1 = -1e30f;
    if (sp < 1800) {
      const unsigned u4 = *(const unsigned*)&r4[2 * sp];
      const unsigned u3 = *(const unsigned*)&r3[2 * sp];
      const float2 i4v = *(const float2*)&invs4[2 * sp];
      const float2 i3v = *(const float2*)&invs3[2 * sp];
      x0 = c4 * bf2f((unsigned short)u4) * i4v.x + c3 * bf2f((unsigned short)u3) * i3v.x;
      x1 = c4 * bf2f((unsigned short)(u4 >> 16)) * i4v.y + c3 * bf2f((unsigned short)(u3 >> 16)) * i3v.y;
    }
    v0[j] = x0; v1[j] = x1;
    mx = fmaxf(mx, fmaxf(x0, x1));
  }
  #pragma unroll
  for (int o = 32; o > 0; o >>= 1) mx = fmaxf(mx, __shfl_xor(mx, o));
  __shared__ float wmax[4], wsum[4];
  if ((tid & 63) == 0) wmax[tid >> 6] = mx;
  __syncthreads();
  mx = fmaxf(fmaxf(wmax[0], wmax[1]), fmaxf(wmax[2], wmax[3]));
  float sum = 0.f;
  #pragma unroll
  for (int j = 0; j < 8; ++j) {
    const int sp = tid + j * 256;
    float e0 = 0.f, e1 = 0.f;
    if (sp < 1800) {
      e0 = __expf(v0[j] - mx);
      e1 = __expf(v1[j] - mx);
    }
    v0[j] = e0; v1[j] = e1;
    sum += e0 + e1;
  }
  #pragma unroll
  for (int o = 32; o > 0; o >>= 1) sum += __shfl_xor(sum, o);
  if ((tid & 63) == 0) wsum[tid >> 6] = sum;
  __syncthreads();
  sum = wsum[0] + wsum[1] + wsum[2] + wsum[3];
  const float inv448 = 448.0f / sum;
  #pragma unroll
  for (int j = 0; j < 8; ++j) {
    const int sp = tid + j * 256;
    if (sp < 1920) {
      const int s = 2 * sp;
      unsigned short w = 0;
      if (sp < 1800) {
        unsigned lo = f2e4m3(v0[j] * inv448);
        unsigned hi = f2e4m3(v1[j] * inv448);
        w = (unsigned short)(lo | (hi << 8));
      }
      *(unsigned short*)&Att[((size_t)(s >> 4) * 3840 + q) * 16 + (s & 15)] = w;
    }
  }
}

// ---------------------------------------------------------------------------
// 5) out[c][p] = 0.5*f_q[c][p] + (0.25/448)*sum_{z=0..5} P[z][p][c]
__global__ __launch_bounds__(256) void final_blend_k(
    const unsigned short* __restrict__ P, const float* __restrict__ fq,
    float* __restrict__ out)
{
  __shared__ float t[32][33];
  const int tx = threadIdx.x, ty = threadIdx.y;
  const int p0 = blockIdx.x * 32, c0 = blockIdx.y * 32;
  const long ZC = 3840L * 512;
  #pragma unroll
  for (int i = 0; i < 4; ++i) {
    int p = p0 + ty + i * 8, c = c0 + tx;
    float s = 0.f;
    if (p < 3600) {
      size_t o = (size_t)p * 512 + c;
      #pragma unroll
      for (int z = 0; z < 6; ++z) s += bf2f(P[o + (size_t)z * ZC]);
    }
    t[ty + i * 8][tx] = s;
  }
  __syncthreads();
  const float wts = 0.25f / 448.0f;
  #pragma unroll
  for (int i = 0; i < 4; ++i) {
    int c = c0 + ty + i * 8, p = p0 + tx;
    if (p < 3600) {
      size_t o = (size_t)c * 3600 + p;
      out[o] = 0.5f * fq[o] + wts * t[tx][ty + i * 8];
    }
  }
}

// ---------------------------------------------------------------------------
extern "C" void kernel_launch(void* const* d_in, const int* in_sizes, int n_in,
                              void* d_out, int out_size, void* d_ws, size_t ws_size,
                              hipStream_t stream) {
  const float* fq3 = (const float*)d_in[0];
  const float* fq4 = (const float*)d_in[1];
  const float* fs3 = (const float*)d_in[2];
  const float* fs4 = (const float*)d_in[3];
  const float* f_q = (const float*)d_in[4];
  const float* f_s = (const float*)d_in[5];
  const float* wch = (const float*)d_in[6];
  float* out = (float*)d_out;

  const size_t HW = 3600, MP = 3840, CH = 512;
  const size_t NG = 96;

  const long sT   = (long)NG * MP * 16;
  const long sV   = 240L * CH * 16;
  const long sL   = (long)MP * MP;
  const long sAtt = 240L * MP * 16;
  const long sPart = 96L * HW;
  const long sInv  = (long)HW;

  // workspace (~196 MB)
  unsigned char* QT4 = (unsigned char*)d_ws;
  unsigned char* ST4 = QT4 + sT;                      // 2x
  unsigned char* V8  = ST4 + 2 * sT;                  // 2x
  unsigned short* L4 = (unsigned short*)(V8 + 2 * sV);    // 2x
  unsigned short* L3 = L4 + 2 * sL;                   // 2x
  unsigned char* Att8 = (unsigned char*)(L3 + 2 * sL);    // 2x
  unsigned short* Pb = (unsigned short*)(Att8 + 2 * sAtt); // 6x (MP,CH)
  float* invq4 = (float*)(Pb + 6 * MP * CH);
  float* invq3 = invq4 + HW;
  float* invs4 = invq3 + HW;                          // 2x
  float* invs3 = invs4 + 2 * HW;                      // 2x
  float* partQ = invs3 + 2 * HW;
  float* partS = partQ + sPart;                       // 2x

  dim3 tb(32, 8);
  prep_k<<<dim3(113, 96, 5), tb, 0, stream>>>(
      fq4, fq3, fs4, fs3, f_s, QT4, ST4, partQ, partS, V8, sT, sPart, sV);
  norm_fin_k<<<dim3(15, 3), 256, 0, stream>>>(
      partQ, partS, invq4, invq3, invs4, invs3, sPart);

  const long G4OFF = 64L * MP * 16;

  gemm128_f4<<<dim3(900, 1, 4), 256, 0, stream>>>(
      QT4, ST4, L4, L3, 3840, 3840, 30, sT, sL, G4OFF);

  softmax_rows_k<<<dim3(3600, 2), 256, 0, stream>>>(
      L4, L3, invq4, invq3, invs4, invs3, wch, Att8, sL, sInv, sAtt);

  pv_f8_k<<<dim3(360, 2), 256, 0, stream>>>(Att8, V8, Pb, sAtt, sV);

  final_blend_k<<<dim3(113, 16), tb, 0, stream>>>(Pb, f_q, out);
}

// Round 23
// 205.690 us; speedup vs baseline: 4.4391x; 1.0172x over previous
//
#include <hip/hip_runtime.h>
#include <cstdint>

#define TEMP_C 20.0f

typedef float f32x4 __attribute__((ext_vector_type(4)));
typedef float f32x16 __attribute__((ext_vector_type(16)));
typedef int i32x4 __attribute__((ext_vector_type(4)));
typedef int i32x8 __attribute__((ext_vector_type(8)));

// fp32 -> bf16 round-to-nearest-even
__device__ __forceinline__ unsigned short f2bf(float f) {
  union { float f; unsigned int u; } v; v.f = f;
  unsigned int r = v.u + 0x7FFFu + ((v.u >> 16) & 1u);
  return (unsigned short)(r >> 16);
}
__device__ __forceinline__ float bf2f(unsigned short b) {
  union { unsigned int u; float f; } v; v.u = ((unsigned int)b) << 16;
  return v.f;
}

// fp32 -> OCP e4m3fn, RTNE, clamp to +-448
__device__ __forceinline__ unsigned char f2e4m3(float f) {
  unsigned u = __float_as_uint(f);
  unsigned s = (u >> 24) & 0x80u;
  float a = fminf(fabsf(f), 448.0f);
  if (a < 0.015625f) {
    int d = (int)rintf(a * 512.0f);
    return (unsigned char)(s | (unsigned)d);
  }
  unsigned au = __float_as_uint(a);
  unsigned r = au + 0xFFFFFu + ((au >> 20) & 1u);
  int Ep = (int)(r >> 23) - 127;
  if (Ep > 8) return (unsigned char)(s | 0x7E);
  unsigned m = (r >> 20) & 7u;
  return (unsigned char)(s | ((unsigned)(Ep + 7) << 3) | m);
}

// fp32 -> e2m1 nibble
__device__ __forceinline__ unsigned f2e2m1(float f) {
  unsigned s = (__float_as_uint(f) >> 28) & 8u;
  float a = fabsf(f);
  unsigned n = (unsigned)(a >= 0.25f) + (a >= 0.75f) + (a >= 1.25f) +
               (a >= 1.75f) + (a >= 2.5f) + (a >= 3.5f) + (a >= 5.0f);
  return s | n;
}

// async global->LDS, 16B per lane
__device__ __forceinline__ void gload_lds16(const void* g, void* l) {
  __builtin_amdgcn_global_load_lds(
      (__attribute__((address_space(1))) void*)(g),
      (__attribute__((address_space(3))) void*)(l), 16, 0, 0);
}

// ---------------------------------------------------------------------------
// 1) MEGA-PREP (vectorized, r22 verified): grid (113, 96, 5).
__global__ __launch_bounds__(256) void prep_k(
    const float* __restrict__ fq4, const float* __restrict__ fq3,
    const float* __restrict__ fs4, const float* __restrict__ fs3,
    const float* __restrict__ f_s,
    unsigned char* __restrict__ QT4, unsigned char* __restrict__ ST4,
    float* __restrict__ partQ, float* __restrict__ partS,
    unsigned char* __restrict__ V8, long sT, long sPart, long sV)
{
  const int z = blockIdx.z;
  const int tx = threadIdx.x, ty = threadIdx.y;
  const int tid = ty * 32 + tx;

  if (z >= 3) {                 // ---- castv path: float4 load, 4B packed store
    const int b = z - 3;
    const long lb = (long)blockIdx.y * 113 + blockIdx.x;
    if (lb >= 1800) return;
    const long i4 = lb * 256 + tid;
    const float* X = f_s + (long)b * 512 * 3600;
    unsigned char* V = V8 + (long)b * sV;
    f32x4 v = *(const f32x4*)&X[i4 * 4];
    const int c = (int)(i4 / 900);
    const int s0 = (int)(i4 - (long)c * 900) * 4;
    unsigned w = (unsigned)f2e4m3(v[0]) | ((unsigned)f2e4m3(v[1]) << 8) |
                 ((unsigned)f2e4m3(v[2]) << 16) | ((unsigned)f2e4m3(v[3]) << 24);
    *(unsigned*)&V[((size_t)(s0 >> 4) * 512 + c) * 16 + (s0 & 15)] = w;
    return;
  }

  // ---- transpose + fp4 + sumsq path
  const float* X4; const float* X3; unsigned char* T; float* part;
  if (z == 0) { X4 = fq4; X3 = fq3; T = QT4; part = partQ; }
  else {
    const int b = z - 1;
    X4 = fs4 + (long)b * 2048 * 3600;
    X3 = fs3 + (long)b * 1024 * 3600;
    T = ST4 + (long)b * sT;
    part = partS + (long)b * sPart;
  }
  __shared__ float tile[32][33];
  __shared__ float red2[8][33];
  const int y = blockIdx.y;
  const float* X; int c0;
  if (y < 64) { X = X4; c0 = y * 32; }
  else        { X = X3; c0 = (y - 64) * 32; }
  const int p0 = blockIdx.x * 32;

  {
    const int cr = tid >> 3;
    const int pc = (tid & 7) * 4;
    const float* src = &X[(size_t)(c0 + cr) * 3600 + p0 + pc];
    if (blockIdx.x != 112) {
      f32x4 v = *(const f32x4*)src;
      tile[cr][pc + 0] = v[0]; tile[cr][pc + 1] = v[1];
      tile[cr][pc + 2] = v[2]; tile[cr][pc + 3] = v[3];
    } else {
      #pragma unroll
      for (int e = 0; e < 4; ++e)
        tile[cr][pc + e] = (p0 + pc + e < 3600) ? src[e] : 0.f;
    }
  }
  __syncthreads();
  {
    float s = 0.f;
    #pragma unroll
    for (int k = 0; k < 4; ++k) { float v = tile[ty * 4 + k][tx]; s += v * v; }
    red2[ty][tx] = s;
  }
  {
    const int p = tid >> 3;
    const int bp = tid & 7;
    const int pg = p0 + p;
    if (pg < 3600) {
      unsigned n0 = f2e2m1(tile[4 * bp + 0][p]);
      unsigned n1 = f2e2m1(tile[4 * bp + 1][p]);
      unsigned n2 = f2e2m1(tile[4 * bp + 2][p]);
      unsigned n3 = f2e2m1(tile[4 * bp + 3][p]);
      unsigned short w = (unsigned short)((n0 | (n1 << 4)) | ((n2 | (n3 << 4)) << 8));
      *(unsigned short*)&T[((size_t)y * 3840 + pg) * 16 + 2 * bp] = w;
    }
  }
  __syncthreads();
  if (ty == 0 && p0 + tx < 3600) {
    float s = 0.f;
    #pragma unroll
    for (int j = 0; j < 8; ++j) s += red2[j][tx];
    part[(size_t)y * 3600 + p0 + tx] = s;
  }
}

// 1b) all three norm jobs: y=0 query, y=1,2 support batch y-1
__global__ __launch_bounds__(256) void norm_fin_k(
    const float* __restrict__ partQ, const float* __restrict__ partS,
    float* __restrict__ invq4, float* __restrict__ invq3,
    float* __restrict__ invs4, float* __restrict__ invs3, long sPart)
{
  const int yy = blockIdx.y;
  const float* part; float* i4; float* i3;
  if (yy == 0) { part = partQ; i4 = invq4; i3 = invq3; }
  else {
    part = partS + (long)(yy - 1) * sPart;
    i4 = invs4 + (long)(yy - 1) * 3600;
    i3 = invs3 + (long)(yy - 1) * 3600;
  }
  const int p = blockIdx.x * 256 + threadIdx.x;
  if (p >= 3600) return;
  float s4 = 0.f, s3 = 0.f;
  #pragma unroll
  for (int y = 0; y < 64; ++y) s4 += part[(size_t)y * 3600 + p];
  #pragma unroll
  for (int y = 64; y < 96; ++y) s3 += part[(size_t)y * 3600 + p];
  i4[p] = 1.0f / fmaxf(sqrtf(s4), 1e-12f);
  i3[p] = 1.0f / fmaxf(sqrtf(s3), 1e-12f);
}

// ---------------------------------------------------------------------------
// 2) 128x128 MX-FP4 GEMM, all 4 jobs in one launch (r20 verified).
//    Grid TRIMMED to 29x29 per job (blocks m==29/n==29 were pure padding:
//    rows/cols 3712-3840 never read downstream). nbn=29; covers 0..3711.
__global__ __launch_bounds__(256, 4) void gemm128_f4(
    const unsigned char* __restrict__ A, const unsigned char* __restrict__ B,
    unsigned short* __restrict__ L4, unsigned short* __restrict__ L3,
    int MPr, int ldc, int nbn, long sB_b, long sC_b, long G4OFF)
{
  const int zb = blockIdx.z;
  const int bat = zb & 1, lev = zb >> 1;
  const long lof = lev ? G4OFF : 0;
  const int K = lev ? 1024 : 2048;
  A += lof;
  B += (long)bat * sB_b + lof;
  unsigned short* C = (lev ? L3 : L4) + (long)bat * sC_b;

  __shared__ __align__(16) unsigned char As[2][8192];
  __shared__ __align__(16) unsigned char Bs[2][8192];

  const int tid  = threadIdx.x;
  const int lane = tid & 63;
  const int wave = tid >> 6;
  const int wrow = wave >> 1;
  const int wcol = wave & 1;

  const int nwg = gridDim.x;
  const int q8 = nwg >> 3, r8 = nwg & 7;
  const int xcd = blockIdx.x & 7, bidx = blockIdx.x >> 3;
  const int wg = (xcd < r8 ? xcd * (q8 + 1) : r8 * (q8 + 1) + (xcd - r8) * q8) + bidx;
  const long Arow0 = (long)(wg / nbn) * 128;
  const long Brow0 = (long)(wg % nbn) * 128;

  const unsigned char* sA[2];
  const unsigned char* sB[2];
  #pragma unroll
  for (int q = 0; q < 2; ++q) {
    const int c = q * 256 + tid;
    const int g = c >> 7, r = c & 127;
    sA[q] = A + ((long)g * MPr + Arow0 + r) * 16;
    sB[q] = B + ((long)g * MPr + Brow0 + r) * 16;
  }
  const long kstride = (long)MPr * 16 * 4;

  #define STAGE(tt) do { const int _sl = (tt) & 1; const long _ko = (long)(tt) * kstride; \
    gload_lds16(sA[0] + _ko, &As[_sl][tid * 16]);              \
    gload_lds16(sA[1] + _ko, &As[_sl][(256 + tid) * 16]);      \
    gload_lds16(sB[0] + _ko, &Bs[_sl][tid * 16]);              \
    gload_lds16(sB[1] + _ko, &Bs[_sl][(256 + tid) * 16]);      \
  } while (0)

  const int l31 = lane & 31, lk = lane >> 5;
  const int arow0 = (wrow * 64 + l31) * 16;
  const int brow0 = (wcol * 64 + l31) * 16;

  f32x16 acc[2][2] = {};
  const int NT = K >> 7;

  STAGE(0);

  for (int t = 0; t < NT; ++t) {
    const int sl = t & 1;
    if (t + 1 < NT) {
      STAGE(t + 1);
      asm volatile("s_waitcnt vmcnt(4)" ::: "memory");
    } else {
      asm volatile("s_waitcnt vmcnt(0)" ::: "memory");
    }
    asm volatile("s_barrier" ::: "memory");

    const unsigned char* Ap = As[sl];
    const unsigned char* Bp = Bs[sl];
    #define FRAG4(dst, base, rowb, g) do {                       \
      i32x4 _v = *(const i32x4*)((base) + ((g) << 11) + (rowb)); \
      dst[0]=_v[0]; dst[1]=_v[1]; dst[2]=_v[2]; dst[3]=_v[3];    \
      dst[4]=_v[0]; dst[5]=_v[1]; dst[6]=_v[2]; dst[7]=_v[3];    \
    } while (0)
    #define MFMA4(a, b, m, n) \
      acc[m][n] = __builtin_amdgcn_mfma_scale_f32_32x32x64_f8f6f4( \
          a, b, acc[m][n], 4, 4, 0, 127, 0, 127)

    #pragma unroll
    for (int h = 0; h < 2; ++h) {
      const int g = h * 2 + lk;
      i32x8 a0, a1, b0, b1;
      FRAG4(a0, Ap, arow0, g); FRAG4(a1, Ap, arow0 + 512, g);
      FRAG4(b0, Bp, brow0, g); FRAG4(b1, Bp, brow0 + 512, g);
      __builtin_amdgcn_s_setprio(1);
      MFMA4(a0, b0, 0, 0); MFMA4(a0, b1, 0, 1);
      MFMA4(a1, b0, 1, 0); MFMA4(a1, b1, 1, 1);
      __builtin_amdgcn_s_setprio(0);
    }
    #undef FRAG4
    #undef MFMA4
    asm volatile("s_barrier" ::: "memory");
  }
  #undef STAGE

  #pragma unroll
  for (int m = 0; m < 2; ++m) {
    const long rowb = Arow0 + wrow * 64 + m * 32;
    #pragma unroll
    for (int g4 = 0; g4 < 4; ++g4) {
      #pragma unroll
      for (int r4 = 0; r4 < 4; ++r4) {
        const long row = rowb + r4 + 8 * g4 + 4 * lk;
        unsigned short* cp = C + row * (long)ldc + Brow0 + wcol * 64 + l31;
        cp[0]  = f2bf(acc[m][0][g4 * 4 + r4]);
        cp[32] = f2bf(acc[m][1][g4 * 4 + r4]);
      }
    }
  }
}

// ---------------------------------------------------------------------------
// 3) PV MX-fp8 GEMM, deep-pipelined (r14/r19 verified); blockIdx.y = batch.
__global__ __launch_bounds__(256, 2) void pv_f8_k(
    const unsigned char* __restrict__ Att, const unsigned char* __restrict__ V,
    unsigned short* __restrict__ P, long sAtt, long sV)
{
  const int bb = blockIdx.y;
  Att += (long)bb * sAtt;
  V   += (long)bb * sV;
  __shared__ __align__(16) unsigned char As[4][4096];
  __shared__ __align__(16) unsigned char As2[4][4096];
  __shared__ __align__(16) unsigned char Bs[4][4096];
  __shared__ __align__(16) unsigned char Bs2[4][4096];

  const int tid  = threadIdx.x;
  const int lane = tid & 63;
  const int wave = tid >> 6;
  const int wrow = wave >> 1;
  const int wcol = wave & 1;

  const int xcd = blockIdx.x & 7, bidx = blockIdx.x >> 3;
  const int wg = xcd * 45 + bidx;
  const int x = wg / 12, rem = wg % 12;
  const int y = rem & 3, z = rem >> 2;
  const long Arow0 = (long)x * 128;
  const long Brow0 = (long)y * 128;
  P += (long)(bb * 3 + z) * 3840 * 512;

  const unsigned char* sA[2];
  const unsigned char* sB[2];
  #pragma unroll
  for (int q = 0; q < 2; ++q) {
    const int c = q * 256 + tid;
    const int g = c >> 7, r = c & 127;
    sA[q] = Att + ((long)(z * 80 + g) * 3840 + Arow0 + r) * 16;
    sB[q] = V   + ((long)(z * 80 + g) * 512  + Brow0 + r) * 16;
  }
  const long ksA = 3840L * 16 * 4;
  const long ksB = 512L * 16 * 4;

  #define STAGE(tt) do { const int _sl = (tt) & 3;                      \
    gload_lds16(sA[0] + (long)(tt) * ksA, &As[_sl][tid * 16]);          \
    gload_lds16(sA[1] + (long)(tt) * ksA, &As2[_sl][tid * 16]);         \
    gload_lds16(sB[0] + (long)(tt) * ksB, &Bs[_sl][tid * 16]);          \
    gload_lds16(sB[1] + (long)(tt) * ksB, &Bs2[_sl][tid * 16]);         \
  } while (0)

  const int l31 = lane & 31, lk = lane >> 5;
  const int arow0 = (wrow * 64 + l31) * 16;
  const int brow0 = (wcol * 64 + l31) * 16;

  f32x16 acc[2][2] = {};
  const int NT = 20;

  STAGE(0); STAGE(1); STAGE(2);

  for (int t = 0; t < NT; ++t) {
    const int sl = t & 3;
    const int rem_t = NT - 1 - t;
    if (rem_t >= 2)      asm volatile("s_waitcnt vmcnt(8)" ::: "memory");
    else if (rem_t == 1) asm volatile("s_waitcnt vmcnt(4)" ::: "memory");
    else                 asm volatile("s_waitcnt vmcnt(0)" ::: "memory");
    asm volatile("s_barrier" ::: "memory");
    if (t + 3 < NT) STAGE(t + 3);

    const unsigned char* ApL = lk ? As2[sl] : As[sl];
    const unsigned char* BpL = lk ? Bs2[sl] : Bs[sl];
    #define LDF(base, rowb, s) (*(const i32x4*)((base) + (((s) << 11) + (rowb))))
    #define FRAG(dst, base, rowb) do {                  \
      i32x4 _lo = LDF(base, rowb, 0);                   \
      i32x4 _hi = LDF(base, rowb, 1);                   \
      dst[0]=_lo[0]; dst[1]=_lo[1]; dst[2]=_lo[2]; dst[3]=_lo[3]; \
      dst[4]=_hi[0]; dst[5]=_hi[1]; dst[6]=_hi[2]; dst[7]=_hi[3]; \
    } while (0)
    #define MFMA8(a, b, m, n) \
      acc[m][n] = __builtin_amdgcn_mfma_scale_f32_32x32x64_f8f6f4( \
          a, b, acc[m][n], 0, 0, 0, 127, 0, 127)

    i32x8 a0, a1, b0, b1;
    FRAG(a0, ApL, arow0); FRAG(a1, ApL, arow0 + 512);
    FRAG(b0, BpL, brow0); FRAG(b1, BpL, brow0 + 512);
    asm volatile("s_waitcnt lgkmcnt(0)" ::: "memory");
    __builtin_amdgcn_sched_barrier(0);
    __builtin_amdgcn_s_setprio(1);
    MFMA8(a0, b0, 0, 0); MFMA8(a0, b1, 0, 1);
    MFMA8(a1, b0, 1, 0); MFMA8(a1, b1, 1, 1);
    __builtin_amdgcn_s_setprio(0);
    #undef LDF
    #undef FRAG
    #undef MFMA8
  }
  #undef STAGE

  #pragma unroll
  for (int m = 0; m < 2; ++m) {
    const long rowb = Arow0 + wrow * 64 + m * 32;
    #pragma unroll
    for (int g4 = 0; g4 < 4; ++g4) {
      #pragma unroll
      for (int r4 = 0; r4 < 4; ++r4) {
        const long row = rowb + r4 + 8 * g4 + 4 * lk;
        unsigned short* cp = P + row * 512 + Brow0 + wcol * 64 + l31;
        cp[0]  = f2bf(acc[m][0][g4 * 4 + r4]);
        cp[32] = f2bf(acc[m][1][g4 * 4 + r4]);
      }
    }
  }
}

// ---------------------------------------------------------------------------
// 4) row softmax, pair-vectorized (r20 verified); blockIdx.y = batch
__global__ __launch_bounds__(256) void softmax_rows_k(
    const unsigned short* __restrict__ L4, const unsigned short* __restrict__ L3,
    const float* __restrict__ invq4, const float* __restrict__ invq3,
    const float* __restrict__ invs4, const float* __restrict__ invs3,
    const float* __restrict__ wch, unsigned char* __restrict__ Att,
    long sL, long sInv, long sAtt)
{
  const int b = blockIdx.y;
  L4 += (long)b * sL; L3 += (long)b * sL;
  invs4 += (long)b * sInv; invs3 += (long)b * sInv;
  Att += (long)b * sAtt;
  const int q = blockIdx.x;
  const unsigned short* r4 = L4 + (size_t)q * 3840;
  const unsigned short* r3 = L3 + (size_t)q * 3840;
  const float c4 = TEMP_C * wch[0] * invq4[q];
  const float c3 = TEMP_C * wch[1] * invq3[q];
  const int tid = threadIdx.x;
  float v0[8], v1[8];
  float mx = -1e30f;
  #pragma unroll
  for (int j = 0; j < 8; ++j) {
    const int sp = tid + j * 256;
    float x0 = -1e30f, x1 = -1e30f;
    if (sp < 1800) {
      const unsigned u4 = *(const unsigned*)&r4[2 * sp];
      const unsigned u3 = *(const unsigned*)&r3[2 * sp];
      const float2 i4v = *(const float2*)&invs4[2 * sp];
      const float2 i3v = *(const float2*)&invs3[2 * sp];
      x0 = c4 * bf2f((unsigned short)u4) * i4v.x + c3 * bf2f((unsigned short)u3) * i3v.x;
      x1 = c4 * bf2f((unsigned short)(u4 >> 16)) * i4v.y + c3 * bf2f((unsigned short)(u3 >> 16)) * i3v.y;
    }
    v0[j] = x0; v1[j] = x1;
    mx = fmaxf(mx, fmaxf(x0, x1));
  }
  #pragma unroll
  for (int o = 32; o > 0; o >>= 1) mx = fmaxf(mx, __shfl_xor(mx, o));
  __shared__ float wmax[4], wsum[4];
  if ((tid & 63) == 0) wmax[tid >> 6] = mx;
  __syncthreads();
  mx = fmaxf(fmaxf(wmax[0], wmax[1]), fmaxf(wmax[2], wmax[3]));
  float sum = 0.f;
  #pragma unroll
  for (int j = 0; j < 8; ++j) {
    const int sp = tid + j * 256;
    float e0 = 0.f, e1 = 0.f;
    if (sp < 1800) {
      e0 = __expf(v0[j] - mx);
      e1 = __expf(v1[j] - mx);
    }
    v0[j] = e0; v1[j] = e1;
    sum += e0 + e1;
  }
  #pragma unroll
  for (int o = 32; o > 0; o >>= 1) sum += __shfl_xor(sum, o);
  if ((tid & 63) == 0) wsum[tid >> 6] = sum;
  __syncthreads();
  sum = wsum[0] + wsum[1] + wsum[2] + wsum[3];
  const float inv448 = 448.0f / sum;
  #pragma unroll
  for (int j = 0; j < 8; ++j) {
    const int sp = tid + j * 256;
    if (sp < 1920) {
      const int s = 2 * sp;
      unsigned short w = 0;
      if (sp < 1800) {
        unsigned lo = f2e4m3(v0[j] * inv448);
        unsigned hi = f2e4m3(v1[j] * inv448);
        w = (unsigned short)(lo | (hi << 8));
      }
      *(unsigned short*)&Att[((size_t)(s >> 4) * 3840 + q) * 16 + (s & 15)] = w;
    }
  }
}

// ---------------------------------------------------------------------------
// 5) out[c][p] = 0.5*f_q[c][p] + (0.25/448)*sum_{z=0..5} P[z][p][c]
__global__ __launch_bounds__(256) void final_blend_k(
    const unsigned short* __restrict__ P, const float* __restrict__ fq,
    float* __restrict__ out)
{
  __shared__ float t[32][33];
  const int tx = threadIdx.x, ty = threadIdx.y;
  const int p0 = blockIdx.x * 32, c0 = blockIdx.y * 32;
  const long ZC = 3840L * 512;
  #pragma unroll
  for (int i = 0; i < 4; ++i) {
    int p = p0 + ty + i * 8, c = c0 + tx;
    float s = 0.f;
    if (p < 3600) {
      size_t o = (size_t)p * 512 + c;
      #pragma unroll
      for (int z = 0; z < 6; ++z) s += bf2f(P[o + (size_t)z * ZC]);
    }
    t[ty + i * 8][tx] = s;
  }
  __syncthreads();
  const float wts = 0.25f / 448.0f;
  #pragma unroll
  for (int i = 0; i < 4; ++i) {
    int c = c0 + ty + i * 8, p = p0 + tx;
    if (p < 3600) {
      size_t o = (size_t)c * 3600 + p;
      out[o] = 0.5f * fq[o] + wts * t[tx][ty + i * 8];
    }
  }
}

// ---------------------------------------------------------------------------
extern "C" void kernel_launch(void* const* d_in, const int* in_sizes, int n_in,
                              void* d_out, int out_size, void* d_ws, size_t ws_size,
                              hipStream_t stream) {
  const float* fq3 = (const float*)d_in[0];
  const float* fq4 = (const float*)d_in[1];
  const float* fs3 = (const float*)d_in[2];
  const float* fs4 = (const float*)d_in[3];
  const float* f_q = (const float*)d_in[4];
  const float* f_s = (const float*)d_in[5];
  const float* wch = (const float*)d_in[6];
  float* out = (float*)d_out;

  const size_t HW = 3600, MP = 3840, CH = 512;
  const size_t NG = 96;

  const long sT   = (long)NG * MP * 16;
  const long sV   = 240L * CH * 16;
  const long sL   = (long)MP * MP;
  const long sAtt = 240L * MP * 16;
  const long sPart = 96L * HW;
  const long sInv  = (long)HW;

  // workspace (~196 MB)
  unsigned char* QT4 = (unsigned char*)d_ws;
  unsigned char* ST4 = QT4 + sT;                      // 2x
  unsigned char* V8  = ST4 + 2 * sT;                  // 2x
  unsigned short* L4 = (unsigned short*)(V8 + 2 * sV);    // 2x
  unsigned short* L3 = L4 + 2 * sL;                   // 2x
  unsigned char* Att8 = (unsigned char*)(L3 + 2 * sL);    // 2x
  unsigned short* Pb = (unsigned short*)(Att8 + 2 * sAtt); // 6x (MP,CH)
  float* invq4 = (float*)(Pb + 6 * MP * CH);
  float* invq3 = invq4 + HW;
  float* invs4 = invq3 + HW;                          // 2x
  float* invs3 = invs4 + 2 * HW;                      // 2x
  float* partQ = invs3 + 2 * HW;
  float* partS = partQ + sPart;                       // 2x

  dim3 tb(32, 8);
  prep_k<<<dim3(113, 96, 5), tb, 0, stream>>>(
      fq4, fq3, fs4, fs3, f_s, QT4, ST4, partQ, partS, V8, sT, sPart, sV);
  norm_fin_k<<<dim3(15, 3), 256, 0, stream>>>(
      partQ, partS, invq4, invq3, invs4, invs3, sPart);

  const long G4OFF = 64L * MP * 16;

  // 29x29 = 841 blocks per job (m/n block 29 was pure padding)
  gemm128_f4<<<dim3(841, 1, 4), 256, 0, stream>>>(
      QT4, ST4, L4, L3, 3840, 3840, 29, sT, sL, G4OFF);

  softmax_rows_k<<<dim3(3600, 2), 256, 0, stream>>>(
      L4, L3, invq4, invq3, invs4, invs3, wch, Att8, sL, sInv, sAtt);

  pv_f8_k<<<dim3(360, 2), 256, 0, stream>>>(Att8, V8, Pb, sAtt, sV);

  final_blend_k<<<dim3(113, 16), tb, 0, stream>>>(Pb, f_q, out);
}

// Round 24
// 205.445 us; speedup vs baseline: 4.4444x; 1.0012x over previous
//
#include <hip/hip_runtime.h>
#include <cstdint>

#define TEMP_C 20.0f

typedef float f32x4 __attribute__((ext_vector_type(4)));
typedef float f32x16 __attribute__((ext_vector_type(16)));
typedef int i32x4 __attribute__((ext_vector_type(4)));
typedef int i32x8 __attribute__((ext_vector_type(8)));

// fp32 -> bf16 round-to-nearest-even
__device__ __forceinline__ unsigned short f2bf(float f) {
  union { float f; unsigned int u; } v; v.f = f;
  unsigned int r = v.u + 0x7FFFu + ((v.u >> 16) & 1u);
  return (unsigned short)(r >> 16);
}
__device__ __forceinline__ float bf2f(unsigned short b) {
  union { unsigned int u; float f; } v; v.u = ((unsigned int)b) << 16;
  return v.f;
}

// fp32 -> OCP e4m3fn, RTNE, clamp to +-448
__device__ __forceinline__ unsigned char f2e4m3(float f) {
  unsigned u = __float_as_uint(f);
  unsigned s = (u >> 24) & 0x80u;
  float a = fminf(fabsf(f), 448.0f);
  if (a < 0.015625f) {
    int d = (int)rintf(a * 512.0f);
    return (unsigned char)(s | (unsigned)d);
  }
  unsigned au = __float_as_uint(a);
  unsigned r = au + 0xFFFFFu + ((au >> 20) & 1u);
  int Ep = (int)(r >> 23) - 127;
  if (Ep > 8) return (unsigned char)(s | 0x7E);
  unsigned m = (r >> 20) & 7u;
  return (unsigned char)(s | ((unsigned)(Ep + 7) << 3) | m);
}

// fp32 -> e2m1 nibble
__device__ __forceinline__ unsigned f2e2m1(float f) {
  unsigned s = (__float_as_uint(f) >> 28) & 8u;
  float a = fabsf(f);
  unsigned n = (unsigned)(a >= 0.25f) + (a >= 0.75f) + (a >= 1.25f) +
               (a >= 1.75f) + (a >= 2.5f) + (a >= 3.5f) + (a >= 5.0f);
  return s | n;
}

// async global->LDS, 16B per lane
__device__ __forceinline__ void gload_lds16(const void* g, void* l) {
  __builtin_amdgcn_global_load_lds(
      (__attribute__((address_space(1))) void*)(g),
      (__attribute__((address_space(3))) void*)(l), 16, 0, 0);
}

// ---------------------------------------------------------------------------
// 1) MEGA-PREP (vectorized, r22 verified): grid (113, 96, 5).
__global__ __launch_bounds__(256) void prep_k(
    const float* __restrict__ fq4, const float* __restrict__ fq3,
    const float* __restrict__ fs4, const float* __restrict__ fs3,
    const float* __restrict__ f_s,
    unsigned char* __restrict__ QT4, unsigned char* __restrict__ ST4,
    float* __restrict__ partQ, float* __restrict__ partS,
    unsigned char* __restrict__ V8, long sT, long sPart, long sV)
{
  const int z = blockIdx.z;
  const int tx = threadIdx.x, ty = threadIdx.y;
  const int tid = ty * 32 + tx;

  if (z >= 3) {                 // ---- castv path: float4 load, 4B packed store
    const int b = z - 3;
    const long lb = (long)blockIdx.y * 113 + blockIdx.x;
    if (lb >= 1800) return;
    const long i4 = lb * 256 + tid;
    const float* X = f_s + (long)b * 512 * 3600;
    unsigned char* V = V8 + (long)b * sV;
    f32x4 v = *(const f32x4*)&X[i4 * 4];
    const int c = (int)(i4 / 900);
    const int s0 = (int)(i4 - (long)c * 900) * 4;
    unsigned w = (unsigned)f2e4m3(v[0]) | ((unsigned)f2e4m3(v[1]) << 8) |
                 ((unsigned)f2e4m3(v[2]) << 16) | ((unsigned)f2e4m3(v[3]) << 24);
    *(unsigned*)&V[((size_t)(s0 >> 4) * 512 + c) * 16 + (s0 & 15)] = w;
    return;
  }

  // ---- transpose + fp4 + sumsq path
  const float* X4; const float* X3; unsigned char* T; float* part;
  if (z == 0) { X4 = fq4; X3 = fq3; T = QT4; part = partQ; }
  else {
    const int b = z - 1;
    X4 = fs4 + (long)b * 2048 * 3600;
    X3 = fs3 + (long)b * 1024 * 3600;
    T = ST4 + (long)b * sT;
    part = partS + (long)b * sPart;
  }
  __shared__ float tile[32][33];
  __shared__ float red2[8][33];
  const int y = blockIdx.y;
  const float* X; int c0;
  if (y < 64) { X = X4; c0 = y * 32; }
  else        { X = X3; c0 = (y - 64) * 32; }
  const int p0 = blockIdx.x * 32;

  {
    const int cr = tid >> 3;
    const int pc = (tid & 7) * 4;
    const float* src = &X[(size_t)(c0 + cr) * 3600 + p0 + pc];
    if (blockIdx.x != 112) {
      f32x4 v = *(const f32x4*)src;
      tile[cr][pc + 0] = v[0]; tile[cr][pc + 1] = v[1];
      tile[cr][pc + 2] = v[2]; tile[cr][pc + 3] = v[3];
    } else {
      #pragma unroll
      for (int e = 0; e < 4; ++e)
        tile[cr][pc + e] = (p0 + pc + e < 3600) ? src[e] : 0.f;
    }
  }
  __syncthreads();
  {
    float s = 0.f;
    #pragma unroll
    for (int k = 0; k < 4; ++k) { float v = tile[ty * 4 + k][tx]; s += v * v; }
    red2[ty][tx] = s;
  }
  {
    const int p = tid >> 3;
    const int bp = tid & 7;
    const int pg = p0 + p;
    if (pg < 3600) {
      unsigned n0 = f2e2m1(tile[4 * bp + 0][p]);
      unsigned n1 = f2e2m1(tile[4 * bp + 1][p]);
      unsigned n2 = f2e2m1(tile[4 * bp + 2][p]);
      unsigned n3 = f2e2m1(tile[4 * bp + 3][p]);
      unsigned short w = (unsigned short)((n0 | (n1 << 4)) | ((n2 | (n3 << 4)) << 8));
      *(unsigned short*)&T[((size_t)y * 3840 + pg) * 16 + 2 * bp] = w;
    }
  }
  __syncthreads();
  if (ty == 0 && p0 + tx < 3600) {
    float s = 0.f;
    #pragma unroll
    for (int j = 0; j < 8; ++j) s += red2[j][tx];
    part[(size_t)y * 3600 + p0 + tx] = s;
  }
}

// 1b) all three norm jobs: y=0 query, y=1,2 support batch y-1
__global__ __launch_bounds__(256) void norm_fin_k(
    const float* __restrict__ partQ, const float* __restrict__ partS,
    float* __restrict__ invq4, float* __restrict__ invq3,
    float* __restrict__ invs4, float* __restrict__ invs3, long sPart)
{
  const int yy = blockIdx.y;
  const float* part; float* i4; float* i3;
  if (yy == 0) { part = partQ; i4 = invq4; i3 = invq3; }
  else {
    part = partS + (long)(yy - 1) * sPart;
    i4 = invs4 + (long)(yy - 1) * 3600;
    i3 = invs3 + (long)(yy - 1) * 3600;
  }
  const int p = blockIdx.x * 256 + threadIdx.x;
  if (p >= 3600) return;
  float s4 = 0.f, s3 = 0.f;
  #pragma unroll
  for (int y = 0; y < 64; ++y) s4 += part[(size_t)y * 3600 + p];
  #pragma unroll
  for (int y = 64; y < 96; ++y) s3 += part[(size_t)y * 3600 + p];
  i4[p] = 1.0f / fmaxf(sqrtf(s4), 1e-12f);
  i3[p] = 1.0f / fmaxf(sqrtf(s3), 1e-12f);
}

// ---------------------------------------------------------------------------
// 2) 128x128 MX-FP4 GEMM — PV-STYLE SCHEDULE (ported from pv_f8_k, the one
//    structure in this file that broke the read/MFMA lockstep: r13 46us ->
//    r14 ~17us). BK=128, 3 LDS slots (48KB -> 3 blocks/CU), ONE barrier per
//    K-tile, stage-after-barrier, depth-2 prefetch with counted vmcnt(4).
//    Slot-reuse safety (PV argument, 10 rounds verified): STAGE(t+2) targets
//    slot (t+2)%3 == (t-1)%3, whose ds-reads every wave drained (compiler
//    lgkmcnt before MFMA use) before passing this barrier; async LDS writes
//    are issued after the barrier, so they land after those reads.
//    Grid 29x29 per job (r23 trim); all 4 jobs (batch x level) in z.
__global__ __launch_bounds__(256, 3) void gemm128_f4(
    const unsigned char* __restrict__ A, const unsigned char* __restrict__ B,
    unsigned short* __restrict__ L4, unsigned short* __restrict__ L3,
    int MPr, int ldc, int nbn, long sB_b, long sC_b, long G4OFF)
{
  const int zb = blockIdx.z;
  const int bat = zb & 1, lev = zb >> 1;
  const long lof = lev ? G4OFF : 0;
  const int K = lev ? 1024 : 2048;
  A += lof;
  B += (long)bat * sB_b + lof;
  unsigned short* C = (lev ? L3 : L4) + (long)bat * sC_b;

  __shared__ __align__(16) unsigned char As[3][8192];
  __shared__ __align__(16) unsigned char Bs[3][8192];

  const int tid  = threadIdx.x;
  const int lane = tid & 63;
  const int wave = tid >> 6;
  const int wrow = wave >> 1;
  const int wcol = wave & 1;

  const int nwg = gridDim.x;
  const int q8 = nwg >> 3, r8 = nwg & 7;
  const int xcd = blockIdx.x & 7, bidx = blockIdx.x >> 3;
  const int wg = (xcd < r8 ? xcd * (q8 + 1) : r8 * (q8 + 1) + (xcd - r8) * q8) + bidx;
  const long Arow0 = (long)(wg / nbn) * 128;
  const long Brow0 = (long)(wg % nbn) * 128;

  const unsigned char* sA[2];
  const unsigned char* sB[2];
  #pragma unroll
  for (int q = 0; q < 2; ++q) {
    const int c = q * 256 + tid;
    const int g = c >> 7, r = c & 127;
    sA[q] = A + ((long)g * MPr + Arow0 + r) * 16;
    sB[q] = B + ((long)g * MPr + Brow0 + r) * 16;
  }
  const long kstride = (long)MPr * 16 * 4;   // 4 groups (=128 fp4 k) per tile

  #define STAGE(tt, sl_) do { const long _ko = (long)(tt) * kstride; \
    gload_lds16(sA[0] + _ko, &As[sl_][tid * 16]);              \
    gload_lds16(sA[1] + _ko, &As[sl_][(256 + tid) * 16]);      \
    gload_lds16(sB[0] + _ko, &Bs[sl_][tid * 16]);              \
    gload_lds16(sB[1] + _ko, &Bs[sl_][(256 + tid) * 16]);      \
  } while (0)

  const int l31 = lane & 31, lk = lane >> 5;
  const int arow0 = (wrow * 64 + l31) * 16;
  const int brow0 = (wcol * 64 + l31) * 16;

  f32x16 acc[2][2] = {};
  const int NT = K >> 7;   // 16 or 8

  STAGE(0, 0);
  STAGE(1, 1);

  int sl = 0;
  for (int t = 0; t < NT; ++t) {
    if (t + 1 < NT) {
      asm volatile("s_waitcnt vmcnt(4)" ::: "memory");  // tile t landed; t+1 in flight
    } else {
      asm volatile("s_waitcnt vmcnt(0)" ::: "memory");
    }
    asm volatile("s_barrier" ::: "memory");             // slot sl ready for all waves
    if (t + 2 < NT) {
      int sl2 = sl + 2; if (sl2 >= 3) sl2 -= 3;         // == (t-1)%3, safe to reuse
      STAGE(t + 2, sl2);
    }

    const unsigned char* Ap = As[sl];
    const unsigned char* Bp = Bs[sl];
    #define FRAG4(dst, base, rowb, g) do {                       \
      i32x4 _v = *(const i32x4*)((base) + ((g) << 11) + (rowb)); \
      dst[0]=_v[0]; dst[1]=_v[1]; dst[2]=_v[2]; dst[3]=_v[3];    \
      dst[4]=_v[0]; dst[5]=_v[1]; dst[6]=_v[2]; dst[7]=_v[3];    \
    } while (0)
    #define MFMA4(a, b, m, n) \
      acc[m][n] = __builtin_amdgcn_mfma_scale_f32_32x32x64_f8f6f4( \
          a, b, acc[m][n], 4, 4, 0, 127, 0, 127)

    #pragma unroll
    for (int h = 0; h < 2; ++h) {
      const int g = h * 2 + lk;
      i32x8 a0, a1, b0, b1;
      FRAG4(a0, Ap, arow0, g); FRAG4(a1, Ap, arow0 + 512, g);
      FRAG4(b0, Bp, brow0, g); FRAG4(b1, Bp, brow0 + 512, g);
      __builtin_amdgcn_s_setprio(1);
      MFMA4(a0, b0, 0, 0); MFMA4(a0, b1, 0, 1);
      MFMA4(a1, b0, 1, 0); MFMA4(a1, b1, 1, 1);
      __builtin_amdgcn_s_setprio(0);
    }
    #undef FRAG4
    #undef MFMA4
    sl = (sl == 2) ? 0 : sl + 1;
  }
  #undef STAGE

  // epilogue (bf16): col=lane&31, row = (reg&3) + 8*(reg>>2) + 4*(lane>>5)
  #pragma unroll
  for (int m = 0; m < 2; ++m) {
    const long rowb = Arow0 + wrow * 64 + m * 32;
    #pragma unroll
    for (int g4 = 0; g4 < 4; ++g4) {
      #pragma unroll
      for (int r4 = 0; r4 < 4; ++r4) {
        const long row = rowb + r4 + 8 * g4 + 4 * lk;
        unsigned short* cp = C + row * (long)ldc + Brow0 + wcol * 64 + l31;
        cp[0]  = f2bf(acc[m][0][g4 * 4 + r4]);
        cp[32] = f2bf(acc[m][1][g4 * 4 + r4]);
      }
    }
  }
}

// ---------------------------------------------------------------------------
// 3) PV MX-fp8 GEMM, deep-pipelined (r14/r19 verified); blockIdx.y = batch.
//    Grid x trimmed 30->29 (q rows 3712+ pure padding); 348 blocks/batch,
//    general m204 bijective XCD decode (348 = 8*43 + 4).
__global__ __launch_bounds__(256, 2) void pv_f8_k(
    const unsigned char* __restrict__ Att, const unsigned char* __restrict__ V,
    unsigned short* __restrict__ P, long sAtt, long sV)
{
  const int bb = blockIdx.y;
  Att += (long)bb * sAtt;
  V   += (long)bb * sV;
  __shared__ __align__(16) unsigned char As[4][4096];
  __shared__ __align__(16) unsigned char As2[4][4096];
  __shared__ __align__(16) unsigned char Bs[4][4096];
  __shared__ __align__(16) unsigned char Bs2[4][4096];

  const int tid  = threadIdx.x;
  const int lane = tid & 63;
  const int wave = tid >> 6;
  const int wrow = wave >> 1;
  const int wcol = wave & 1;

  const int nwg = gridDim.x;
  const int q8 = nwg >> 3, r8 = nwg & 7;
  const int xcd = blockIdx.x & 7, bidx = blockIdx.x >> 3;
  const int wg = (xcd < r8 ? xcd * (q8 + 1) : r8 * (q8 + 1) + (xcd - r8) * q8) + bidx;
  const int x = wg / 12, rem = wg % 12;
  const int y = rem & 3, z = rem >> 2;
  const long Arow0 = (long)x * 128;
  const long Brow0 = (long)y * 128;
  P += (long)(bb * 3 + z) * 3840 * 512;

  const unsigned char* sA[2];
  const unsigned char* sB[2];
  #pragma unroll
  for (int q = 0; q < 2; ++q) {
    const int c = q * 256 + tid;
    const int g = c >> 7, r = c & 127;
    sA[q] = Att + ((long)(z * 80 + g) * 3840 + Arow0 + r) * 16;
    sB[q] = V   + ((long)(z * 80 + g) * 512  + Brow0 + r) * 16;
  }
  const long ksA = 3840L * 16 * 4;
  const long ksB = 512L * 16 * 4;

  #define STAGE(tt) do { const int _sl = (tt) & 3;                      \
    gload_lds16(sA[0] + (long)(tt) * ksA, &As[_sl][tid * 16]);          \
    gload_lds16(sA[1] + (long)(tt) * ksA, &As2[_sl][tid * 16]);         \
    gload_lds16(sB[0] + (long)(tt) * ksB, &Bs[_sl][tid * 16]);          \
    gload_lds16(sB[1] + (long)(tt) * ksB, &Bs2[_sl][tid * 16]);         \
  } while (0)

  const int l31 = lane & 31, lk = lane >> 5;
  const int arow0 = (wrow * 64 + l31) * 16;
  const int brow0 = (wcol * 64 + l31) * 16;

  f32x16 acc[2][2] = {};
  const int NT = 20;

  STAGE(0); STAGE(1); STAGE(2);

  for (int t = 0; t < NT; ++t) {
    const int sl = t & 3;
    const int rem_t = NT - 1 - t;
    if (rem_t >= 2)      asm volatile("s_waitcnt vmcnt(8)" ::: "memory");
    else if (rem_t == 1) asm volatile("s_waitcnt vmcnt(4)" ::: "memory");
    else                 asm volatile("s_waitcnt vmcnt(0)" ::: "memory");
    asm volatile("s_barrier" ::: "memory");
    if (t + 3 < NT) STAGE(t + 3);

    const unsigned char* ApL = lk ? As2[sl] : As[sl];
    const unsigned char* BpL = lk ? Bs2[sl] : Bs[sl];
    #define LDF(base, rowb, s) (*(const i32x4*)((base) + (((s) << 11) + (rowb))))
    #define FRAG(dst, base, rowb) do {                  \
      i32x4 _lo = LDF(base, rowb, 0);                   \
      i32x4 _hi = LDF(base, rowb, 1);                   \
      dst[0]=_lo[0]; dst[1]=_lo[1]; dst[2]=_lo[2]; dst[3]=_lo[3]; \
      dst[4]=_hi[0]; dst[5]=_hi[1]; dst[6]=_hi[2]; dst[7]=_hi[3]; \
    } while (0)
    #define MFMA8(a, b, m, n) \
      acc[m][n] = __builtin_amdgcn_mfma_scale_f32_32x32x64_f8f6f4( \
          a, b, acc[m][n], 0, 0, 0, 127, 0, 127)

    i32x8 a0, a1, b0, b1;
    FRAG(a0, ApL, arow0); FRAG(a1, ApL, arow0 + 512);
    FRAG(b0, BpL, brow0); FRAG(b1, BpL, brow0 + 512);
    asm volatile("s_waitcnt lgkmcnt(0)" ::: "memory");
    __builtin_amdgcn_sched_barrier(0);
    __builtin_amdgcn_s_setprio(1);
    MFMA8(a0, b0, 0, 0); MFMA8(a0, b1, 0, 1);
    MFMA8(a1, b0, 1, 0); MFMA8(a1, b1, 1, 1);
    __builtin_amdgcn_s_setprio(0);
    #undef LDF
    #undef FRAG
    #undef MFMA8
  }
  #undef STAGE

  #pragma unroll
  for (int m = 0; m < 2; ++m) {
    const long rowb = Arow0 + wrow * 64 + m * 32;
    #pragma unroll
    for (int g4 = 0; g4 < 4; ++g4) {
      #pragma unroll
      for (int r4 = 0; r4 < 4; ++r4) {
        const long row = rowb + r4 + 8 * g4 + 4 * lk;
        unsigned short* cp = P + row * 512 + Brow0 + wcol * 64 + l31;
        cp[0]  = f2bf(acc[m][0][g4 * 4 + r4]);
        cp[32] = f2bf(acc[m][1][g4 * 4 + r4]);
      }
    }
  }
}

// ---------------------------------------------------------------------------
// 4) row softmax, pair-vectorized (r20 verified); blockIdx.y = batch
__global__ __launch_bounds__(256) void softmax_rows_k(
    const unsigned short* __restrict__ L4, const unsigned short* __restrict__ L3,
    const float* __restrict__ invq4, const float* __restrict__ invq3,
    const float* __restrict__ invs4, const float* __restrict__ invs3,
    const float* __restrict__ wch, unsigned char* __restrict__ Att,
    long sL, long sInv, long sAtt)
{
  const int b = blockIdx.y;
  L4 += (long)b * sL; L3 += (long)b * sL;
  invs4 += (long)b * sInv; invs3 += (long)b * sInv;
  Att += (long)b * sAtt;
  const int q = blockIdx.x;
  const unsigned short* r4 = L4 + (size_t)q * 3840;
  const unsigned short* r3 = L3 + (size_t)q * 3840;
  const float c4 = TEMP_C * wch[0] * invq4[q];
  const float c3 = TEMP_C * wch[1] * invq3[q];
  const int tid = threadIdx.x;
  float v0[8], v1[8];
  float mx = -1e30f;
  #pragma unroll
  for (int j = 0; j < 8; ++j) {
    const int sp = tid + j * 256;
    float x0 = -1e30f, x1 = -1e30f;
    if (sp < 1800) {
      const unsigned u4 = *(const unsigned*)&r4[2 * sp];
      const unsigned u3 = *(const unsigned*)&r3[2 * sp];
      const float2 i4v = *(const float2*)&invs4[2 * sp];
      const float2 i3v = *(const float2*)&invs3[2 * sp];
      x0 = c4 * bf2f((unsigned short)u4) * i4v.x + c3 * bf2f((unsigned short)u3) * i3v.x;
      x1 = c4 * bf2f((unsigned short)(u4 >> 16)) * i4v.y + c3 * bf2f((unsigned short)(u3 >> 16)) * i3v.y;
    }
    v0[j] = x0; v1[j] = x1;
    mx = fmaxf(mx, fmaxf(x0, x1));
  }
  #pragma unroll
  for (int o = 32; o > 0; o >>= 1) mx = fmaxf(mx, __shfl_xor(mx, o));
  __shared__ float wmax[4], wsum[4];
  if ((tid & 63) == 0) wmax[tid >> 6] = mx;
  __syncthreads();
  mx = fmaxf(fmaxf(wmax[0], wmax[1]), fmaxf(wmax[2], wmax[3]));
  float sum = 0.f;
  #pragma unroll
  for (int j = 0; j < 8; ++j) {
    const int sp = tid + j * 256;
    float e0 = 0.f, e1 = 0.f;
    if (sp < 1800) {
      e0 = __expf(v0[j] - mx);
      e1 = __expf(v1[j] - mx);
    }
    v0[j] = e0; v1[j] = e1;
    sum += e0 + e1;
  }
  #pragma unroll
  for (int o = 32; o > 0; o >>= 1) sum += __shfl_xor(sum, o);
  if ((tid & 63) == 0) wsum[tid >> 6] = sum;
  __syncthreads();
  sum = wsum[0] + wsum[1] + wsum[2] + wsum[3];
  const float inv448 = 448.0f / sum;
  #pragma unroll
  for (int j = 0; j < 8; ++j) {
    const int sp = tid + j * 256;
    if (sp < 1920) {
      const int s = 2 * sp;
      unsigned short w = 0;
      if (sp < 1800) {
        unsigned lo = f2e4m3(v0[j] * inv448);
        unsigned hi = f2e4m3(v1[j] * inv448);
        w = (unsigned short)(lo | (hi << 8));
      }
      *(unsigned short*)&Att[((size_t)(s >> 4) * 3840 + q) * 16 + (s & 15)] = w;
    }
  }
}

// ---------------------------------------------------------------------------
// 5) out[c][p] = 0.5*f_q[c][p] + (0.25/448)*sum_{z=0..5} P[z][p][c]
__global__ __launch_bounds__(256) void final_blend_k(
    const unsigned short* __restrict__ P, const float* __restrict__ fq,
    float* __restrict__ out)
{
  __shared__ float t[32][33];
  const int tx = threadIdx.x, ty = threadIdx.y;
  const int p0 = blockIdx.x * 32, c0 = blockIdx.y * 32;
  const long ZC = 3840L * 512;
  #pragma unroll
  for (int i = 0; i < 4; ++i) {
    int p = p0 + ty + i * 8, c = c0 + tx;
    float s = 0.f;
    if (p < 3600) {
      size_t o = (size_t)p * 512 + c;
      #pragma unroll
      for (int z = 0; z < 6; ++z) s += bf2f(P[o + (size_t)z * ZC]);
    }
    t[ty + i * 8][tx] = s;
  }
  __syncthreads();
  const float wts = 0.25f / 448.0f;
  #pragma unroll
  for (int i = 0; i < 4; ++i) {
    int c = c0 + ty + i * 8, p = p0 + tx;
    if (p < 3600) {
      size_t o = (size_t)c * 3600 + p;
      out[o] = 0.5f * fq[o] + wts * t[tx][ty + i * 8];
    }
  }
}

// ---------------------------------------------------------------------------
extern "C" void kernel_launch(void* const* d_in, const int* in_sizes, int n_in,
                              void* d_out, int out_size, void* d_ws, size_t ws_size,
                              hipStream_t stream) {
  const float* fq3 = (const float*)d_in[0];
  const float* fq4 = (const float*)d_in[1];
  const float* fs3 = (const float*)d_in[2];
  const float* fs4 = (const float*)d_in[3];
  const float* f_q = (const float*)d_in[4];
  const float* f_s = (const float*)d_in[5];
  const float* wch = (const float*)d_in[6];
  float* out = (float*)d_out;

  const size_t HW = 3600, MP = 3840, CH = 512;
  const size_t NG = 96;

  const long sT   = (long)NG * MP * 16;
  const long sV   = 240L * CH * 16;
  const long sL   = (long)MP * MP;
  const long sAtt = 240L * MP * 16;
  const long sPart = 96L * HW;
  const long sInv  = (long)HW;

  // workspace (~196 MB)
  unsigned char* QT4 = (unsigned char*)d_ws;
  unsigned char* ST4 = QT4 + sT;                      // 2x
  unsigned char* V8  = ST4 + 2 * sT;                  // 2x
  unsigned short* L4 = (unsigned short*)(V8 + 2 * sV);    // 2x
  unsigned short* L3 = L4 + 2 * sL;                   // 2x
  unsigned char* Att8 = (unsigned char*)(L3 + 2 * sL);    // 2x
  unsigned short* Pb = (unsigned short*)(Att8 + 2 * sAtt); // 6x (MP,CH)
  float* invq4 = (float*)(Pb + 6 * MP * CH);
  float* invq3 = invq4 + HW;
  float* invs4 = invq3 + HW;                          // 2x
  float* invs3 = invs4 + 2 * HW;                      // 2x
  float* partQ = invs3 + 2 * HW;
  float* partS = partQ + sPart;                       // 2x

  dim3 tb(32, 8);
  prep_k<<<dim3(113, 96, 5), tb, 0, stream>>>(
      fq4, fq3, fs4, fs3, f_s, QT4, ST4, partQ, partS, V8, sT, sPart, sV);
  norm_fin_k<<<dim3(15, 3), 256, 0, stream>>>(
      partQ, partS, invq4, invq3, invs4, invs3, sPart);

  const long G4OFF = 64L * MP * 16;

  // 29x29 = 841 blocks per job; PV-style 1-barrier schedule
  gemm128_f4<<<dim3(841, 1, 4), 256, 0, stream>>>(
      QT4, ST4, L4, L3, 3840, 3840, 29, sT, sL, G4OFF);

  softmax_rows_k<<<dim3(3600, 2), 256, 0, stream>>>(
      L4, L3, invq4, invq3, invs4, invs3, wch, Att8, sL, sInv, sAtt);

  // PV: x trimmed to 29 (q rows 3712+ were padding) -> 348 blocks/batch
  pv_f8_k<<<dim3(348, 2), 256, 0, stream>>>(Att8, V8, Pb, sAtt, sV);

  final_blend_k<<<dim3(113, 16), tb, 0, stream>>>(Pb, f_q, out);
}

// Round 25
// 202.887 us; speedup vs baseline: 4.5004x; 1.0126x over previous
//
#include <hip/hip_runtime.h>
#include <cstdint>

#define TEMP_C 20.0f

typedef float f32x4 __attribute__((ext_vector_type(4)));
typedef float f32x16 __attribute__((ext_vector_type(16)));
typedef int i32x4 __attribute__((ext_vector_type(4)));
typedef int i32x8 __attribute__((ext_vector_type(8)));

// fp32 -> bf16 round-to-nearest-even
__device__ __forceinline__ unsigned short f2bf(float f) {
  union { float f; unsigned int u; } v; v.f = f;
  unsigned int r = v.u + 0x7FFFu + ((v.u >> 16) & 1u);
  return (unsigned short)(r >> 16);
}
__device__ __forceinline__ float bf2f(unsigned short b) {
  union { unsigned int u; float f; } v; v.u = ((unsigned int)b) << 16;
  return v.f;
}

// fp32 -> OCP e4m3fn, RTNE, clamp to +-448
__device__ __forceinline__ unsigned char f2e4m3(float f) {
  unsigned u = __float_as_uint(f);
  unsigned s = (u >> 24) & 0x80u;
  float a = fminf(fabsf(f), 448.0f);
  if (a < 0.015625f) {
    int d = (int)rintf(a * 512.0f);
    return (unsigned char)(s | (unsigned)d);
  }
  unsigned au = __float_as_uint(a);
  unsigned r = au + 0xFFFFFu + ((au >> 20) & 1u);
  int Ep = (int)(r >> 23) - 127;
  if (Ep > 8) return (unsigned char)(s | 0x7E);
  unsigned m = (r >> 20) & 7u;
  return (unsigned char)(s | ((unsigned)(Ep + 7) << 3) | m);
}

// fp32 -> e2m1 nibble
__device__ __forceinline__ unsigned f2e2m1(float f) {
  unsigned s = (__float_as_uint(f) >> 28) & 8u;
  float a = fabsf(f);
  unsigned n = (unsigned)(a >= 0.25f) + (a >= 0.75f) + (a >= 1.25f) +
               (a >= 1.75f) + (a >= 2.5f) + (a >= 3.5f) + (a >= 5.0f);
  return s | n;
}

// async global->LDS, 16B per lane
__device__ __forceinline__ void gload_lds16(const void* g, void* l) {
  __builtin_amdgcn_global_load_lds(
      (__attribute__((address_space(1))) void*)(g),
      (__attribute__((address_space(3))) void*)(l), 16, 0, 0);
}

// ---------------------------------------------------------------------------
// 1) MEGA-PREP (vectorized, r22 verified): grid (113, 96, 5).
__global__ __launch_bounds__(256) void prep_k(
    const float* __restrict__ fq4, const float* __restrict__ fq3,
    const float* __restrict__ fs4, const float* __restrict__ fs3,
    const float* __restrict__ f_s,
    unsigned char* __restrict__ QT4, unsigned char* __restrict__ ST4,
    float* __restrict__ partQ, float* __restrict__ partS,
    unsigned char* __restrict__ V8, long sT, long sPart, long sV)
{
  const int z = blockIdx.z;
  const int tx = threadIdx.x, ty = threadIdx.y;
  const int tid = ty * 32 + tx;

  if (z >= 3) {                 // ---- castv path: float4 load, 4B packed store
    const int b = z - 3;
    const long lb = (long)blockIdx.y * 113 + blockIdx.x;
    if (lb >= 1800) return;
    const long i4 = lb * 256 + tid;
    const float* X = f_s + (long)b * 512 * 3600;
    unsigned char* V = V8 + (long)b * sV;
    f32x4 v = *(const f32x4*)&X[i4 * 4];
    const int c = (int)(i4 / 900);
    const int s0 = (int)(i4 - (long)c * 900) * 4;
    unsigned w = (unsigned)f2e4m3(v[0]) | ((unsigned)f2e4m3(v[1]) << 8) |
                 ((unsigned)f2e4m3(v[2]) << 16) | ((unsigned)f2e4m3(v[3]) << 24);
    *(unsigned*)&V[((size_t)(s0 >> 4) * 512 + c) * 16 + (s0 & 15)] = w;
    return;
  }

  // ---- transpose + fp4 + sumsq path
  const float* X4; const float* X3; unsigned char* T; float* part;
  if (z == 0) { X4 = fq4; X3 = fq3; T = QT4; part = partQ; }
  else {
    const int b = z - 1;
    X4 = fs4 + (long)b * 2048 * 3600;
    X3 = fs3 + (long)b * 1024 * 3600;
    T = ST4 + (long)b * sT;
    part = partS + (long)b * sPart;
  }
  __shared__ float tile[32][33];
  __shared__ float red2[8][33];
  const int y = blockIdx.y;
  const float* X; int c0;
  if (y < 64) { X = X4; c0 = y * 32; }
  else        { X = X3; c0 = (y - 64) * 32; }
  const int p0 = blockIdx.x * 32;

  {
    const int cr = tid >> 3;
    const int pc = (tid & 7) * 4;
    const float* src = &X[(size_t)(c0 + cr) * 3600 + p0 + pc];
    if (blockIdx.x != 112) {
      f32x4 v = *(const f32x4*)src;
      tile[cr][pc + 0] = v[0]; tile[cr][pc + 1] = v[1];
      tile[cr][pc + 2] = v[2]; tile[cr][pc + 3] = v[3];
    } else {
      #pragma unroll
      for (int e = 0; e < 4; ++e)
        tile[cr][pc + e] = (p0 + pc + e < 3600) ? src[e] : 0.f;
    }
  }
  __syncthreads();
  {
    float s = 0.f;
    #pragma unroll
    for (int k = 0; k < 4; ++k) { float v = tile[ty * 4 + k][tx]; s += v * v; }
    red2[ty][tx] = s;
  }
  {
    const int p = tid >> 3;
    const int bp = tid & 7;
    const int pg = p0 + p;
    if (pg < 3600) {
      unsigned n0 = f2e2m1(tile[4 * bp + 0][p]);
      unsigned n1 = f2e2m1(tile[4 * bp + 1][p]);
      unsigned n2 = f2e2m1(tile[4 * bp + 2][p]);
      unsigned n3 = f2e2m1(tile[4 * bp + 3][p]);
      unsigned short w = (unsigned short)((n0 | (n1 << 4)) | ((n2 | (n3 << 4)) << 8));
      *(unsigned short*)&T[((size_t)y * 3840 + pg) * 16 + 2 * bp] = w;
    }
  }
  __syncthreads();
  if (ty == 0 && p0 + tx < 3600) {
    float s = 0.f;
    #pragma unroll
    for (int j = 0; j < 8; ++j) s += red2[j][tx];
    part[(size_t)y * 3600 + p0 + tx] = s;
  }
}

// 1b) all three norm jobs: y=0 query, y=1,2 support batch y-1
__global__ __launch_bounds__(256) void norm_fin_k(
    const float* __restrict__ partQ, const float* __restrict__ partS,
    float* __restrict__ invq4, float* __restrict__ invq3,
    float* __restrict__ invs4, float* __restrict__ invs3, long sPart)
{
  const int yy = blockIdx.y;
  const float* part; float* i4; float* i3;
  if (yy == 0) { part = partQ; i4 = invq4; i3 = invq3; }
  else {
    part = partS + (long)(yy - 1) * sPart;
    i4 = invs4 + (long)(yy - 1) * 3600;
    i3 = invs3 + (long)(yy - 1) * 3600;
  }
  const int p = blockIdx.x * 256 + threadIdx.x;
  if (p >= 3600) return;
  float s4 = 0.f, s3 = 0.f;
  #pragma unroll
  for (int y = 0; y < 64; ++y) s4 += part[(size_t)y * 3600 + p];
  #pragma unroll
  for (int y = 64; y < 96; ++y) s3 += part[(size_t)y * 3600 + p];
  i4[p] = 1.0f / fmaxf(sqrtf(s4), 1e-12f);
  i3[p] = 1.0f / fmaxf(sqrtf(s3), 1e-12f);
}

// ---------------------------------------------------------------------------
// 2) 128x128 MX-FP4 GEMM — r23 VERIFIED BEST (2 LDS slots, 2 barriers/tile,
//    launch_bounds(256,4) -> 4 blocks/CU, 67us measured). All 4 jobs in z;
//    grid 29x29 per job. r24's 1-barrier/3-slot port regressed (occupancy
//    3 blocks/CU lost more than barriers saved) — reverted.
__global__ __launch_bounds__(256, 4) void gemm128_f4(
    const unsigned char* __restrict__ A, const unsigned char* __restrict__ B,
    unsigned short* __restrict__ L4, unsigned short* __restrict__ L3,
    int MPr, int ldc, int nbn, long sB_b, long sC_b, long G4OFF)
{
  const int zb = blockIdx.z;
  const int bat = zb & 1, lev = zb >> 1;
  const long lof = lev ? G4OFF : 0;
  const int K = lev ? 1024 : 2048;
  A += lof;
  B += (long)bat * sB_b + lof;
  unsigned short* C = (lev ? L3 : L4) + (long)bat * sC_b;

  __shared__ __align__(16) unsigned char As[2][8192];
  __shared__ __align__(16) unsigned char Bs[2][8192];

  const int tid  = threadIdx.x;
  const int lane = tid & 63;
  const int wave = tid >> 6;
  const int wrow = wave >> 1;
  const int wcol = wave & 1;

  const int nwg = gridDim.x;
  const int q8 = nwg >> 3, r8 = nwg & 7;
  const int xcd = blockIdx.x & 7, bidx = blockIdx.x >> 3;
  const int wg = (xcd < r8 ? xcd * (q8 + 1) : r8 * (q8 + 1) + (xcd - r8) * q8) + bidx;
  const long Arow0 = (long)(wg / nbn) * 128;
  const long Brow0 = (long)(wg % nbn) * 128;

  const unsigned char* sA[2];
  const unsigned char* sB[2];
  #pragma unroll
  for (int q = 0; q < 2; ++q) {
    const int c = q * 256 + tid;
    const int g = c >> 7, r = c & 127;
    sA[q] = A + ((long)g * MPr + Arow0 + r) * 16;
    sB[q] = B + ((long)g * MPr + Brow0 + r) * 16;
  }
  const long kstride = (long)MPr * 16 * 4;

  #define STAGE(tt) do { const int _sl = (tt) & 1; const long _ko = (long)(tt) * kstride; \
    gload_lds16(sA[0] + _ko, &As[_sl][tid * 16]);              \
    gload_lds16(sA[1] + _ko, &As[_sl][(256 + tid) * 16]);      \
    gload_lds16(sB[0] + _ko, &Bs[_sl][tid * 16]);              \
    gload_lds16(sB[1] + _ko, &Bs[_sl][(256 + tid) * 16]);      \
  } while (0)

  const int l31 = lane & 31, lk = lane >> 5;
  const int arow0 = (wrow * 64 + l31) * 16;
  const int brow0 = (wcol * 64 + l31) * 16;

  f32x16 acc[2][2] = {};
  const int NT = K >> 7;

  STAGE(0);

  for (int t = 0; t < NT; ++t) {
    const int sl = t & 1;
    if (t + 1 < NT) {
      STAGE(t + 1);
      asm volatile("s_waitcnt vmcnt(4)" ::: "memory");
    } else {
      asm volatile("s_waitcnt vmcnt(0)" ::: "memory");
    }
    asm volatile("s_barrier" ::: "memory");

    const unsigned char* Ap = As[sl];
    const unsigned char* Bp = Bs[sl];
    #define FRAG4(dst, base, rowb, g) do {                       \
      i32x4 _v = *(const i32x4*)((base) + ((g) << 11) + (rowb)); \
      dst[0]=_v[0]; dst[1]=_v[1]; dst[2]=_v[2]; dst[3]=_v[3];    \
      dst[4]=_v[0]; dst[5]=_v[1]; dst[6]=_v[2]; dst[7]=_v[3];    \
    } while (0)
    #define MFMA4(a, b, m, n) \
      acc[m][n] = __builtin_amdgcn_mfma_scale_f32_32x32x64_f8f6f4( \
          a, b, acc[m][n], 4, 4, 0, 127, 0, 127)

    #pragma unroll
    for (int h = 0; h < 2; ++h) {
      const int g = h * 2 + lk;
      i32x8 a0, a1, b0, b1;
      FRAG4(a0, Ap, arow0, g); FRAG4(a1, Ap, arow0 + 512, g);
      FRAG4(b0, Bp, brow0, g); FRAG4(b1, Bp, brow0 + 512, g);
      __builtin_amdgcn_s_setprio(1);
      MFMA4(a0, b0, 0, 0); MFMA4(a0, b1, 0, 1);
      MFMA4(a1, b0, 1, 0); MFMA4(a1, b1, 1, 1);
      __builtin_amdgcn_s_setprio(0);
    }
    #undef FRAG4
    #undef MFMA4
    asm volatile("s_barrier" ::: "memory");
  }
  #undef STAGE

  #pragma unroll
  for (int m = 0; m < 2; ++m) {
    const long rowb = Arow0 + wrow * 64 + m * 32;
    #pragma unroll
    for (int g4 = 0; g4 < 4; ++g4) {
      #pragma unroll
      for (int r4 = 0; r4 < 4; ++r4) {
        const long row = rowb + r4 + 8 * g4 + 4 * lk;
        unsigned short* cp = C + row * (long)ldc + Brow0 + wcol * 64 + l31;
        cp[0]  = f2bf(acc[m][0][g4 * 4 + r4]);
        cp[32] = f2bf(acc[m][1][g4 * 4 + r4]);
      }
    }
  }
}

// ---------------------------------------------------------------------------
// 3) PV MX-fp8 GEMM, deep-pipelined (r14/r19 verified); blockIdx.y = batch.
//    Grid x 29 (348 blocks/batch), general m204 bijective XCD decode.
__global__ __launch_bounds__(256, 2) void pv_f8_k(
    const unsigned char* __restrict__ Att, const unsigned char* __restrict__ V,
    unsigned short* __restrict__ P, long sAtt, long sV)
{
  const int bb = blockIdx.y;
  Att += (long)bb * sAtt;
  V   += (long)bb * sV;
  __shared__ __align__(16) unsigned char As[4][4096];
  __shared__ __align__(16) unsigned char As2[4][4096];
  __shared__ __align__(16) unsigned char Bs[4][4096];
  __shared__ __align__(16) unsigned char Bs2[4][4096];

  const int tid  = threadIdx.x;
  const int lane = tid & 63;
  const int wave = tid >> 6;
  const int wrow = wave >> 1;
  const int wcol = wave & 1;

  const int nwg = gridDim.x;
  const int q8 = nwg >> 3, r8 = nwg & 7;
  const int xcd = blockIdx.x & 7, bidx = blockIdx.x >> 3;
  const int wg = (xcd < r8 ? xcd * (q8 + 1) : r8 * (q8 + 1) + (xcd - r8) * q8) + bidx;
  const int x = wg / 12, rem = wg % 12;
  const int y = rem & 3, z = rem >> 2;
  const long Arow0 = (long)x * 128;
  const long Brow0 = (long)y * 128;
  P += (long)(bb * 3 + z) * 3840 * 512;

  const unsigned char* sA[2];
  const unsigned char* sB[2];
  #pragma unroll
  for (int q = 0; q < 2; ++q) {
    const int c = q * 256 + tid;
    const int g = c >> 7, r = c & 127;
    sA[q] = Att + ((long)(z * 80 + g) * 3840 + Arow0 + r) * 16;
    sB[q] = V   + ((long)(z * 80 + g) * 512  + Brow0 + r) * 16;
  }
  const long ksA = 3840L * 16 * 4;
  const long ksB = 512L * 16 * 4;

  #define STAGE(tt) do { const int _sl = (tt) & 3;                      \
    gload_lds16(sA[0] + (long)(tt) * ksA, &As[_sl][tid * 16]);          \
    gload_lds16(sA[1] + (long)(tt) * ksA, &As2[_sl][tid * 16]);         \
    gload_lds16(sB[0] + (long)(tt) * ksB, &Bs[_sl][tid * 16]);          \
    gload_lds16(sB[1] + (long)(tt) * ksB, &Bs2[_sl][tid * 16]);         \
  } while (0)

  const int l31 = lane & 31, lk = lane >> 5;
  const int arow0 = (wrow * 64 + l31) * 16;
  const int brow0 = (wcol * 64 + l31) * 16;

  f32x16 acc[2][2] = {};
  const int NT = 20;

  STAGE(0); STAGE(1); STAGE(2);

  for (int t = 0; t < NT; ++t) {
    const int sl = t & 3;
    const int rem_t = NT - 1 - t;
    if (rem_t >= 2)      asm volatile("s_waitcnt vmcnt(8)" ::: "memory");
    else if (rem_t == 1) asm volatile("s_waitcnt vmcnt(4)" ::: "memory");
    else                 asm volatile("s_waitcnt vmcnt(0)" ::: "memory");
    asm volatile("s_barrier" ::: "memory");
    if (t + 3 < NT) STAGE(t + 3);

    const unsigned char* ApL = lk ? As2[sl] : As[sl];
    const unsigned char* BpL = lk ? Bs2[sl] : Bs[sl];
    #define LDF(base, rowb, s) (*(const i32x4*)((base) + (((s) << 11) + (rowb))))
    #define FRAG(dst, base, rowb) do {                  \
      i32x4 _lo = LDF(base, rowb, 0);                   \
      i32x4 _hi = LDF(base, rowb, 1);                   \
      dst[0]=_lo[0]; dst[1]=_lo[1]; dst[2]=_lo[2]; dst[3]=_lo[3]; \
      dst[4]=_hi[0]; dst[5]=_hi[1]; dst[6]=_hi[2]; dst[7]=_hi[3]; \
    } while (0)
    #define MFMA8(a, b, m, n) \
      acc[m][n] = __builtin_amdgcn_mfma_scale_f32_32x32x64_f8f6f4( \
          a, b, acc[m][n], 0, 0, 0, 127, 0, 127)

    i32x8 a0, a1, b0, b1;
    FRAG(a0, ApL, arow0); FRAG(a1, ApL, arow0 + 512);
    FRAG(b0, BpL, brow0); FRAG(b1, BpL, brow0 + 512);
    asm volatile("s_waitcnt lgkmcnt(0)" ::: "memory");
    __builtin_amdgcn_sched_barrier(0);
    __builtin_amdgcn_s_setprio(1);
    MFMA8(a0, b0, 0, 0); MFMA8(a0, b1, 0, 1);
    MFMA8(a1, b0, 1, 0); MFMA8(a1, b1, 1, 1);
    __builtin_amdgcn_s_setprio(0);
    #undef LDF
    #undef FRAG
    #undef MFMA8
  }
  #undef STAGE

  #pragma unroll
  for (int m = 0; m < 2; ++m) {
    const long rowb = Arow0 + wrow * 64 + m * 32;
    #pragma unroll
    for (int g4 = 0; g4 < 4; ++g4) {
      #pragma unroll
      for (int r4 = 0; r4 < 4; ++r4) {
        const long row = rowb + r4 + 8 * g4 + 4 * lk;
        unsigned short* cp = P + row * 512 + Brow0 + wcol * 64 + l31;
        cp[0]  = f2bf(acc[m][0][g4 * 4 + r4]);
        cp[32] = f2bf(acc[m][1][g4 * 4 + r4]);
      }
    }
  }
}

// ---------------------------------------------------------------------------
// 4) row softmax, pair-vectorized (r20 verified); blockIdx.y = batch
__global__ __launch_bounds__(256) void softmax_rows_k(
    const unsigned short* __restrict__ L4, const unsigned short* __restrict__ L3,
    const float* __restrict__ invq4, const float* __restrict__ invq3,
    const float* __restrict__ invs4, const float* __restrict__ invs3,
    const float* __restrict__ wch, unsigned char* __restrict__ Att,
    long sL, long sInv, long sAtt)
{
  const int b = blockIdx.y;
  L4 += (long)b * sL; L3 += (long)b * sL;
  invs4 += (long)b * sInv; invs3 += (long)b * sInv;
  Att += (long)b * sAtt;
  const int q = blockIdx.x;
  const unsigned short* r4 = L4 + (size_t)q * 3840;
  const unsigned short* r3 = L3 + (size_t)q * 3840;
  const float c4 = TEMP_C * wch[0] * invq4[q];
  const float c3 = TEMP_C * wch[1] * invq3[q];
  const int tid = threadIdx.x;
  float v0[8], v1[8];
  float mx = -1e30f;
  #pragma unroll
  for (int j = 0; j < 8; ++j) {
    const int sp = tid + j * 256;
    float x0 = -1e30f, x1 = -1e30f;
    if (sp < 1800) {
      const unsigned u4 = *(const unsigned*)&r4[2 * sp];
      const unsigned u3 = *(const unsigned*)&r3[2 * sp];
      const float2 i4v = *(const float2*)&invs4[2 * sp];
      const float2 i3v = *(const float2*)&invs3[2 * sp];
      x0 = c4 * bf2f((unsigned short)u4) * i4v.x + c3 * bf2f((unsigned short)u3) * i3v.x;
      x1 = c4 * bf2f((unsigned short)(u4 >> 16)) * i4v.y + c3 * bf2f((unsigned short)(u3 >> 16)) * i3v.y;
    }
    v0[j] = x0; v1[j] = x1;
    mx = fmaxf(mx, fmaxf(x0, x1));
  }
  #pragma unroll
  for (int o = 32; o > 0; o >>= 1) mx = fmaxf(mx, __shfl_xor(mx, o));
  __shared__ float wmax[4], wsum[4];
  if ((tid & 63) == 0) wmax[tid >> 6] = mx;
  __syncthreads();
  mx = fmaxf(fmaxf(wmax[0], wmax[1]), fmaxf(wmax[2], wmax[3]));
  float sum = 0.f;
  #pragma unroll
  for (int j = 0; j < 8; ++j) {
    const int sp = tid + j * 256;
    float e0 = 0.f, e1 = 0.f;
    if (sp < 1800) {
      e0 = __expf(v0[j] - mx);
      e1 = __expf(v1[j] - mx);
    }
    v0[j] = e0; v1[j] = e1;
    sum += e0 + e1;
  }
  #pragma unroll
  for (int o = 32; o > 0; o >>= 1) sum += __shfl_xor(sum, o);
  if ((tid & 63) == 0) wsum[tid >> 6] = sum;
  __syncthreads();
  sum = wsum[0] + wsum[1] + wsum[2] + wsum[3];
  const float inv448 = 448.0f / sum;
  #pragma unroll
  for (int j = 0; j < 8; ++j) {
    const int sp = tid + j * 256;
    if (sp < 1920) {
      const int s = 2 * sp;
      unsigned short w = 0;
      if (sp < 1800) {
        unsigned lo = f2e4m3(v0[j] * inv448);
        unsigned hi = f2e4m3(v1[j] * inv448);
        w = (unsigned short)(lo | (hi << 8));
      }
      *(unsigned short*)&Att[((size_t)(s >> 4) * 3840 + q) * 16 + (s & 15)] = w;
    }
  }
}

// ---------------------------------------------------------------------------
// 5) out[c][p] = 0.5*f_q[c][p] + (0.25/448)*sum_{z=0..5} P[z][p][c]
__global__ __launch_bounds__(256) void final_blend_k(
    const unsigned short* __restrict__ P, const float* __restrict__ fq,
    float* __restrict__ out)
{
  __shared__ float t[32][33];
  const int tx = threadIdx.x, ty = threadIdx.y;
  const int p0 = blockIdx.x * 32, c0 = blockIdx.y * 32;
  const long ZC = 3840L * 512;
  #pragma unroll
  for (int i = 0; i < 4; ++i) {
    int p = p0 + ty + i * 8, c = c0 + tx;
    float s = 0.f;
    if (p < 3600) {
      size_t o = (size_t)p * 512 + c;
      #pragma unroll
      for (int z = 0; z < 6; ++z) s += bf2f(P[o + (size_t)z * ZC]);
    }
    t[ty + i * 8][tx] = s;
  }
  __syncthreads();
  const float wts = 0.25f / 448.0f;
  #pragma unroll
  for (int i = 0; i < 4; ++i) {
    int c = c0 + ty + i * 8, p = p0 + tx;
    if (p < 3600) {
      size_t o = (size_t)c * 3600 + p;
      out[o] = 0.5f * fq[o] + wts * t[tx][ty + i * 8];
    }
  }
}

// ---------------------------------------------------------------------------
extern "C" void kernel_launch(void* const* d_in, const int* in_sizes, int n_in,
                              void* d_out, int out_size, void* d_ws, size_t ws_size,
                              hipStream_t stream) {
  const float* fq3 = (const float*)d_in[0];
  const float* fq4 = (const float*)d_in[1];
  const float* fs3 = (const float*)d_in[2];
  const float* fs4 = (const float*)d_in[3];
  const float* f_q = (const float*)d_in[4];
  const float* f_s = (const float*)d_in[5];
  const float* wch = (const float*)d_in[6];
  float* out = (float*)d_out;

  const size_t HW = 3600, MP = 3840, CH = 512;
  const size_t NG = 96;

  const long sT   = (long)NG * MP * 16;
  const long sV   = 240L * CH * 16;
  const long sL   = (long)MP * MP;
  const long sAtt = 240L * MP * 16;
  const long sPart = 96L * HW;
  const long sInv  = (long)HW;

  // workspace (~196 MB)
  unsigned char* QT4 = (unsigned char*)d_ws;
  unsigned char* ST4 = QT4 + sT;                      // 2x
  unsigned char* V8  = ST4 + 2 * sT;                  // 2x
  unsigned short* L4 = (unsigned short*)(V8 + 2 * sV);    // 2x
  unsigned short* L3 = L4 + 2 * sL;                   // 2x
  unsigned char* Att8 = (unsigned char*)(L3 + 2 * sL);    // 2x
  unsigned short* Pb = (unsigned short*)(Att8 + 2 * sAtt); // 6x (MP,CH)
  float* invq4 = (float*)(Pb + 6 * MP * CH);
  float* invq3 = invq4 + HW;
  float* invs4 = invq3 + HW;                          // 2x
  float* invs3 = invs4 + 2 * HW;                      // 2x
  float* partQ = invs3 + 2 * HW;
  float* partS = partQ + sPart;                       // 2x

  dim3 tb(32, 8);
  prep_k<<<dim3(113, 96, 5), tb, 0, stream>>>(
      fq4, fq3, fs4, fs3, f_s, QT4, ST4, partQ, partS, V8, sT, sPart, sV);
  norm_fin_k<<<dim3(15, 3), 256, 0, stream>>>(
      partQ, partS, invq4, invq3, invs4, invs3, sPart);

  const long G4OFF = 64L * MP * 16;

  // 29x29 = 841 blocks per job; r23 2-barrier structure (verified best)
  gemm128_f4<<<dim3(841, 1, 4), 256, 0, stream>>>(
      QT4, ST4, L4, L3, 3840, 3840, 29, sT, sL, G4OFF);

  softmax_rows_k<<<dim3(3600, 2), 256, 0, stream>>>(
      L4, L3, invq4, invq3, invs4, invs3, wch, Att8, sL, sInv, sAtt);

  // PV: x=29 (348 blocks/batch)
  pv_f8_k<<<dim3(348, 2), 256, 0, stream>>>(Att8, V8, Pb, sAtt, sV);

  final_blend_k<<<dim3(113, 16), tb, 0, stream>>>(Pb, f_q, out);
}